// Round 10
// baseline (999.915 us; speedup 1.0000x reference)
//
#include <hip/hip_runtime.h>
#include <hip/hip_bf16.h>
#include <utility>

typedef __attribute__((ext_vector_type(4))) float f32x4;
typedef __attribute__((ext_vector_type(8))) short bf16x8;
typedef __attribute__((ext_vector_type(4))) unsigned short u16x4;
typedef unsigned short u16;

constexpr int HH = 384, WW = 384;
constexpr int AWP = 386;               // padded activation width (+1 halo each side)
constexpr int ASTR = AWP * 64;         // elements per padded activation row
constexpr int NPIX = HH * WW;          // 147456
constexpr int NPIX3 = NPIX * 3;        // 442368 (one output tensor)
constexpr int DP = 398, DPLANE = DP * DP;  // data padded by 7 each side
constexpr size_t ACT_BYTES = (size_t)AWP * AWP * 64 * 2;  // 19,071,488
constexpr int WSW = 72 * 512;          // swizzled weights per conv: 72 iters * 64 lanes * 8
constexpr int WP1N = 12 * 512;         // conv1 swizzled weights (K=96)

__device__ __forceinline__ u16 f2bf(float f) {
  union { __hip_bfloat16 h; u16 u; } v; v.h = __float2bfloat16(f); return v.u;
}
__device__ __forceinline__ float bf2f(u16 u) {
  union { float f; unsigned int i; } v; v.i = ((unsigned int)u) << 16; return v.f;
}

// ---------------- weight/bias repack ----------------
// wpack: 7 convs, A-frag order: iter=(tap*2+ich)*4+m; oc=m*16+(lane&15); ic=ich*32+(lane>>4)*8+j
// wp1: conv1 (6ic, K=96): iter=kb*4+m; oc=m*16+(lane&15); k=kb*32+(lane>>4)*8+j; tap=k/8, ic=k%8
__global__ void repack_kern(const float* __restrict__ w1, const float* __restrict__ w2,
                            const float* __restrict__ wo, const float* __restrict__ b1,
                            const float* __restrict__ b2, const float* __restrict__ bo,
                            const float* __restrict__ wf,
                            u16* __restrict__ wpack, float* __restrict__ bpack,
                            u16* __restrict__ wp1)
{
  const int idx = blockIdx.x * 256 + threadIdx.x;
  constexpr int NW = 7 * WSW;
  if (idx < NW) {
    const int c = idx / WSW;
    const int r = idx % WSW;
    const int iter = r / 512;
    const int lane = (r % 512) / 8;
    const int j = r % 8;
    const int tap = iter >> 3;
    const int ich = (iter >> 2) & 1;
    const int m = iter & 3;
    const int oc = m * 16 + (lane & 15);
    const int ic = ich * 32 + (lane >> 4) * 8 + j;
    float v;
    if (c < 6) {
      const float* s = (c & 1) ? w2 : w1;
      v = s[(((c >> 1) * 64 + oc) * 64 + ic) * 9 + tap];
    } else {
      v = (oc < 35) ? wo[(oc * 64 + ic) * 9 + tap] : 0.f;
    }
    wpack[idx] = f2bf(v);
  } else if (idx < NW + 448) {
    const int t = idx - NW;
    const int c = t / 64, oc = t % 64;
    float v;
    if (c < 6) v = ((c & 1) ? b2 : b1)[(c >> 1) * 64 + oc];
    else v = (oc < 35) ? bo[oc] : 0.f;
    bpack[t] = v;
  } else if (idx < NW + 448 + WP1N) {
    const int t = idx - NW - 448;
    const int iter = t / 512;
    const int lane = (t % 512) / 8;
    const int j = t % 8;
    const int m = iter & 3;
    const int kb = iter >> 2;
    const int oc = m * 16 + (lane & 15);
    const int k = kb * 32 + (lane >> 4) * 8 + j;
    const int tap = k >> 3, ic = k & 7;
    const float v = (tap < 9 && ic < 6) ? wf[oc * 54 + ic * 9 + tap] : 0.f;
    wp1[t] = f2bf(v);
  }
}

// ---------------- halo clear: only the border bytes (replaces 42MB of memsets) ----------------
__global__ void halo_kern(u16* __restrict__ A0, u16* __restrict__ A1,
                          u16* __restrict__ in8, float* __restrict__ dpad)
{
  const int idx = blockIdx.x * 256 + threadIdx.x;
  if (idx < 49280) {                       // A0/A1 border: 1540 px * 16 u16x4 each
    u16* buf = (idx < 24640) ? A0 : A1;
    const int t = (idx < 24640) ? idx : idx - 24640;
    const int pos = t >> 4, q = t & 15;
    int y, x;
    if (pos < 386) { y = 0; x = pos; }
    else if (pos < 772) { y = 385; x = pos - 386; }
    else if (pos < 1156) { y = pos - 772 + 1; x = 0; }
    else { y = pos - 1156 + 1; x = 385; }
    *(u16x4*)(buf + ((size_t)y * AWP + x) * 64 + q * 4) = u16x4{0, 0, 0, 0};
  } else if (idx < 49280 + 3080) {         // in8 border: 1540 px * 2 u16x4
    const int t = idx - 49280;
    const int pos = t >> 1, q = t & 1;
    int y, x;
    if (pos < 386) { y = 0; x = pos; }
    else if (pos < 772) { y = 385; x = pos - 386; }
    else if (pos < 1156) { y = pos - 772 + 1; x = 0; }
    else { y = pos - 1156 + 1; x = 385; }
    *(u16x4*)(in8 + ((size_t)y * AWP + x) * 8 + q * 4) = u16x4{0, 0, 0, 0};
  } else if (idx < 49280 + 3080 + 32844) { // dpad border width 7, 3 ch
    const int t = idx - 52360;
    const int c = t / 10948, r = t % 10948;
    int y, x;
    if (r < 2786) { y = r / 398; x = r % 398; }
    else if (r < 5572) { const int rr = r - 2786; y = 391 + rr / 398; x = rr % 398; }
    else { const int rr = r - 5572; y = 7 + rr / 14; const int k = rr % 14; x = (k < 7) ? k : 384 + k; }
    dpad[(size_t)c * DPLANE + (size_t)y * DP + x] = 0.f;
  }
}

// ---------------- pad-copy data (fp32, halo 7) ----------------
__global__ void padcopy_kern(const float* __restrict__ data, float* __restrict__ dpad)
{
  const int idx = blockIdx.x * 256 + threadIdx.x;  // exactly 442368 threads
  const int c = idx / NPIX, r = idx % NPIX;
  const int y = r / WW, x = r % WW;
  dpad[c * DPLANE + (y + 7) * DP + (x + 7)] = data[idx];
}

// ---------------- pad data_with_est to NHWC8 bf16 (halo 1, ic 6->8 zero) ----------------
__global__ void pad6_kern(const float* __restrict__ din, u16* __restrict__ in8)
{
  const int px = blockIdx.x * 256 + threadIdx.x;   // 576*256 = NPIX exactly
  const int y = px / WW, x = px % WW;
  u16 vals[8];
  #pragma unroll
  for (int ic = 0; ic < 6; ++ic) vals[ic] = f2bf(din[ic * NPIX + px]);
  vals[6] = 0; vals[7] = 0;
  u16* o = in8 + ((size_t)(y + 1) * AWP + (x + 1)) * 8;
  *(u16x4*)(o) = u16x4{vals[0], vals[1], vals[2], vals[3]};
  *(u16x4*)(o + 4) = u16x4{vals[4], vals[5], vals[6], vals[7]};
}

// ---------------- conv1 via MFMA: 8ch NHWC bf16 -> 64, K=96 ----------------
__global__ __launch_bounds__(64)
void conv1_mfma(const u16* __restrict__ in8, const u16* __restrict__ wp,
                const float* __restrict__ bias, u16* __restrict__ outb)
{
  const int lane = threadIdx.x;
  const int l15 = lane & 15, g8 = lane >> 4;
  // XCD swizzle: 2304 = 8 * 288
  const int bid = blockIdx.x;
  const int sw = (bid & 7) * 288 + (bid >> 3);
  const int y = sw / 6;
  const int x0 = (sw % 6) * 64;

  f32x4 acc[4][4];
  #pragma unroll
  for (int m = 0; m < 4; ++m)
    #pragma unroll
    for (int n = 0; n < 4; ++n)
      acc[m][n] = f32x4{0.f, 0.f, 0.f, 0.f};

  #pragma unroll
  for (int kb = 0; kb < 3; ++kb) {
    const int tap = kb * 4 + g8;
    const int vt = tap < 9 ? tap : 0;                // dup tap0 for pad (weights are 0)
    const int kr = vt / 3, kc = vt % 3;
    const u16* inr = in8 + ((size_t)(y + kr) * AWP + x0 + kc) * 8;
    bf16x8 a[4], b[4];
    #pragma unroll
    for (int m = 0; m < 4; ++m)
      a[m] = *(const bf16x8*)(wp + (kb * 4 + m) * 512 + lane * 8);
    #pragma unroll
    for (int n = 0; n < 4; ++n)
      b[n] = *(const bf16x8*)(inr + (size_t)(n * 16 + l15) * 8);
    #pragma unroll
    for (int m = 0; m < 4; ++m)
      #pragma unroll
      for (int n = 0; n < 4; ++n)
        acc[m][n] = __builtin_amdgcn_mfma_f32_16x16x32_bf16(a[m], b[n], acc[m][n], 0, 0, 0);
  }

  const int oc_lo = g8 * 4;
  #pragma unroll
  for (int m = 0; m < 4; ++m) {
    const int oc0 = m * 16 + oc_lo;
    const f32x4 bv = *(const f32x4*)(bias + oc0);
    #pragma unroll
    for (int n = 0; n < 4; ++n) {
      const int px = x0 + n * 16 + l15;
      const f32x4 v = acc[m][n] + bv;
      u16x4 s;
      #pragma unroll
      for (int j = 0; j < 4; ++j) s[j] = f2bf(v[j]);
      *(u16x4*)(outb + ((size_t)(y + 1) * AWP + (px + 1)) * 64 + oc0) = s;
    }
  }
}

// ---------------- MFMA implicit-GEMM 3x3 conv: 2 output rows/block, K-split 2 waves ----------------
// Input rows y0+1,y0+2 feed both output rows -> 84KB loads/wave for 288 MFMA (-42% vs 1-row).
// Wave w = ich-half w; cross-wave K-reduce through LDS; wave w finishes output row w.
// MODE 0: +bias, relu; MODE 1: +bias,+residual; MODE 2: +bias, f32 planar (oc<35)
template<int MODE>
__global__ __launch_bounds__(128, 2)
void conv_mfma(const u16* __restrict__ in, const u16* __restrict__ wp,
               const float* __restrict__ bias, u16* __restrict__ outb,
               float* __restrict__ outf)
{
  __shared__ float red[2][16][256];                // 32 KB
  const int lane = threadIdx.x & 63;
  const int wv = threadIdx.x >> 6;                 // K-half: ich = wv
  const int l15 = lane & 15, g8 = lane >> 4;
  // XCD-aware swizzle: 1152 blocks = 8 XCDs * 144 (24 row-pairs... 192 row-pairs/8? 144 = 24*6)
  const int bid = blockIdx.x;
  const int sw = (bid & 7) * 144 + (bid >> 3);     // 1152 = 8*144, bijective
  const int y0 = (sw / 6) * 2;                     // output row base, 0..382 step 2
  const int x0 = (sw % 6) * 64;
  const int ich = wv;

  f32x4 acc[2][4][4];
  #pragma unroll
  for (int o = 0; o < 2; ++o)
    #pragma unroll
    for (int m = 0; m < 4; ++m)
      #pragma unroll
      for (int n = 0; n < 4; ++n)
        acc[o][m][n] = f32x4{0.f, 0.f, 0.f, 0.f};

  #pragma unroll
  for (int kc = 0; kc < 3; ++kc) {
    bf16x8 a[3][4];
    #pragma unroll
    for (int kr = 0; kr < 3; ++kr) {
      const u16* wpi = wp + (((kr * 3 + kc) * 2 + ich) * 4) * 512 + lane * 8;
      #pragma unroll
      for (int m = 0; m < 4; ++m) a[kr][m] = *(const bf16x8*)(wpi + m * 512);
    }
    #pragma unroll
    for (int ir = 0; ir < 4; ++ir) {               // padded input row y0+ir
      const u16* inr = in + (size_t)(y0 + ir) * ASTR + (size_t)(x0 + kc) * 64;
      bf16x8 b[4];
      #pragma unroll
      for (int n = 0; n < 4; ++n)
        b[n] = *(const bf16x8*)(inr + (size_t)(n * 16 + l15) * 64 + ich * 32 + g8 * 8);
      #pragma unroll
      for (int o = 0; o < 2; ++o) {
        constexpr int dummy = 0; (void)dummy;
        const int kr = ir - o;                     // compile-time under unroll
        if (kr >= 0 && kr < 3) {
          #pragma unroll
          for (int m = 0; m < 4; ++m)
            #pragma unroll
            for (int n = 0; n < 4; ++n)
              acc[o][m][n] = __builtin_amdgcn_mfma_f32_16x16x32_bf16(a[kr][m], b[n], acc[o][m][n], 0, 0, 0);
        }
      }
    }
  }

  // wave wv writes its partial for the OTHER row to LDS
  {
    const int oo = 1 - wv;
    #pragma unroll
    for (int m = 0; m < 4; ++m)
      #pragma unroll
      for (int n = 0; n < 4; ++n)
        *(f32x4*)(&red[oo][m * 4 + n][lane * 4]) = acc[oo][m][n];
  }
  __syncthreads();

  // wave wv finishes output row y0+wv
  const int o = wv;
  const int y = y0 + o;
  const int oc_lo = g8 * 4;
  #pragma unroll
  for (int m = 0; m < 4; ++m) {
    const int oc0 = m * 16 + oc_lo;                // D row = (lane>>4)*4 + reg
    const f32x4 bv = *(const f32x4*)(bias + oc0);
    #pragma unroll
    for (int n = 0; n < 4; ++n) {
      const int px = x0 + n * 16 + l15;            // D col = lane&15
      f32x4 v = acc[o][m][n] + *(const f32x4*)(&red[o][m * 4 + n][lane * 4]) + bv;
      if constexpr (MODE == 0) {
        #pragma unroll
        for (int j = 0; j < 4; ++j) v[j] = v[j] > 0.f ? v[j] : 0.f;
      }
      if constexpr (MODE == 1) {
        const u16x4 r = *(const u16x4*)(outb + ((size_t)(y + 1) * AWP + (px + 1)) * 64 + oc0);
        #pragma unroll
        for (int j = 0; j < 4; ++j) v[j] += bf2f(r[j]);
      }
      if constexpr (MODE <= 1) {
        u16x4 s;
        #pragma unroll
        for (int j = 0; j < 4; ++j) s[j] = f2bf(v[j]);
        *(u16x4*)(outb + ((size_t)(y + 1) * AWP + (px + 1)) * 64 + oc0) = s;
      } else {
        #pragma unroll
        for (int j = 0; j < 4; ++j) {
          const int oc = oc0 + j;
          if (oc < 35) outf[(size_t)oc * NPIX + (size_t)y * WW + px] = v[j];
        }
      }
    }
  }
}

// ---------------- KPN apply: template-fold sweep (guaranteed static indexing) ----------------
constexpr int isqrt_(int d2) { int li = 0; while ((li + 1) * (li + 1) <= d2) ++li; return li; }
constexpr double csqrt_(double x) {
  double g = x < 1.0 ? 1.0 : x;
  for (int i = 0; i < 60; ++i) g = 0.5 * (g + x / g);
  return g;
}
constexpr int KOFFS[7] = {0, 2, 5, 9, 14, 20, 27};

template<int SEC0, int NSEC, int CKN, int A, int B, int T>
__device__ __forceinline__ void kpn_sec_one(const float (&g)[3], const float (&ck)[CKN],
                                            float (&s)[NSEC], float (&p)[NSEC][3])
{
  constexpr int WIDE = SEC0 + T + 2;
  if constexpr (A < WIDE && B < WIDE) {
    constexpr int d2 = A * A + B * B;
    constexpr int li = isqrt_(d2);
    constexpr bool exact = (li * li == d2);
    constexpr int hraw = exact ? li : li + 1;
    constexpr float dd = (float)csqrt_((double)d2);
    constexpr float wlo = exact ? 1.0f : ((float)hraw - dd);
    constexpr float whi = exact ? 0.0f : (dd - (float)li);
    constexpr float mult = ((A > 0) ? 2.0f : 1.0f) * ((B > 0) ? 2.0f : 1.0f);
    constexpr int lidx = li < WIDE - 1 ? li : WIDE - 1;
    constexpr int hidx = hraw < WIDE - 1 ? hraw : WIDE - 1;
    constexpr bool msk = d2 <= (WIDE - 1) * (WIDE - 1);
    constexpr int cb = KOFFS[SEC0 + T] - KOFFS[SEC0];
    float e;
    if constexpr (msk) e = __expf(wlo * ck[cb + lidx] + whi * ck[cb + hidx]);
    else e = 1.0f;                                   // masked: logit 0, still in softmax
    s[T] += mult * e;
    p[T][0] += e * g[0];
    p[T][1] += e * g[1];
    p[T][2] += e * g[2];
  }
}

template<int SEC0, int NSEC, int CKN, int A, int B, int... Ts>
__device__ __forceinline__ void kpn_secs(std::integer_sequence<int, Ts...>,
                                         const float (&g)[3], const float (&ck)[CKN],
                                         float (&s)[NSEC], float (&p)[NSEC][3])
{
  (kpn_sec_one<SEC0, NSEC, CKN, A, B, Ts>(g, ck, s, p), ...);
}

template<int SEC0, int NSEC, int CKN, int WMAX, int C>
__device__ __forceinline__ void kpn_cell(const float* __restrict__ base,
                                         const float (&ck)[CKN],
                                         float (&s)[NSEC], float (&p)[NSEC][3])
{
  constexpr int A = C / WMAX, B = C % WMAX;
  float g[3];
  #pragma unroll
  for (int c = 0; c < 3; ++c) {
    const float* bc = base + c * DPLANE;
    float v = bc[A * DP + B];
    if constexpr (B > 0) v += bc[A * DP - B];
    if constexpr (A > 0) v += bc[-A * DP + B];
    if constexpr (A > 0 && B > 0) v += bc[-A * DP - B];
    g[c] = v;
  }
  kpn_secs<SEC0, NSEC, CKN, A, B>(std::make_integer_sequence<int, NSEC>{}, g, ck, s, p);
}

template<int SEC0, int NSEC, int CKN, int WMAX, int... Cs>
__device__ __forceinline__ void kpn_cells(std::integer_sequence<int, Cs...>,
                                          const float* __restrict__ base,
                                          const float (&ck)[CKN],
                                          float (&s)[NSEC], float (&p)[NSEC][3])
{
  (kpn_cell<SEC0, NSEC, CKN, WMAX, Cs>(base, ck, s, p), ...);
}

template<int SEC0, int NSEC>
__device__ __forceinline__ void kpn_grp_body(const float* __restrict__ corep,
                                             const float* __restrict__ dpad,
                                             float* __restrict__ out)
{
  constexpr int WMAX = SEC0 + NSEC + 1;          // widest WIDE in this group
  constexpr int CK0 = KOFFS[SEC0];
  constexpr int CKN = KOFFS[SEC0 + NSEC - 1] + (SEC0 + NSEC + 1) - CK0;

  const int px = blockIdx.x * 64 + threadIdx.x;       // 2304*64 = NPIX exactly
  const int y = px / WW, x = px % WW;
  const float* base = dpad + (size_t)(y + 7) * DP + (x + 7);

  float ck[CKN];
  #pragma unroll
  for (int i = 0; i < CKN; ++i) ck[i] = fabsf(corep[(size_t)(CK0 + i) * NPIX + px]);

  float s[NSEC], p[NSEC][3];
  #pragma unroll
  for (int k = 0; k < NSEC; ++k) { s[k] = 0.f; p[k][0] = 0.f; p[k][1] = 0.f; p[k][2] = 0.f; }

  kpn_cells<SEC0, NSEC, CKN, WMAX>(std::make_integer_sequence<int, WMAX * WMAX>{},
                                   base, ck, s, p);

  #pragma unroll
  for (int t = 0; t < NSEC; ++t) {
    const float inv = 1.f / s[t];
    float* o = out + (size_t)(SEC0 + t + 1) * NPIX3 + px;
    o[0] = p[t][0] * inv;
    o[NPIX] = p[t][1] * inv;
    o[2 * NPIX] = p[t][2] * inv;
  }
}

__global__ __launch_bounds__(64, 6)
void kpn_split(const float* __restrict__ corep, const float* __restrict__ dpad,
               float* __restrict__ out)
{
  if (blockIdx.y == 0) kpn_grp_body<0, 5>(corep, dpad, out);   // WIDE 2-6
  else                 kpn_grp_body<5, 2>(corep, dpad, out);   // WIDE 7-8
}

// ---------------- launch ----------------
extern "C" void kernel_launch(void* const* d_in, const int* in_sizes, int n_in,
                              void* d_out, int out_size, void* d_ws, size_t ws_size,
                              hipStream_t stream)
{
  const float* d_est   = (const float*)d_in[0];
  const float* data    = (const float*)d_in[1];
  const float* w_first = (const float*)d_in[2];
  const float* b_first = (const float*)d_in[3];
  const float* w_blk1  = (const float*)d_in[4];
  const float* b_blk1  = (const float*)d_in[5];
  const float* w_blk2  = (const float*)d_in[6];
  const float* b_blk2  = (const float*)d_in[7];
  const float* w_out   = (const float*)d_in[8];
  const float* b_out   = (const float*)d_in[9];

  char* ws = (char*)d_ws;
  const size_t OFF_A1    = ACT_BYTES;
  const size_t OFF_CORE  = 2 * ACT_BYTES;
  const size_t OFF_DPAD  = OFF_CORE + (size_t)35 * NPIX * 4;
  const size_t OFF_WPACK = OFF_DPAD + (size_t)3 * DPLANE * 4;
  const size_t OFF_BPACK = OFF_WPACK + (size_t)7 * WSW * 2;
  const size_t OFF_WP1   = OFF_BPACK + 448 * 4;
  const size_t OFF_IN8   = OFF_WP1 + (size_t)WP1N * 2;

  u16*   A0    = (u16*)(ws);
  u16*   A1    = (u16*)(ws + OFF_A1);
  float* corep = (float*)(ws + OFF_CORE);
  float* dpad  = (float*)(ws + OFF_DPAD);
  u16*   wpack = (u16*)(ws + OFF_WPACK);
  float* bpack = (float*)(ws + OFF_BPACK);
  u16*   wp1   = (u16*)(ws + OFF_WP1);
  u16*   in8   = (u16*)(ws + OFF_IN8);

  // output 0 is an exact copy of `data`
  hipMemcpyAsync(d_out, data, (size_t)NPIX3 * 4, hipMemcpyDeviceToDevice, stream);

  halo_kern<<<333, 256, 0, stream>>>(A0, A1, in8, dpad);
  repack_kern<<<1034, 256, 0, stream>>>(w_blk1, w_blk2, w_out, b_blk1, b_blk2, b_out,
                                        w_first, wpack, bpack, wp1);
  padcopy_kern<<<1728, 256, 0, stream>>>(data, dpad);
  pad6_kern<<<576, 256, 0, stream>>>(d_est, in8);
  conv1_mfma<<<2304, 64, 0, stream>>>(in8, wp1, b_first, A0);

  for (int i = 0; i < 3; ++i) {
    conv_mfma<0><<<1152, 128, 0, stream>>>(A0, wpack + (size_t)(2 * i) * WSW,
                                           bpack + (2 * i) * 64, A1, nullptr);
    conv_mfma<1><<<1152, 128, 0, stream>>>(A1, wpack + (size_t)(2 * i + 1) * WSW,
                                           bpack + (2 * i + 1) * 64, A0, nullptr);
  }
  conv_mfma<2><<<1152, 128, 0, stream>>>(A0, wpack + (size_t)6 * WSW,
                                         bpack + 6 * 64, nullptr, corep);

  kpn_split<<<dim3(2304, 2), 64, 0, stream>>>(corep, dpad, (float*)d_out);
}

// Round 11
// 330.475 us; speedup vs baseline: 3.0257x; 3.0257x over previous
//
#include <hip/hip_runtime.h>
#include <hip/hip_bf16.h>
#include <utility>

typedef __attribute__((ext_vector_type(4))) float f32x4;
typedef __attribute__((ext_vector_type(8))) short bf16x8;
typedef __attribute__((ext_vector_type(4))) unsigned short u16x4;
typedef unsigned short u16;

constexpr int HH = 384, WW = 384;
constexpr int AWP = 386;               // padded activation width (+1 halo each side)
constexpr int ASTR = AWP * 64;         // elements per padded activation row
constexpr int NPIX = HH * WW;          // 147456
constexpr int NPIX3 = NPIX * 3;        // 442368 (one output tensor)
constexpr int DP = 398, DPLANE = DP * DP;  // data padded by 7 each side
constexpr size_t ACT_BYTES = (size_t)AWP * AWP * 64 * 2;  // 19,071,488
constexpr int WSW = 72 * 512;          // swizzled weights per conv: 72 iters * 64 lanes * 8
constexpr int WP1N = 12 * 512;         // conv1 swizzled weights (K=96)

__device__ __forceinline__ u16 f2bf(float f) {
  union { __hip_bfloat16 h; u16 u; } v; v.h = __float2bfloat16(f); return v.u;
}
__device__ __forceinline__ float bf2f(u16 u) {
  union { float f; unsigned int i; } v; v.i = ((unsigned int)u) << 16; return v.f;
}

// ---------------- weight/bias repack ----------------
// wpack: 7 convs, A-frag order: iter=(tap*2+ich)*4+m; oc=m*16+(lane&15); ic=ich*32+(lane>>4)*8+j
// wp1: conv1 (6ic, K=96): iter=kb*4+m; oc=m*16+(lane&15); k=kb*32+(lane>>4)*8+j; tap=k/8, ic=k%8
__global__ void repack_kern(const float* __restrict__ w1, const float* __restrict__ w2,
                            const float* __restrict__ wo, const float* __restrict__ b1,
                            const float* __restrict__ b2, const float* __restrict__ bo,
                            const float* __restrict__ wf,
                            u16* __restrict__ wpack, float* __restrict__ bpack,
                            u16* __restrict__ wp1)
{
  const int idx = blockIdx.x * 256 + threadIdx.x;
  constexpr int NW = 7 * WSW;
  if (idx < NW) {
    const int c = idx / WSW;
    const int r = idx % WSW;
    const int iter = r / 512;
    const int lane = (r % 512) / 8;
    const int j = r % 8;
    const int tap = iter >> 3;
    const int ich = (iter >> 2) & 1;
    const int m = iter & 3;
    const int oc = m * 16 + (lane & 15);
    const int ic = ich * 32 + (lane >> 4) * 8 + j;
    float v;
    if (c < 6) {
      const float* s = (c & 1) ? w2 : w1;
      v = s[(((c >> 1) * 64 + oc) * 64 + ic) * 9 + tap];
    } else {
      v = (oc < 35) ? wo[(oc * 64 + ic) * 9 + tap] : 0.f;
    }
    wpack[idx] = f2bf(v);
  } else if (idx < NW + 448) {
    const int t = idx - NW;
    const int c = t / 64, oc = t % 64;
    float v;
    if (c < 6) v = ((c & 1) ? b2 : b1)[(c >> 1) * 64 + oc];
    else v = (oc < 35) ? bo[oc] : 0.f;
    bpack[t] = v;
  } else if (idx < NW + 448 + WP1N) {
    const int t = idx - NW - 448;
    const int iter = t / 512;
    const int lane = (t % 512) / 8;
    const int j = t % 8;
    const int m = iter & 3;
    const int kb = iter >> 2;
    const int oc = m * 16 + (lane & 15);
    const int k = kb * 32 + (lane >> 4) * 8 + j;
    const int tap = k >> 3, ic = k & 7;
    const float v = (tap < 9 && ic < 6) ? wf[oc * 54 + ic * 9 + tap] : 0.f;
    wp1[t] = f2bf(v);
  }
}

// ---------------- halo clear: only the border bytes (replaces 42MB of memsets) ----------------
__global__ void halo_kern(u16* __restrict__ A0, u16* __restrict__ A1,
                          u16* __restrict__ in8, float* __restrict__ dpad)
{
  const int idx = blockIdx.x * 256 + threadIdx.x;
  if (idx < 49280) {                       // A0/A1 border: 1540 px * 16 u16x4 each
    u16* buf = (idx < 24640) ? A0 : A1;
    const int t = (idx < 24640) ? idx : idx - 24640;
    const int pos = t >> 4, q = t & 15;
    int y, x;
    if (pos < 386) { y = 0; x = pos; }
    else if (pos < 772) { y = 385; x = pos - 386; }
    else if (pos < 1156) { y = pos - 772 + 1; x = 0; }
    else { y = pos - 1156 + 1; x = 385; }
    *(u16x4*)(buf + ((size_t)y * AWP + x) * 64 + q * 4) = u16x4{0, 0, 0, 0};
  } else if (idx < 49280 + 3080) {         // in8 border: 1540 px * 2 u16x4
    const int t = idx - 49280;
    const int pos = t >> 1, q = t & 1;
    int y, x;
    if (pos < 386) { y = 0; x = pos; }
    else if (pos < 772) { y = 385; x = pos - 386; }
    else if (pos < 1156) { y = pos - 772 + 1; x = 0; }
    else { y = pos - 1156 + 1; x = 385; }
    *(u16x4*)(in8 + ((size_t)y * AWP + x) * 8 + q * 4) = u16x4{0, 0, 0, 0};
  } else if (idx < 49280 + 3080 + 32844) { // dpad border width 7, 3 ch
    const int t = idx - 52360;
    const int c = t / 10948, r = t % 10948;
    int y, x;
    if (r < 2786) { y = r / 398; x = r % 398; }
    else if (r < 5572) { const int rr = r - 2786; y = 391 + rr / 398; x = rr % 398; }
    else { const int rr = r - 5572; y = 7 + rr / 14; const int k = rr % 14; x = (k < 7) ? k : 384 + k; }
    dpad[(size_t)c * DPLANE + (size_t)y * DP + x] = 0.f;
  }
}

// ---------------- pad-copy data (fp32, halo 7) ----------------
__global__ void padcopy_kern(const float* __restrict__ data, float* __restrict__ dpad)
{
  const int idx = blockIdx.x * 256 + threadIdx.x;  // exactly 442368 threads
  const int c = idx / NPIX, r = idx % NPIX;
  const int y = r / WW, x = r % WW;
  dpad[c * DPLANE + (y + 7) * DP + (x + 7)] = data[idx];
}

// ---------------- pad data_with_est to NHWC8 bf16 (halo 1, ic 6->8 zero) ----------------
__global__ void pad6_kern(const float* __restrict__ din, u16* __restrict__ in8)
{
  const int px = blockIdx.x * 256 + threadIdx.x;   // 576*256 = NPIX exactly
  const int y = px / WW, x = px % WW;
  u16 vals[8];
  #pragma unroll
  for (int ic = 0; ic < 6; ++ic) vals[ic] = f2bf(din[ic * NPIX + px]);
  vals[6] = 0; vals[7] = 0;
  u16* o = in8 + ((size_t)(y + 1) * AWP + (x + 1)) * 8;
  *(u16x4*)(o) = u16x4{vals[0], vals[1], vals[2], vals[3]};
  *(u16x4*)(o + 4) = u16x4{vals[4], vals[5], vals[6], vals[7]};
}

// ---------------- conv1 via MFMA: 8ch NHWC bf16 -> 64, K=96 ----------------
__global__ __launch_bounds__(64)
void conv1_mfma(const u16* __restrict__ in8, const u16* __restrict__ wp,
                const float* __restrict__ bias, u16* __restrict__ outb)
{
  const int lane = threadIdx.x;
  const int l15 = lane & 15, g8 = lane >> 4;
  // XCD swizzle: 2304 = 8 * 288
  const int bid = blockIdx.x;
  const int sw = (bid & 7) * 288 + (bid >> 3);
  const int y = sw / 6;
  const int x0 = (sw % 6) * 64;

  f32x4 acc[4][4];
  #pragma unroll
  for (int m = 0; m < 4; ++m)
    #pragma unroll
    for (int n = 0; n < 4; ++n)
      acc[m][n] = f32x4{0.f, 0.f, 0.f, 0.f};

  #pragma unroll
  for (int kb = 0; kb < 3; ++kb) {
    const int tap = kb * 4 + g8;
    const int vt = tap < 9 ? tap : 0;                // dup tap0 for pad (weights are 0)
    const int kr = vt / 3, kc = vt % 3;
    const u16* inr = in8 + ((size_t)(y + kr) * AWP + x0 + kc) * 8;
    bf16x8 a[4], b[4];
    #pragma unroll
    for (int m = 0; m < 4; ++m)
      a[m] = *(const bf16x8*)(wp + (kb * 4 + m) * 512 + lane * 8);
    #pragma unroll
    for (int n = 0; n < 4; ++n)
      b[n] = *(const bf16x8*)(inr + (size_t)(n * 16 + l15) * 8);
    #pragma unroll
    for (int m = 0; m < 4; ++m)
      #pragma unroll
      for (int n = 0; n < 4; ++n)
        acc[m][n] = __builtin_amdgcn_mfma_f32_16x16x32_bf16(a[m], b[n], acc[m][n], 0, 0, 0);
  }

  const int oc_lo = g8 * 4;
  #pragma unroll
  for (int m = 0; m < 4; ++m) {
    const int oc0 = m * 16 + oc_lo;
    const f32x4 bv = *(const f32x4*)(bias + oc0);
    #pragma unroll
    for (int n = 0; n < 4; ++n) {
      const int px = x0 + n * 16 + l15;
      const f32x4 v = acc[m][n] + bv;
      u16x4 s;
      #pragma unroll
      for (int j = 0; j < 4; ++j) s[j] = f2bf(v[j]);
      *(u16x4*)(outb + ((size_t)(y + 1) * AWP + (px + 1)) * 64 + oc0) = s;
    }
  }
}

// ---------------- MFMA implicit-GEMM 3x3 conv, K-split across 2 waves (R9 known-good) ----------------
// MODE 0: +bias, relu; MODE 1: +bias,+residual; MODE 2: +bias, f32 planar (oc<35)
template<int MODE>
__global__ __launch_bounds__(128, 3)
void conv_mfma(const u16* __restrict__ in, const u16* __restrict__ wp,
               const float* __restrict__ bias, u16* __restrict__ outb,
               float* __restrict__ outf)
{
  __shared__ float red[64 * 64];                   // 16 KB: wave1's partial acc
  const int lane = threadIdx.x & 63;
  const int wv = threadIdx.x >> 6;                 // K-half: ich = wv
  const int l15 = lane & 15, g8 = lane >> 4;
  // XCD-aware swizzle: 2304 blocks = 8 XCDs * 288 (48 rows * 6 col-blocks each)
  const int bid = blockIdx.x;
  const int sw = (bid & 7) * 288 + (bid >> 3);
  const int y = sw / 6;
  const int x0 = (sw % 6) * 64;
  const int ich = wv;

  f32x4 acc[4][4];
  #pragma unroll
  for (int m = 0; m < 4; ++m)
    #pragma unroll
    for (int n = 0; n < 4; ++n)
      acc[m][n] = f32x4{0.f, 0.f, 0.f, 0.f};

  #pragma unroll
  for (int tap = 0; tap < 9; ++tap) {
    const int kr = tap / 3, kc = tap % 3;
    const u16* inr = in + (size_t)(y + kr) * ASTR + (size_t)(x0 + kc) * 64;
    const u16* wpi = wp + ((tap * 2 + ich) * 4) * 512 + lane * 8;  // coalesced A-frags
    bf16x8 a[4], b[4];
    #pragma unroll
    for (int m = 0; m < 4; ++m)
      a[m] = *(const bf16x8*)(wpi + m * 512);
    #pragma unroll
    for (int n = 0; n < 4; ++n)
      b[n] = *(const bf16x8*)(inr + (size_t)(n * 16 + l15) * 64 + ich * 32 + g8 * 8);
    #pragma unroll
    for (int m = 0; m < 4; ++m)
      #pragma unroll
      for (int n = 0; n < 4; ++n)
        acc[m][n] = __builtin_amdgcn_mfma_f32_16x16x32_bf16(a[m], b[n], acc[m][n], 0, 0, 0);
  }

  if (wv == 1) {
    #pragma unroll
    for (int m = 0; m < 4; ++m)
      #pragma unroll
      for (int n = 0; n < 4; ++n)
        *(f32x4*)(red + (m * 4 + n) * 256 + lane * 4) = acc[m][n];
  }
  __syncthreads();
  if (wv == 1) return;

  const int oc_lo = g8 * 4;
  #pragma unroll
  for (int m = 0; m < 4; ++m) {
    const int oc0 = m * 16 + oc_lo;                  // D row = (lane>>4)*4 + reg
    const f32x4 bv = *(const f32x4*)(bias + oc0);
    #pragma unroll
    for (int n = 0; n < 4; ++n) {
      const int px = x0 + n * 16 + l15;              // D col = lane&15
      f32x4 v = acc[m][n] + *(const f32x4*)(red + (m * 4 + n) * 256 + lane * 4) + bv;
      if constexpr (MODE == 0) {
        #pragma unroll
        for (int j = 0; j < 4; ++j) v[j] = v[j] > 0.f ? v[j] : 0.f;
      }
      if constexpr (MODE == 1) {
        const u16x4 r = *(const u16x4*)(outb + ((size_t)(y + 1) * AWP + (px + 1)) * 64 + oc0);
        #pragma unroll
        for (int j = 0; j < 4; ++j) v[j] += bf2f(r[j]);
      }
      if constexpr (MODE <= 1) {
        u16x4 s;
        #pragma unroll
        for (int j = 0; j < 4; ++j) s[j] = f2bf(v[j]);
        *(u16x4*)(outb + ((size_t)(y + 1) * AWP + (px + 1)) * 64 + oc0) = s;
      } else {
        #pragma unroll
        for (int j = 0; j < 4; ++j) {
          const int oc = oc0 + j;
          if (oc < 35) outf[(size_t)oc * NPIX + (size_t)y * WW + px] = v[j];
        }
      }
    }
  }
}

// ---------------- KPN apply: template-fold sweep (guaranteed static indexing) ----------------
constexpr int isqrt_(int d2) { int li = 0; while ((li + 1) * (li + 1) <= d2) ++li; return li; }
constexpr double csqrt_(double x) {
  double g = x < 1.0 ? 1.0 : x;
  for (int i = 0; i < 60; ++i) g = 0.5 * (g + x / g);
  return g;
}
constexpr int KOFFS[7] = {0, 2, 5, 9, 14, 20, 27};

template<int SEC0, int NSEC, int CKN, int A, int B, int T>
__device__ __forceinline__ void kpn_sec_one(const float (&g)[3], const float (&ck)[CKN],
                                            float (&s)[NSEC], float (&p)[NSEC][3])
{
  constexpr int WIDE = SEC0 + T + 2;
  if constexpr (A < WIDE && B < WIDE) {
    constexpr int d2 = A * A + B * B;
    constexpr int li = isqrt_(d2);
    constexpr bool exact = (li * li == d2);
    constexpr int hraw = exact ? li : li + 1;
    constexpr float dd = (float)csqrt_((double)d2);
    constexpr float wlo = exact ? 1.0f : ((float)hraw - dd);
    constexpr float whi = exact ? 0.0f : (dd - (float)li);
    constexpr float mult = ((A > 0) ? 2.0f : 1.0f) * ((B > 0) ? 2.0f : 1.0f);
    constexpr int lidx = li < WIDE - 1 ? li : WIDE - 1;
    constexpr int hidx = hraw < WIDE - 1 ? hraw : WIDE - 1;
    constexpr bool msk = d2 <= (WIDE - 1) * (WIDE - 1);
    constexpr int cb = KOFFS[SEC0 + T] - KOFFS[SEC0];
    float e;
    if constexpr (msk) e = __expf(wlo * ck[cb + lidx] + whi * ck[cb + hidx]);
    else e = 1.0f;                                   // masked: logit 0, still in softmax
    s[T] += mult * e;
    p[T][0] += e * g[0];
    p[T][1] += e * g[1];
    p[T][2] += e * g[2];
  }
}

template<int SEC0, int NSEC, int CKN, int A, int B, int... Ts>
__device__ __forceinline__ void kpn_secs(std::integer_sequence<int, Ts...>,
                                         const float (&g)[3], const float (&ck)[CKN],
                                         float (&s)[NSEC], float (&p)[NSEC][3])
{
  (kpn_sec_one<SEC0, NSEC, CKN, A, B, Ts>(g, ck, s, p), ...);
}

template<int SEC0, int NSEC, int CKN, int WMAX, int C>
__device__ __forceinline__ void kpn_cell(const float* __restrict__ base,
                                         const float (&ck)[CKN],
                                         float (&s)[NSEC], float (&p)[NSEC][3])
{
  constexpr int A = C / WMAX, B = C % WMAX;
  float g[3];
  #pragma unroll
  for (int c = 0; c < 3; ++c) {
    const float* bc = base + c * DPLANE;
    float v = bc[A * DP + B];
    if constexpr (B > 0) v += bc[A * DP - B];
    if constexpr (A > 0) v += bc[-A * DP + B];
    if constexpr (A > 0 && B > 0) v += bc[-A * DP - B];
    g[c] = v;
  }
  kpn_secs<SEC0, NSEC, CKN, A, B>(std::make_integer_sequence<int, NSEC>{}, g, ck, s, p);
}

template<int SEC0, int NSEC, int CKN, int WMAX, int... Cs>
__device__ __forceinline__ void kpn_cells(std::integer_sequence<int, Cs...>,
                                          const float* __restrict__ base,
                                          const float (&ck)[CKN],
                                          float (&s)[NSEC], float (&p)[NSEC][3])
{
  (kpn_cell<SEC0, NSEC, CKN, WMAX, Cs>(base, ck, s, p), ...);
}

template<int SEC0, int NSEC>
__device__ __forceinline__ void kpn_grp_body(const float* __restrict__ corep,
                                             const float* __restrict__ dpad,
                                             float* __restrict__ out)
{
  constexpr int WMAX = SEC0 + NSEC + 1;          // widest WIDE in this group
  constexpr int CK0 = KOFFS[SEC0];
  constexpr int CKN = KOFFS[SEC0 + NSEC - 1] + (SEC0 + NSEC + 1) - CK0;

  const int px = blockIdx.x * 64 + threadIdx.x;       // 2304*64 = NPIX exactly
  const int y = px / WW, x = px % WW;
  const float* base = dpad + (size_t)(y + 7) * DP + (x + 7);

  float ck[CKN];
  #pragma unroll
  for (int i = 0; i < CKN; ++i) ck[i] = fabsf(corep[(size_t)(CK0 + i) * NPIX + px]);

  float s[NSEC], p[NSEC][3];
  #pragma unroll
  for (int k = 0; k < NSEC; ++k) { s[k] = 0.f; p[k][0] = 0.f; p[k][1] = 0.f; p[k][2] = 0.f; }

  kpn_cells<SEC0, NSEC, CKN, WMAX>(std::make_integer_sequence<int, WMAX * WMAX>{},
                                   base, ck, s, p);

  #pragma unroll
  for (int t = 0; t < NSEC; ++t) {
    const float inv = 1.f / s[t];
    float* o = out + (size_t)(SEC0 + t + 1) * NPIX3 + px;
    o[0] = p[t][0] * inv;
    o[NPIX] = p[t][1] * inv;
    o[2 * NPIX] = p[t][2] * inv;
  }
}

__global__ __launch_bounds__(64, 6)
void kpn_split(const float* __restrict__ corep, const float* __restrict__ dpad,
               float* __restrict__ out)
{
  if (blockIdx.y == 0) kpn_grp_body<0, 5>(corep, dpad, out);   // WIDE 2-6
  else                 kpn_grp_body<5, 2>(corep, dpad, out);   // WIDE 7-8
}

// ---------------- launch ----------------
extern "C" void kernel_launch(void* const* d_in, const int* in_sizes, int n_in,
                              void* d_out, int out_size, void* d_ws, size_t ws_size,
                              hipStream_t stream)
{
  const float* d_est   = (const float*)d_in[0];
  const float* data    = (const float*)d_in[1];
  const float* w_first = (const float*)d_in[2];
  const float* b_first = (const float*)d_in[3];
  const float* w_blk1  = (const float*)d_in[4];
  const float* b_blk1  = (const float*)d_in[5];
  const float* w_blk2  = (const float*)d_in[6];
  const float* b_blk2  = (const float*)d_in[7];
  const float* w_out   = (const float*)d_in[8];
  const float* b_out   = (const float*)d_in[9];

  char* ws = (char*)d_ws;
  const size_t OFF_A1    = ACT_BYTES;
  const size_t OFF_CORE  = 2 * ACT_BYTES;
  const size_t OFF_DPAD  = OFF_CORE + (size_t)35 * NPIX * 4;
  const size_t OFF_WPACK = OFF_DPAD + (size_t)3 * DPLANE * 4;
  const size_t OFF_BPACK = OFF_WPACK + (size_t)7 * WSW * 2;
  const size_t OFF_WP1   = OFF_BPACK + 448 * 4;
  const size_t OFF_IN8   = OFF_WP1 + (size_t)WP1N * 2;

  u16*   A0    = (u16*)(ws);
  u16*   A1    = (u16*)(ws + OFF_A1);
  float* corep = (float*)(ws + OFF_CORE);
  float* dpad  = (float*)(ws + OFF_DPAD);
  u16*   wpack = (u16*)(ws + OFF_WPACK);
  float* bpack = (float*)(ws + OFF_BPACK);
  u16*   wp1   = (u16*)(ws + OFF_WP1);
  u16*   in8   = (u16*)(ws + OFF_IN8);

  // output 0 is an exact copy of `data`
  hipMemcpyAsync(d_out, data, (size_t)NPIX3 * 4, hipMemcpyDeviceToDevice, stream);

  halo_kern<<<333, 256, 0, stream>>>(A0, A1, in8, dpad);
  repack_kern<<<1034, 256, 0, stream>>>(w_blk1, w_blk2, w_out, b_blk1, b_blk2, b_out,
                                        w_first, wpack, bpack, wp1);
  padcopy_kern<<<1728, 256, 0, stream>>>(data, dpad);
  pad6_kern<<<576, 256, 0, stream>>>(d_est, in8);
  conv1_mfma<<<2304, 64, 0, stream>>>(in8, wp1, b_first, A0);

  for (int i = 0; i < 3; ++i) {
    conv_mfma<0><<<2304, 128, 0, stream>>>(A0, wpack + (size_t)(2 * i) * WSW,
                                           bpack + (2 * i) * 64, A1, nullptr);
    conv_mfma<1><<<2304, 128, 0, stream>>>(A1, wpack + (size_t)(2 * i + 1) * WSW,
                                           bpack + (2 * i + 1) * 64, A0, nullptr);
  }
  conv_mfma<2><<<2304, 128, 0, stream>>>(A0, wpack + (size_t)6 * WSW,
                                         bpack + 6 * 64, nullptr, corep);

  kpn_split<<<dim3(2304, 2), 64, 0, stream>>>(corep, dpad, (float*)d_out);
}

// Round 12
// 283.011 us; speedup vs baseline: 3.5331x; 1.1677x over previous
//
#include <hip/hip_runtime.h>
#include <hip/hip_bf16.h>
#include <utility>

typedef __attribute__((ext_vector_type(4))) float f32x4;
typedef __attribute__((ext_vector_type(8))) short bf16x8;
typedef __attribute__((ext_vector_type(4))) unsigned short u16x4;
typedef unsigned short u16;

constexpr int HH = 384, WW = 384;
constexpr int AWP = 386;               // padded activation width (+1 halo each side)
constexpr int ASTR = AWP * 64;         // elements per padded activation row
constexpr int NPIX = HH * WW;          // 147456
constexpr int NPIX3 = NPIX * 3;        // 442368 (one output tensor)
constexpr int DP = 398, DPLANE = DP * DP;  // data padded by 7 each side
constexpr size_t ACT_BYTES = (size_t)AWP * AWP * 64 * 2;  // 19,071,488
constexpr int WSW = 72 * 512;          // swizzled weights per conv: 72 iters * 64 lanes * 8
constexpr int WP1N = 12 * 512;         // conv1 swizzled weights (K=96)

__device__ __forceinline__ u16 f2bf(float f) {
  union { __hip_bfloat16 h; u16 u; } v; v.h = __float2bfloat16(f); return v.u;
}
__device__ __forceinline__ float bf2f(u16 u) {
  union { float f; unsigned int i; } v; v.i = ((unsigned int)u) << 16; return v.f;
}

// ---------------- weight/bias repack ----------------
// wpack: 7 convs, A-frag order: iter=(tap*2+ich)*4+m; oc=m*16+(lane&15); ic=ich*32+(lane>>4)*8+j
// wp1: conv1 (6ic, K=96): iter=kb*4+m; oc=m*16+(lane&15); k=kb*32+(lane>>4)*8+j; tap=k/8, ic=k%8
__global__ void repack_kern(const float* __restrict__ w1, const float* __restrict__ w2,
                            const float* __restrict__ wo, const float* __restrict__ b1,
                            const float* __restrict__ b2, const float* __restrict__ bo,
                            const float* __restrict__ wf,
                            u16* __restrict__ wpack, float* __restrict__ bpack,
                            u16* __restrict__ wp1)
{
  const int idx = blockIdx.x * 256 + threadIdx.x;
  constexpr int NW = 7 * WSW;
  if (idx < NW) {
    const int c = idx / WSW;
    const int r = idx % WSW;
    const int iter = r / 512;
    const int lane = (r % 512) / 8;
    const int j = r % 8;
    const int tap = iter >> 3;
    const int ich = (iter >> 2) & 1;
    const int m = iter & 3;
    const int oc = m * 16 + (lane & 15);
    const int ic = ich * 32 + (lane >> 4) * 8 + j;
    float v;
    if (c < 6) {
      const float* s = (c & 1) ? w2 : w1;
      v = s[(((c >> 1) * 64 + oc) * 64 + ic) * 9 + tap];
    } else {
      v = (oc < 35) ? wo[(oc * 64 + ic) * 9 + tap] : 0.f;
    }
    wpack[idx] = f2bf(v);
  } else if (idx < NW + 448) {
    const int t = idx - NW;
    const int c = t / 64, oc = t % 64;
    float v;
    if (c < 6) v = ((c & 1) ? b2 : b1)[(c >> 1) * 64 + oc];
    else v = (oc < 35) ? bo[oc] : 0.f;
    bpack[t] = v;
  } else if (idx < NW + 448 + WP1N) {
    const int t = idx - NW - 448;
    const int iter = t / 512;
    const int lane = (t % 512) / 8;
    const int j = t % 8;
    const int m = iter & 3;
    const int kb = iter >> 2;
    const int oc = m * 16 + (lane & 15);
    const int k = kb * 32 + (lane >> 4) * 8 + j;
    const int tap = k >> 3, ic = k & 7;
    const float v = (tap < 9 && ic < 6) ? wf[oc * 54 + ic * 9 + tap] : 0.f;
    wp1[t] = f2bf(v);
  }
}

// ---------------- halo clear: only the border bytes (replaces 42MB of memsets) ----------------
__global__ void halo_kern(u16* __restrict__ A0, u16* __restrict__ A1,
                          u16* __restrict__ in8, float* __restrict__ dpad)
{
  const int idx = blockIdx.x * 256 + threadIdx.x;
  if (idx < 49280) {                       // A0/A1 border: 1540 px * 16 u16x4 each
    u16* buf = (idx < 24640) ? A0 : A1;
    const int t = (idx < 24640) ? idx : idx - 24640;
    const int pos = t >> 4, q = t & 15;
    int y, x;
    if (pos < 386) { y = 0; x = pos; }
    else if (pos < 772) { y = 385; x = pos - 386; }
    else if (pos < 1156) { y = pos - 772 + 1; x = 0; }
    else { y = pos - 1156 + 1; x = 385; }
    *(u16x4*)(buf + ((size_t)y * AWP + x) * 64 + q * 4) = u16x4{0, 0, 0, 0};
  } else if (idx < 49280 + 3080) {         // in8 border: 1540 px * 2 u16x4
    const int t = idx - 49280;
    const int pos = t >> 1, q = t & 1;
    int y, x;
    if (pos < 386) { y = 0; x = pos; }
    else if (pos < 772) { y = 385; x = pos - 386; }
    else if (pos < 1156) { y = pos - 772 + 1; x = 0; }
    else { y = pos - 1156 + 1; x = 385; }
    *(u16x4*)(in8 + ((size_t)y * AWP + x) * 8 + q * 4) = u16x4{0, 0, 0, 0};
  } else if (idx < 49280 + 3080 + 32844) { // dpad border width 7, 3 ch
    const int t = idx - 52360;
    const int c = t / 10948, r = t % 10948;
    int y, x;
    if (r < 2786) { y = r / 398; x = r % 398; }
    else if (r < 5572) { const int rr = r - 2786; y = 391 + rr / 398; x = rr % 398; }
    else { const int rr = r - 5572; y = 7 + rr / 14; const int k = rr % 14; x = (k < 7) ? k : 384 + k; }
    dpad[(size_t)c * DPLANE + (size_t)y * DP + x] = 0.f;
  }
}

// ---------------- pad-copy data (fp32, halo 7) ----------------
__global__ void padcopy_kern(const float* __restrict__ data, float* __restrict__ dpad)
{
  const int idx = blockIdx.x * 256 + threadIdx.x;  // exactly 442368 threads
  const int c = idx / NPIX, r = idx % NPIX;
  const int y = r / WW, x = r % WW;
  dpad[c * DPLANE + (y + 7) * DP + (x + 7)] = data[idx];
}

// ---------------- pad data_with_est to NHWC8 bf16 (halo 1, ic 6->8 zero) ----------------
__global__ void pad6_kern(const float* __restrict__ din, u16* __restrict__ in8)
{
  const int px = blockIdx.x * 256 + threadIdx.x;   // 576*256 = NPIX exactly
  const int y = px / WW, x = px % WW;
  u16 vals[8];
  #pragma unroll
  for (int ic = 0; ic < 6; ++ic) vals[ic] = f2bf(din[ic * NPIX + px]);
  vals[6] = 0; vals[7] = 0;
  u16* o = in8 + ((size_t)(y + 1) * AWP + (x + 1)) * 8;
  *(u16x4*)(o) = u16x4{vals[0], vals[1], vals[2], vals[3]};
  *(u16x4*)(o + 4) = u16x4{vals[4], vals[5], vals[6], vals[7]};
}

// ---------------- conv1 via MFMA: 8ch NHWC bf16 -> 64, K=96 ----------------
__global__ __launch_bounds__(64)
void conv1_mfma(const u16* __restrict__ in8, const u16* __restrict__ wp,
                const float* __restrict__ bias, u16* __restrict__ outb)
{
  const int lane = threadIdx.x;
  const int l15 = lane & 15, g8 = lane >> 4;
  // XCD swizzle: 2304 = 8 * 288
  const int bid = blockIdx.x;
  const int sw = (bid & 7) * 288 + (bid >> 3);
  const int y = sw / 6;
  const int x0 = (sw % 6) * 64;

  f32x4 acc[4][4];
  #pragma unroll
  for (int m = 0; m < 4; ++m)
    #pragma unroll
    for (int n = 0; n < 4; ++n)
      acc[m][n] = f32x4{0.f, 0.f, 0.f, 0.f};

  #pragma unroll
  for (int kb = 0; kb < 3; ++kb) {
    const int tap = kb * 4 + g8;
    const int vt = tap < 9 ? tap : 0;                // dup tap0 for pad (weights are 0)
    const int kr = vt / 3, kc = vt % 3;
    const u16* inr = in8 + ((size_t)(y + kr) * AWP + x0 + kc) * 8;
    bf16x8 a[4], b[4];
    #pragma unroll
    for (int m = 0; m < 4; ++m)
      a[m] = *(const bf16x8*)(wp + (kb * 4 + m) * 512 + lane * 8);
    #pragma unroll
    for (int n = 0; n < 4; ++n)
      b[n] = *(const bf16x8*)(inr + (size_t)(n * 16 + l15) * 8);
    #pragma unroll
    for (int m = 0; m < 4; ++m)
      #pragma unroll
      for (int n = 0; n < 4; ++n)
        acc[m][n] = __builtin_amdgcn_mfma_f32_16x16x32_bf16(a[m], b[n], acc[m][n], 0, 0, 0);
  }

  const int oc_lo = g8 * 4;
  #pragma unroll
  for (int m = 0; m < 4; ++m) {
    const int oc0 = m * 16 + oc_lo;
    const f32x4 bv = *(const f32x4*)(bias + oc0);
    #pragma unroll
    for (int n = 0; n < 4; ++n) {
      const int px = x0 + n * 16 + l15;
      const f32x4 v = acc[m][n] + bv;
      u16x4 s;
      #pragma unroll
      for (int j = 0; j < 4; ++j) s[j] = f2bf(v[j]);
      *(u16x4*)(outb + ((size_t)(y + 1) * AWP + (px + 1)) * 64 + oc0) = s;
    }
  }
}

// ---------------- MFMA implicit-GEMM 3x3 conv, K-split across 2 waves (R9 known-good) ----------------
// MODE 0: +bias, relu; MODE 1: +bias,+residual; MODE 2: +bias, f32 planar (oc<35)
template<int MODE>
__global__ __launch_bounds__(128, 3)
void conv_mfma(const u16* __restrict__ in, const u16* __restrict__ wp,
               const float* __restrict__ bias, u16* __restrict__ outb,
               float* __restrict__ outf)
{
  __shared__ float red[64 * 64];                   // 16 KB: wave1's partial acc
  const int lane = threadIdx.x & 63;
  const int wv = threadIdx.x >> 6;                 // K-half: ich = wv
  const int l15 = lane & 15, g8 = lane >> 4;
  // XCD-aware swizzle: 2304 blocks = 8 XCDs * 288 (48 rows * 6 col-blocks each)
  const int bid = blockIdx.x;
  const int sw = (bid & 7) * 288 + (bid >> 3);
  const int y = sw / 6;
  const int x0 = (sw % 6) * 64;
  const int ich = wv;

  f32x4 acc[4][4];
  #pragma unroll
  for (int m = 0; m < 4; ++m)
    #pragma unroll
    for (int n = 0; n < 4; ++n)
      acc[m][n] = f32x4{0.f, 0.f, 0.f, 0.f};

  #pragma unroll
  for (int tap = 0; tap < 9; ++tap) {
    const int kr = tap / 3, kc = tap % 3;
    const u16* inr = in + (size_t)(y + kr) * ASTR + (size_t)(x0 + kc) * 64;
    const u16* wpi = wp + ((tap * 2 + ich) * 4) * 512 + lane * 8;  // coalesced A-frags
    bf16x8 a[4], b[4];
    #pragma unroll
    for (int m = 0; m < 4; ++m)
      a[m] = *(const bf16x8*)(wpi + m * 512);
    #pragma unroll
    for (int n = 0; n < 4; ++n)
      b[n] = *(const bf16x8*)(inr + (size_t)(n * 16 + l15) * 64 + ich * 32 + g8 * 8);
    #pragma unroll
    for (int m = 0; m < 4; ++m)
      #pragma unroll
      for (int n = 0; n < 4; ++n)
        acc[m][n] = __builtin_amdgcn_mfma_f32_16x16x32_bf16(a[m], b[n], acc[m][n], 0, 0, 0);
  }

  if (wv == 1) {
    #pragma unroll
    for (int m = 0; m < 4; ++m)
      #pragma unroll
      for (int n = 0; n < 4; ++n)
        *(f32x4*)(red + (m * 4 + n) * 256 + lane * 4) = acc[m][n];
  }
  __syncthreads();
  if (wv == 1) return;

  const int oc_lo = g8 * 4;
  #pragma unroll
  for (int m = 0; m < 4; ++m) {
    const int oc0 = m * 16 + oc_lo;                  // D row = (lane>>4)*4 + reg
    const f32x4 bv = *(const f32x4*)(bias + oc0);
    #pragma unroll
    for (int n = 0; n < 4; ++n) {
      const int px = x0 + n * 16 + l15;              // D col = lane&15
      f32x4 v = acc[m][n] + *(const f32x4*)(red + (m * 4 + n) * 256 + lane * 4) + bv;
      if constexpr (MODE == 0) {
        #pragma unroll
        for (int j = 0; j < 4; ++j) v[j] = v[j] > 0.f ? v[j] : 0.f;
      }
      if constexpr (MODE == 1) {
        const u16x4 r = *(const u16x4*)(outb + ((size_t)(y + 1) * AWP + (px + 1)) * 64 + oc0);
        #pragma unroll
        for (int j = 0; j < 4; ++j) v[j] += bf2f(r[j]);
      }
      if constexpr (MODE <= 1) {
        u16x4 s;
        #pragma unroll
        for (int j = 0; j < 4; ++j) s[j] = f2bf(v[j]);
        *(u16x4*)(outb + ((size_t)(y + 1) * AWP + (px + 1)) * 64 + oc0) = s;
      } else {
        #pragma unroll
        for (int j = 0; j < 4; ++j) {
          const int oc = oc0 + j;
          if (oc < 35) outf[(size_t)oc * NPIX + (size_t)y * WW + px] = v[j];
        }
      }
    }
  }
}

// ---------------- KPN apply: template-fold sweep (guaranteed static indexing) ----------------
constexpr int isqrt_(int d2) { int li = 0; while ((li + 1) * (li + 1) <= d2) ++li; return li; }
constexpr double csqrt_(double x) {
  double g = x < 1.0 ? 1.0 : x;
  for (int i = 0; i < 60; ++i) g = 0.5 * (g + x / g);
  return g;
}
constexpr int KOFFS[7] = {0, 2, 5, 9, 14, 20, 27};

template<int SEC0, int NSEC, int CKN, int A, int B, int T>
__device__ __forceinline__ void kpn_sec_one(const float (&g)[3], const float (&ck)[CKN],
                                            float (&s)[NSEC], float (&p)[NSEC][3])
{
  constexpr int WIDE = SEC0 + T + 2;
  if constexpr (A < WIDE && B < WIDE) {
    constexpr int d2 = A * A + B * B;
    constexpr int li = isqrt_(d2);
    constexpr bool exact = (li * li == d2);
    constexpr int hraw = exact ? li : li + 1;
    constexpr float dd = (float)csqrt_((double)d2);
    constexpr float wlo = exact ? 1.0f : ((float)hraw - dd);
    constexpr float whi = exact ? 0.0f : (dd - (float)li);
    constexpr float mult = ((A > 0) ? 2.0f : 1.0f) * ((B > 0) ? 2.0f : 1.0f);
    constexpr int lidx = li < WIDE - 1 ? li : WIDE - 1;
    constexpr int hidx = hraw < WIDE - 1 ? hraw : WIDE - 1;
    constexpr bool msk = d2 <= (WIDE - 1) * (WIDE - 1);
    constexpr int cb = KOFFS[SEC0 + T] - KOFFS[SEC0];
    float e;
    if constexpr (msk) e = __expf(wlo * ck[cb + lidx] + whi * ck[cb + hidx]);
    else e = 1.0f;                                   // masked: logit 0, still in softmax
    s[T] += mult * e;
    p[T][0] += e * g[0];
    p[T][1] += e * g[1];
    p[T][2] += e * g[2];
  }
}

template<int SEC0, int NSEC, int CKN, int A, int B, int... Ts>
__device__ __forceinline__ void kpn_secs(std::integer_sequence<int, Ts...>,
                                         const float (&g)[3], const float (&ck)[CKN],
                                         float (&s)[NSEC], float (&p)[NSEC][3])
{
  (kpn_sec_one<SEC0, NSEC, CKN, A, B, Ts>(g, ck, s, p), ...);
}

template<int SEC0, int NSEC, int CKN, int WMAX, int C>
__device__ __forceinline__ void kpn_cell(const float* __restrict__ base,
                                         const float (&ck)[CKN],
                                         float (&s)[NSEC], float (&p)[NSEC][3])
{
  constexpr int A = C / WMAX, B = C % WMAX;
  float g[3];
  #pragma unroll
  for (int c = 0; c < 3; ++c) {
    const float* bc = base + c * DPLANE;
    float v = bc[A * DP + B];
    if constexpr (B > 0) v += bc[A * DP - B];
    if constexpr (A > 0) v += bc[-A * DP + B];
    if constexpr (A > 0 && B > 0) v += bc[-A * DP - B];
    g[c] = v;
  }
  kpn_secs<SEC0, NSEC, CKN, A, B>(std::make_integer_sequence<int, NSEC>{}, g, ck, s, p);
}

template<int SEC0, int NSEC, int CKN, int WMAX, int... Cs>
__device__ __forceinline__ void kpn_cells(std::integer_sequence<int, Cs...>,
                                          const float* __restrict__ base,
                                          const float (&ck)[CKN],
                                          float (&s)[NSEC], float (&p)[NSEC][3])
{
  (kpn_cell<SEC0, NSEC, CKN, WMAX, Cs>(base, ck, s, p), ...);
}

template<int SEC0, int NSEC>
__device__ __forceinline__ void kpn_grp_body(const float* __restrict__ corep,
                                             const float* __restrict__ dpad,
                                             float* __restrict__ out)
{
  constexpr int WMAX = SEC0 + NSEC + 1;          // widest WIDE in this group
  constexpr int CK0 = KOFFS[SEC0];
  constexpr int CKN = KOFFS[SEC0 + NSEC - 1] + (SEC0 + NSEC + 1) - CK0;

  // XCD-contiguous band swizzle: 576 = 8 XCDs * 72 blocks (48 rows each) ->
  // per-XCD corep slice (~2.6MB) + dpad band fit the private 4MB L2.
  const int bid = blockIdx.x;
  const int sw = (bid & 7) * 72 + (bid >> 3);
  const int px = sw * 256 + threadIdx.x;              // 576*256 = NPIX exactly
  const int y = px / WW, x = px % WW;
  const float* base = dpad + (size_t)(y + 7) * DP + (x + 7);

  float ck[CKN];
  #pragma unroll
  for (int i = 0; i < CKN; ++i) ck[i] = fabsf(corep[(size_t)(CK0 + i) * NPIX + px]);

  float s[NSEC], p[NSEC][3];
  #pragma unroll
  for (int k = 0; k < NSEC; ++k) { s[k] = 0.f; p[k][0] = 0.f; p[k][1] = 0.f; p[k][2] = 0.f; }

  kpn_cells<SEC0, NSEC, CKN, WMAX>(std::make_integer_sequence<int, WMAX * WMAX>{},
                                   base, ck, s, p);

  #pragma unroll
  for (int t = 0; t < NSEC; ++t) {
    const float inv = 1.f / s[t];
    float* o = out + (size_t)(SEC0 + t + 1) * NPIX3 + px;
    o[0] = p[t][0] * inv;
    o[NPIX] = p[t][1] * inv;
    o[2 * NPIX] = p[t][2] * inv;
  }
}

__global__ __launch_bounds__(256, 4)
void kpn_split(const float* __restrict__ corep, const float* __restrict__ dpad,
               float* __restrict__ out)
{
  if (blockIdx.y == 0) kpn_grp_body<0, 5>(corep, dpad, out);   // WIDE 2-6
  else                 kpn_grp_body<5, 2>(corep, dpad, out);   // WIDE 7-8
}

// ---------------- launch ----------------
extern "C" void kernel_launch(void* const* d_in, const int* in_sizes, int n_in,
                              void* d_out, int out_size, void* d_ws, size_t ws_size,
                              hipStream_t stream)
{
  const float* d_est   = (const float*)d_in[0];
  const float* data    = (const float*)d_in[1];
  const float* w_first = (const float*)d_in[2];
  const float* b_first = (const float*)d_in[3];
  const float* w_blk1  = (const float*)d_in[4];
  const float* b_blk1  = (const float*)d_in[5];
  const float* w_blk2  = (const float*)d_in[6];
  const float* b_blk2  = (const float*)d_in[7];
  const float* w_out   = (const float*)d_in[8];
  const float* b_out   = (const float*)d_in[9];

  char* ws = (char*)d_ws;
  const size_t OFF_A1    = ACT_BYTES;
  const size_t OFF_CORE  = 2 * ACT_BYTES;
  const size_t OFF_DPAD  = OFF_CORE + (size_t)35 * NPIX * 4;
  const size_t OFF_WPACK = OFF_DPAD + (size_t)3 * DPLANE * 4;
  const size_t OFF_BPACK = OFF_WPACK + (size_t)7 * WSW * 2;
  const size_t OFF_WP1   = OFF_BPACK + 448 * 4;
  const size_t OFF_IN8   = OFF_WP1 + (size_t)WP1N * 2;

  u16*   A0    = (u16*)(ws);
  u16*   A1    = (u16*)(ws + OFF_A1);
  float* corep = (float*)(ws + OFF_CORE);
  float* dpad  = (float*)(ws + OFF_DPAD);
  u16*   wpack = (u16*)(ws + OFF_WPACK);
  float* bpack = (float*)(ws + OFF_BPACK);
  u16*   wp1   = (u16*)(ws + OFF_WP1);
  u16*   in8   = (u16*)(ws + OFF_IN8);

  // output 0 is an exact copy of `data`
  hipMemcpyAsync(d_out, data, (size_t)NPIX3 * 4, hipMemcpyDeviceToDevice, stream);

  halo_kern<<<333, 256, 0, stream>>>(A0, A1, in8, dpad);
  repack_kern<<<1034, 256, 0, stream>>>(w_blk1, w_blk2, w_out, b_blk1, b_blk2, b_out,
                                        w_first, wpack, bpack, wp1);
  padcopy_kern<<<1728, 256, 0, stream>>>(data, dpad);
  pad6_kern<<<576, 256, 0, stream>>>(d_est, in8);
  conv1_mfma<<<2304, 64, 0, stream>>>(in8, wp1, b_first, A0);

  for (int i = 0; i < 3; ++i) {
    conv_mfma<0><<<2304, 128, 0, stream>>>(A0, wpack + (size_t)(2 * i) * WSW,
                                           bpack + (2 * i) * 64, A1, nullptr);
    conv_mfma<1><<<2304, 128, 0, stream>>>(A1, wpack + (size_t)(2 * i + 1) * WSW,
                                           bpack + (2 * i + 1) * 64, A0, nullptr);
  }
  conv_mfma<2><<<2304, 128, 0, stream>>>(A0, wpack + (size_t)6 * WSW,
                                         bpack + 6 * 64, nullptr, corep);

  kpn_split<<<dim3(576, 2), 256, 0, stream>>>(corep, dpad, (float*)d_out);
}

// Round 13
// 282.592 us; speedup vs baseline: 3.5384x; 1.0015x over previous
//
#include <hip/hip_runtime.h>
#include <hip/hip_bf16.h>
#include <utility>

typedef __attribute__((ext_vector_type(4))) float f32x4;
typedef __attribute__((ext_vector_type(8))) short bf16x8;
typedef __attribute__((ext_vector_type(4))) unsigned short u16x4;
typedef unsigned short u16;

constexpr int HH = 384, WW = 384;
constexpr int AWP = 386;               // padded activation width (+1 halo each side)
constexpr int ASTR = AWP * 64;         // elements per padded activation row
constexpr int NPIX = HH * WW;          // 147456
constexpr int NPIX3 = NPIX * 3;        // 442368 (one output tensor)
constexpr int DP = 398, DPLANE = DP * DP;  // data padded by 7 each side
constexpr size_t ACT_BYTES = (size_t)AWP * AWP * 64 * 2;  // 19,071,488
constexpr int WSW = 72 * 512;          // swizzled weights per conv: 72 iters * 64 lanes * 8
constexpr int WP1N = 12 * 512;         // conv1 swizzled weights (K=96)

__device__ __forceinline__ u16 f2bf(float f) {
  union { __hip_bfloat16 h; u16 u; } v; v.h = __float2bfloat16(f); return v.u;
}
__device__ __forceinline__ float bf2f(u16 u) {
  union { float f; unsigned int i; } v; v.i = ((unsigned int)u) << 16; return v.f;
}

// ---------------- weight/bias repack ----------------
// wpack: 7 convs, A-frag order: iter=(tap*2+ich)*4+m; oc=m*16+(lane&15); ic=ich*32+(lane>>4)*8+j
// wp1: conv1 (6ic, K=96): iter=kb*4+m; oc=m*16+(lane&15); k=kb*32+(lane>>4)*8+j; tap=k/8, ic=k%8
__global__ void repack_kern(const float* __restrict__ w1, const float* __restrict__ w2,
                            const float* __restrict__ wo, const float* __restrict__ b1,
                            const float* __restrict__ b2, const float* __restrict__ bo,
                            const float* __restrict__ wf,
                            u16* __restrict__ wpack, float* __restrict__ bpack,
                            u16* __restrict__ wp1)
{
  const int idx = blockIdx.x * 256 + threadIdx.x;
  constexpr int NW = 7 * WSW;
  if (idx < NW) {
    const int c = idx / WSW;
    const int r = idx % WSW;
    const int iter = r / 512;
    const int lane = (r % 512) / 8;
    const int j = r % 8;
    const int tap = iter >> 3;
    const int ich = (iter >> 2) & 1;
    const int m = iter & 3;
    const int oc = m * 16 + (lane & 15);
    const int ic = ich * 32 + (lane >> 4) * 8 + j;
    float v;
    if (c < 6) {
      const float* s = (c & 1) ? w2 : w1;
      v = s[(((c >> 1) * 64 + oc) * 64 + ic) * 9 + tap];
    } else {
      v = (oc < 35) ? wo[(oc * 64 + ic) * 9 + tap] : 0.f;
    }
    wpack[idx] = f2bf(v);
  } else if (idx < NW + 448) {
    const int t = idx - NW;
    const int c = t / 64, oc = t % 64;
    float v;
    if (c < 6) v = ((c & 1) ? b2 : b1)[(c >> 1) * 64 + oc];
    else v = (oc < 35) ? bo[oc] : 0.f;
    bpack[t] = v;
  } else if (idx < NW + 448 + WP1N) {
    const int t = idx - NW - 448;
    const int iter = t / 512;
    const int lane = (t % 512) / 8;
    const int j = t % 8;
    const int m = iter & 3;
    const int kb = iter >> 2;
    const int oc = m * 16 + (lane & 15);
    const int k = kb * 32 + (lane >> 4) * 8 + j;
    const int tap = k >> 3, ic = k & 7;
    const float v = (tap < 9 && ic < 6) ? wf[oc * 54 + ic * 9 + tap] : 0.f;
    wp1[t] = f2bf(v);
  }
}

// ---------------- halo clear: only the border bytes (replaces 42MB of memsets) ----------------
__global__ void halo_kern(u16* __restrict__ A0, u16* __restrict__ A1,
                          u16* __restrict__ in8, float* __restrict__ dpad)
{
  const int idx = blockIdx.x * 256 + threadIdx.x;
  if (idx < 49280) {                       // A0/A1 border: 1540 px * 16 u16x4 each
    u16* buf = (idx < 24640) ? A0 : A1;
    const int t = (idx < 24640) ? idx : idx - 24640;
    const int pos = t >> 4, q = t & 15;
    int y, x;
    if (pos < 386) { y = 0; x = pos; }
    else if (pos < 772) { y = 385; x = pos - 386; }
    else if (pos < 1156) { y = pos - 772 + 1; x = 0; }
    else { y = pos - 1156 + 1; x = 385; }
    *(u16x4*)(buf + ((size_t)y * AWP + x) * 64 + q * 4) = u16x4{0, 0, 0, 0};
  } else if (idx < 49280 + 3080) {         // in8 border: 1540 px * 2 u16x4
    const int t = idx - 49280;
    const int pos = t >> 1, q = t & 1;
    int y, x;
    if (pos < 386) { y = 0; x = pos; }
    else if (pos < 772) { y = 385; x = pos - 386; }
    else if (pos < 1156) { y = pos - 772 + 1; x = 0; }
    else { y = pos - 1156 + 1; x = 385; }
    *(u16x4*)(in8 + ((size_t)y * AWP + x) * 8 + q * 4) = u16x4{0, 0, 0, 0};
  } else if (idx < 49280 + 3080 + 32844) { // dpad border width 7, 3 ch
    const int t = idx - 52360;
    const int c = t / 10948, r = t % 10948;
    int y, x;
    if (r < 2786) { y = r / 398; x = r % 398; }
    else if (r < 5572) { const int rr = r - 2786; y = 391 + rr / 398; x = rr % 398; }
    else { const int rr = r - 5572; y = 7 + rr / 14; const int k = rr % 14; x = (k < 7) ? k : 384 + k; }
    dpad[(size_t)c * DPLANE + (size_t)y * DP + x] = 0.f;
  }
}

// ---------------- pad-copy data (fp32, halo 7) ----------------
__global__ void padcopy_kern(const float* __restrict__ data, float* __restrict__ dpad)
{
  const int idx = blockIdx.x * 256 + threadIdx.x;  // exactly 442368 threads
  const int c = idx / NPIX, r = idx % NPIX;
  const int y = r / WW, x = r % WW;
  dpad[c * DPLANE + (y + 7) * DP + (x + 7)] = data[idx];
}

// ---------------- pad data_with_est to NHWC8 bf16 (halo 1, ic 6->8 zero) ----------------
__global__ void pad6_kern(const float* __restrict__ din, u16* __restrict__ in8)
{
  const int px = blockIdx.x * 256 + threadIdx.x;   // 576*256 = NPIX exactly
  const int y = px / WW, x = px % WW;
  u16 vals[8];
  #pragma unroll
  for (int ic = 0; ic < 6; ++ic) vals[ic] = f2bf(din[ic * NPIX + px]);
  vals[6] = 0; vals[7] = 0;
  u16* o = in8 + ((size_t)(y + 1) * AWP + (x + 1)) * 8;
  *(u16x4*)(o) = u16x4{vals[0], vals[1], vals[2], vals[3]};
  *(u16x4*)(o + 4) = u16x4{vals[4], vals[5], vals[6], vals[7]};
}

// ---------------- conv1 via MFMA: 8ch NHWC bf16 -> 64, K=96 ----------------
__global__ __launch_bounds__(64)
void conv1_mfma(const u16* __restrict__ in8, const u16* __restrict__ wp,
                const float* __restrict__ bias, u16* __restrict__ outb)
{
  const int lane = threadIdx.x;
  const int l15 = lane & 15, g8 = lane >> 4;
  // XCD swizzle: 2304 = 8 * 288
  const int bid = blockIdx.x;
  const int sw = (bid & 7) * 288 + (bid >> 3);
  const int y = sw / 6;
  const int x0 = (sw % 6) * 64;

  f32x4 acc[4][4];
  #pragma unroll
  for (int m = 0; m < 4; ++m)
    #pragma unroll
    for (int n = 0; n < 4; ++n)
      acc[m][n] = f32x4{0.f, 0.f, 0.f, 0.f};

  #pragma unroll
  for (int kb = 0; kb < 3; ++kb) {
    const int tap = kb * 4 + g8;
    const int vt = tap < 9 ? tap : 0;                // dup tap0 for pad (weights are 0)
    const int kr = vt / 3, kc = vt % 3;
    const u16* inr = in8 + ((size_t)(y + kr) * AWP + x0 + kc) * 8;
    bf16x8 a[4], b[4];
    #pragma unroll
    for (int m = 0; m < 4; ++m)
      a[m] = *(const bf16x8*)(wp + (kb * 4 + m) * 512 + lane * 8);
    #pragma unroll
    for (int n = 0; n < 4; ++n)
      b[n] = *(const bf16x8*)(inr + (size_t)(n * 16 + l15) * 8);
    #pragma unroll
    for (int m = 0; m < 4; ++m)
      #pragma unroll
      for (int n = 0; n < 4; ++n)
        acc[m][n] = __builtin_amdgcn_mfma_f32_16x16x32_bf16(a[m], b[n], acc[m][n], 0, 0, 0);
  }

  const int oc_lo = g8 * 4;
  #pragma unroll
  for (int m = 0; m < 4; ++m) {
    const int oc0 = m * 16 + oc_lo;
    const f32x4 bv = *(const f32x4*)(bias + oc0);
    #pragma unroll
    for (int n = 0; n < 4; ++n) {
      const int px = x0 + n * 16 + l15;
      const f32x4 v = acc[m][n] + bv;
      u16x4 s;
      #pragma unroll
      for (int j = 0; j < 4; ++j) s[j] = f2bf(v[j]);
      *(u16x4*)(outb + ((size_t)(y + 1) * AWP + (px + 1)) * 64 + oc0) = s;
    }
  }
}

// ---------------- MFMA implicit-GEMM 3x3 conv, K-split across 2 waves ----------------
// Low-VGPR variant: a loaded one fragment at a time -> live set ~105 regs,
// __launch_bounds__(128,4) => 4 waves/SIMD to hide L2 latency.
// MODE 0: +bias, relu; MODE 1: +bias,+residual; MODE 2: +bias, f32 planar (oc<35)
template<int MODE>
__global__ __launch_bounds__(128, 4)
void conv_mfma(const u16* __restrict__ in, const u16* __restrict__ wp,
               const float* __restrict__ bias, u16* __restrict__ outb,
               float* __restrict__ outf)
{
  __shared__ float red[64 * 64];                   // 16 KB: wave1's partial acc
  const int lane = threadIdx.x & 63;
  const int wv = threadIdx.x >> 6;                 // K-half: ich = wv
  const int l15 = lane & 15, g8 = lane >> 4;
  // XCD-aware swizzle: 2304 blocks = 8 XCDs * 288 (48 rows * 6 col-blocks each)
  const int bid = blockIdx.x;
  const int sw = (bid & 7) * 288 + (bid >> 3);
  const int y = sw / 6;
  const int x0 = (sw % 6) * 64;
  const int ich = wv;

  f32x4 acc[4][4];
  #pragma unroll
  for (int m = 0; m < 4; ++m)
    #pragma unroll
    for (int n = 0; n < 4; ++n)
      acc[m][n] = f32x4{0.f, 0.f, 0.f, 0.f};

  #pragma unroll
  for (int tap = 0; tap < 9; ++tap) {
    const int kr = tap / 3, kc = tap % 3;
    const u16* inr = in + (size_t)(y + kr) * ASTR + (size_t)(x0 + kc) * 64;
    const u16* wpi = wp + ((tap * 2 + ich) * 4) * 512 + lane * 8;  // coalesced A-frags
    bf16x8 b[4];
    #pragma unroll
    for (int n = 0; n < 4; ++n)
      b[n] = *(const bf16x8*)(inr + (size_t)(n * 16 + l15) * 64 + ich * 32 + g8 * 8);
    #pragma unroll
    for (int m = 0; m < 4; ++m) {
      const bf16x8 a = *(const bf16x8*)(wpi + m * 512);
      #pragma unroll
      for (int n = 0; n < 4; ++n)
        acc[m][n] = __builtin_amdgcn_mfma_f32_16x16x32_bf16(a, b[n], acc[m][n], 0, 0, 0);
    }
  }

  if (wv == 1) {
    #pragma unroll
    for (int m = 0; m < 4; ++m)
      #pragma unroll
      for (int n = 0; n < 4; ++n)
        *(f32x4*)(red + (m * 4 + n) * 256 + lane * 4) = acc[m][n];
  }
  __syncthreads();
  if (wv == 1) return;

  const int oc_lo = g8 * 4;
  #pragma unroll
  for (int m = 0; m < 4; ++m) {
    const int oc0 = m * 16 + oc_lo;                  // D row = (lane>>4)*4 + reg
    const f32x4 bv = *(const f32x4*)(bias + oc0);
    #pragma unroll
    for (int n = 0; n < 4; ++n) {
      const int px = x0 + n * 16 + l15;              // D col = lane&15
      f32x4 v = acc[m][n] + *(const f32x4*)(red + (m * 4 + n) * 256 + lane * 4) + bv;
      if constexpr (MODE == 0) {
        #pragma unroll
        for (int j = 0; j < 4; ++j) v[j] = v[j] > 0.f ? v[j] : 0.f;
      }
      if constexpr (MODE == 1) {
        const u16x4 r = *(const u16x4*)(outb + ((size_t)(y + 1) * AWP + (px + 1)) * 64 + oc0);
        #pragma unroll
        for (int j = 0; j < 4; ++j) v[j] += bf2f(r[j]);
      }
      if constexpr (MODE <= 1) {
        u16x4 s;
        #pragma unroll
        for (int j = 0; j < 4; ++j) s[j] = f2bf(v[j]);
        *(u16x4*)(outb + ((size_t)(y + 1) * AWP + (px + 1)) * 64 + oc0) = s;
      } else {
        #pragma unroll
        for (int j = 0; j < 4; ++j) {
          const int oc = oc0 + j;
          if (oc < 35) outf[(size_t)oc * NPIX + (size_t)y * WW + px] = v[j];
        }
      }
    }
  }
}

// ---------------- KPN apply: template-fold sweep (guaranteed static indexing) ----------------
constexpr int isqrt_(int d2) { int li = 0; while ((li + 1) * (li + 1) <= d2) ++li; return li; }
constexpr double csqrt_(double x) {
  double g = x < 1.0 ? 1.0 : x;
  for (int i = 0; i < 60; ++i) g = 0.5 * (g + x / g);
  return g;
}
constexpr int KOFFS[7] = {0, 2, 5, 9, 14, 20, 27};

template<int SEC0, int NSEC, int CKN, int A, int B, int T>
__device__ __forceinline__ void kpn_sec_one(const float (&g)[3], const float (&ck)[CKN],
                                            float (&s)[NSEC], float (&p)[NSEC][3])
{
  constexpr int WIDE = SEC0 + T + 2;
  if constexpr (A < WIDE && B < WIDE) {
    constexpr int d2 = A * A + B * B;
    constexpr int li = isqrt_(d2);
    constexpr bool exact = (li * li == d2);
    constexpr int hraw = exact ? li : li + 1;
    constexpr float dd = (float)csqrt_((double)d2);
    constexpr float wlo = exact ? 1.0f : ((float)hraw - dd);
    constexpr float whi = exact ? 0.0f : (dd - (float)li);
    constexpr float mult = ((A > 0) ? 2.0f : 1.0f) * ((B > 0) ? 2.0f : 1.0f);
    constexpr int lidx = li < WIDE - 1 ? li : WIDE - 1;
    constexpr int hidx = hraw < WIDE - 1 ? hraw : WIDE - 1;
    constexpr bool msk = d2 <= (WIDE - 1) * (WIDE - 1);
    constexpr int cb = KOFFS[SEC0 + T] - KOFFS[SEC0];
    float e;
    if constexpr (msk) e = __expf(wlo * ck[cb + lidx] + whi * ck[cb + hidx]);
    else e = 1.0f;                                   // masked: logit 0, still in softmax
    s[T] += mult * e;
    p[T][0] += e * g[0];
    p[T][1] += e * g[1];
    p[T][2] += e * g[2];
  }
}

template<int SEC0, int NSEC, int CKN, int A, int B, int... Ts>
__device__ __forceinline__ void kpn_secs(std::integer_sequence<int, Ts...>,
                                         const float (&g)[3], const float (&ck)[CKN],
                                         float (&s)[NSEC], float (&p)[NSEC][3])
{
  (kpn_sec_one<SEC0, NSEC, CKN, A, B, Ts>(g, ck, s, p), ...);
}

template<int SEC0, int NSEC, int CKN, int WMAX, int C>
__device__ __forceinline__ void kpn_cell(const float* __restrict__ base,
                                         const float (&ck)[CKN],
                                         float (&s)[NSEC], float (&p)[NSEC][3])
{
  constexpr int A = C / WMAX, B = C % WMAX;
  float g[3];
  #pragma unroll
  for (int c = 0; c < 3; ++c) {
    const float* bc = base + c * DPLANE;
    float v = bc[A * DP + B];
    if constexpr (B > 0) v += bc[A * DP - B];
    if constexpr (A > 0) v += bc[-A * DP + B];
    if constexpr (A > 0 && B > 0) v += bc[-A * DP - B];
    g[c] = v;
  }
  kpn_secs<SEC0, NSEC, CKN, A, B>(std::make_integer_sequence<int, NSEC>{}, g, ck, s, p);
}

template<int SEC0, int NSEC, int CKN, int WMAX, int... Cs>
__device__ __forceinline__ void kpn_cells(std::integer_sequence<int, Cs...>,
                                          const float* __restrict__ base,
                                          const float (&ck)[CKN],
                                          float (&s)[NSEC], float (&p)[NSEC][3])
{
  (kpn_cell<SEC0, NSEC, CKN, WMAX, Cs>(base, ck, s, p), ...);
}

template<int SEC0, int NSEC>
__device__ __forceinline__ void kpn_grp_body(const float* __restrict__ corep,
                                             const float* __restrict__ dpad,
                                             float* __restrict__ out)
{
  constexpr int WMAX = SEC0 + NSEC + 1;          // widest WIDE in this group
  constexpr int CK0 = KOFFS[SEC0];
  constexpr int CKN = KOFFS[SEC0 + NSEC - 1] + (SEC0 + NSEC + 1) - CK0;

  // XCD-contiguous band swizzle: 576 = 8 XCDs * 72 blocks (48 rows each) ->
  // per-XCD corep slice (~2.6MB) + dpad band fit the private 4MB L2.
  const int bid = blockIdx.x;
  const int sw = (bid & 7) * 72 + (bid >> 3);
  const int px = sw * 256 + threadIdx.x;              // 576*256 = NPIX exactly
  const int y = px / WW, x = px % WW;
  const float* base = dpad + (size_t)(y + 7) * DP + (x + 7);

  float ck[CKN];
  #pragma unroll
  for (int i = 0; i < CKN; ++i) ck[i] = fabsf(corep[(size_t)(CK0 + i) * NPIX + px]);

  float s[NSEC], p[NSEC][3];
  #pragma unroll
  for (int k = 0; k < NSEC; ++k) { s[k] = 0.f; p[k][0] = 0.f; p[k][1] = 0.f; p[k][2] = 0.f; }

  kpn_cells<SEC0, NSEC, CKN, WMAX>(std::make_integer_sequence<int, WMAX * WMAX>{},
                                   base, ck, s, p);

  #pragma unroll
  for (int t = 0; t < NSEC; ++t) {
    const float inv = 1.f / s[t];
    float* o = out + (size_t)(SEC0 + t + 1) * NPIX3 + px;
    o[0] = p[t][0] * inv;
    o[NPIX] = p[t][1] * inv;
    o[2 * NPIX] = p[t][2] * inv;
  }
}

__global__ __launch_bounds__(256, 4)
void kpn_split(const float* __restrict__ corep, const float* __restrict__ dpad,
               float* __restrict__ out)
{
  if (blockIdx.y == 0) kpn_grp_body<0, 5>(corep, dpad, out);   // WIDE 2-6
  else                 kpn_grp_body<5, 2>(corep, dpad, out);   // WIDE 7-8
}

// ---------------- launch ----------------
extern "C" void kernel_launch(void* const* d_in, const int* in_sizes, int n_in,
                              void* d_out, int out_size, void* d_ws, size_t ws_size,
                              hipStream_t stream)
{
  const float* d_est   = (const float*)d_in[0];
  const float* data    = (const float*)d_in[1];
  const float* w_first = (const float*)d_in[2];
  const float* b_first = (const float*)d_in[3];
  const float* w_blk1  = (const float*)d_in[4];
  const float* b_blk1  = (const float*)d_in[5];
  const float* w_blk2  = (const float*)d_in[6];
  const float* b_blk2  = (const float*)d_in[7];
  const float* w_out   = (const float*)d_in[8];
  const float* b_out   = (const float*)d_in[9];

  char* ws = (char*)d_ws;
  const size_t OFF_A1    = ACT_BYTES;
  const size_t OFF_CORE  = 2 * ACT_BYTES;
  const size_t OFF_DPAD  = OFF_CORE + (size_t)35 * NPIX * 4;
  const size_t OFF_WPACK = OFF_DPAD + (size_t)3 * DPLANE * 4;
  const size_t OFF_BPACK = OFF_WPACK + (size_t)7 * WSW * 2;
  const size_t OFF_WP1   = OFF_BPACK + 448 * 4;
  const size_t OFF_IN8   = OFF_WP1 + (size_t)WP1N * 2;

  u16*   A0    = (u16*)(ws);
  u16*   A1    = (u16*)(ws + OFF_A1);
  float* corep = (float*)(ws + OFF_CORE);
  float* dpad  = (float*)(ws + OFF_DPAD);
  u16*   wpack = (u16*)(ws + OFF_WPACK);
  float* bpack = (float*)(ws + OFF_BPACK);
  u16*   wp1   = (u16*)(ws + OFF_WP1);
  u16*   in8   = (u16*)(ws + OFF_IN8);

  // output 0 is an exact copy of `data`
  hipMemcpyAsync(d_out, data, (size_t)NPIX3 * 4, hipMemcpyDeviceToDevice, stream);

  halo_kern<<<333, 256, 0, stream>>>(A0, A1, in8, dpad);
  repack_kern<<<1034, 256, 0, stream>>>(w_blk1, w_blk2, w_out, b_blk1, b_blk2, b_out,
                                        w_first, wpack, bpack, wp1);
  padcopy_kern<<<1728, 256, 0, stream>>>(data, dpad);
  pad6_kern<<<576, 256, 0, stream>>>(d_est, in8);
  conv1_mfma<<<2304, 64, 0, stream>>>(in8, wp1, b_first, A0);

  for (int i = 0; i < 3; ++i) {
    conv_mfma<0><<<2304, 128, 0, stream>>>(A0, wpack + (size_t)(2 * i) * WSW,
                                           bpack + (2 * i) * 64, A1, nullptr);
    conv_mfma<1><<<2304, 128, 0, stream>>>(A1, wpack + (size_t)(2 * i + 1) * WSW,
                                           bpack + (2 * i + 1) * 64, A0, nullptr);
  }
  conv_mfma<2><<<2304, 128, 0, stream>>>(A0, wpack + (size_t)6 * WSW,
                                         bpack + 6 * 64, nullptr, corep);

  kpn_split<<<dim3(576, 2), 256, 0, stream>>>(corep, dpad, (float*)d_out);
}

// Round 14
// 206.102 us; speedup vs baseline: 4.8516x; 1.3711x over previous
//
#include <hip/hip_runtime.h>
#include <hip/hip_bf16.h>
#include <utility>

typedef __attribute__((ext_vector_type(4))) float f32x4;
typedef __attribute__((ext_vector_type(8))) short bf16x8;
typedef __attribute__((ext_vector_type(4))) unsigned short u16x4;
typedef unsigned short u16;

constexpr int HH = 384, WW = 384;
constexpr int AWP = 386;               // padded activation width (+1 halo each side)
constexpr int ASTR = AWP * 64;         // elements per padded activation row
constexpr int NPIX = HH * WW;          // 147456
constexpr int NPIX3 = NPIX * 3;        // 442368 (one output tensor)
constexpr int DP = 398, DPLANE = DP * DP;  // data padded by 7 each side
constexpr size_t ACT_BYTES = (size_t)AWP * AWP * 64 * 2;  // 19,071,488
constexpr int WSW = 72 * 512;          // swizzled weights per conv: 72 iters * 64 lanes * 8
constexpr int WP1N = 12 * 512;         // conv1 swizzled weights (K=96)

__device__ __forceinline__ u16 f2bf(float f) {
  union { __hip_bfloat16 h; u16 u; } v; v.h = __float2bfloat16(f); return v.u;
}
__device__ __forceinline__ float bf2f(u16 u) {
  union { float f; unsigned int i; } v; v.i = ((unsigned int)u) << 16; return v.f;
}

// ---------------- weight/bias repack ----------------
// wpack: 7 convs, A-frag order: iter=(tap*2+ich)*4+m; oc=m*16+(lane&15); ic=ich*32+(lane>>4)*8+j
// wp1: conv1 (6ic, K=96): iter=kb*4+m; oc=m*16+(lane&15); k=kb*32+(lane>>4)*8+j; tap=k/8, ic=k%8
__global__ void repack_kern(const float* __restrict__ w1, const float* __restrict__ w2,
                            const float* __restrict__ wo, const float* __restrict__ b1,
                            const float* __restrict__ b2, const float* __restrict__ bo,
                            const float* __restrict__ wf,
                            u16* __restrict__ wpack, float* __restrict__ bpack,
                            u16* __restrict__ wp1)
{
  const int idx = blockIdx.x * 256 + threadIdx.x;
  constexpr int NW = 7 * WSW;
  if (idx < NW) {
    const int c = idx / WSW;
    const int r = idx % WSW;
    const int iter = r / 512;
    const int lane = (r % 512) / 8;
    const int j = r % 8;
    const int tap = iter >> 3;
    const int ich = (iter >> 2) & 1;
    const int m = iter & 3;
    const int oc = m * 16 + (lane & 15);
    const int ic = ich * 32 + (lane >> 4) * 8 + j;
    float v;
    if (c < 6) {
      const float* s = (c & 1) ? w2 : w1;
      v = s[(((c >> 1) * 64 + oc) * 64 + ic) * 9 + tap];
    } else {
      v = (oc < 35) ? wo[(oc * 64 + ic) * 9 + tap] : 0.f;
    }
    wpack[idx] = f2bf(v);
  } else if (idx < NW + 448) {
    const int t = idx - NW;
    const int c = t / 64, oc = t % 64;
    float v;
    if (c < 6) v = ((c & 1) ? b2 : b1)[(c >> 1) * 64 + oc];
    else v = (oc < 35) ? bo[oc] : 0.f;
    bpack[t] = v;
  } else if (idx < NW + 448 + WP1N) {
    const int t = idx - NW - 448;
    const int iter = t / 512;
    const int lane = (t % 512) / 8;
    const int j = t % 8;
    const int m = iter & 3;
    const int kb = iter >> 2;
    const int oc = m * 16 + (lane & 15);
    const int k = kb * 32 + (lane >> 4) * 8 + j;
    const int tap = k >> 3, ic = k & 7;
    const float v = (tap < 9 && ic < 6) ? wf[oc * 54 + ic * 9 + tap] : 0.f;
    wp1[t] = f2bf(v);
  }
}

// ---------------- halo clear: only the border bytes (replaces 42MB of memsets) ----------------
__global__ void halo_kern(u16* __restrict__ A0, u16* __restrict__ A1,
                          u16* __restrict__ in8, float* __restrict__ dpad)
{
  const int idx = blockIdx.x * 256 + threadIdx.x;
  if (idx < 49280) {                       // A0/A1 border: 1540 px * 16 u16x4 each
    u16* buf = (idx < 24640) ? A0 : A1;
    const int t = (idx < 24640) ? idx : idx - 24640;
    const int pos = t >> 4, q = t & 15;
    int y, x;
    if (pos < 386) { y = 0; x = pos; }
    else if (pos < 772) { y = 385; x = pos - 386; }
    else if (pos < 1156) { y = pos - 772 + 1; x = 0; }
    else { y = pos - 1156 + 1; x = 385; }
    *(u16x4*)(buf + ((size_t)y * AWP + x) * 64 + q * 4) = u16x4{0, 0, 0, 0};
  } else if (idx < 49280 + 3080) {         // in8 border: 1540 px * 2 u16x4
    const int t = idx - 49280;
    const int pos = t >> 1, q = t & 1;
    int y, x;
    if (pos < 386) { y = 0; x = pos; }
    else if (pos < 772) { y = 385; x = pos - 386; }
    else if (pos < 1156) { y = pos - 772 + 1; x = 0; }
    else { y = pos - 1156 + 1; x = 385; }
    *(u16x4*)(in8 + ((size_t)y * AWP + x) * 8 + q * 4) = u16x4{0, 0, 0, 0};
  } else if (idx < 49280 + 3080 + 32844) { // dpad border width 7, 3 ch
    const int t = idx - 52360;
    const int c = t / 10948, r = t % 10948;
    int y, x;
    if (r < 2786) { y = r / 398; x = r % 398; }
    else if (r < 5572) { const int rr = r - 2786; y = 391 + rr / 398; x = rr % 398; }
    else { const int rr = r - 5572; y = 7 + rr / 14; const int k = rr % 14; x = (k < 7) ? k : 384 + k; }
    dpad[(size_t)c * DPLANE + (size_t)y * DP + x] = 0.f;
  }
}

// ---------------- pad-copy data (fp32, halo 7) ----------------
__global__ void padcopy_kern(const float* __restrict__ data, float* __restrict__ dpad)
{
  const int idx = blockIdx.x * 256 + threadIdx.x;  // exactly 442368 threads
  const int c = idx / NPIX, r = idx % NPIX;
  const int y = r / WW, x = r % WW;
  dpad[c * DPLANE + (y + 7) * DP + (x + 7)] = data[idx];
}

// ---------------- pad data_with_est to NHWC8 bf16 (halo 1, ic 6->8 zero) ----------------
__global__ void pad6_kern(const float* __restrict__ din, u16* __restrict__ in8)
{
  const int px = blockIdx.x * 256 + threadIdx.x;   // 576*256 = NPIX exactly
  const int y = px / WW, x = px % WW;
  u16 vals[8];
  #pragma unroll
  for (int ic = 0; ic < 6; ++ic) vals[ic] = f2bf(din[ic * NPIX + px]);
  vals[6] = 0; vals[7] = 0;
  u16* o = in8 + ((size_t)(y + 1) * AWP + (x + 1)) * 8;
  *(u16x4*)(o) = u16x4{vals[0], vals[1], vals[2], vals[3]};
  *(u16x4*)(o + 4) = u16x4{vals[4], vals[5], vals[6], vals[7]};
}

// ---------------- conv1 via MFMA: 8ch NHWC bf16 -> 64, K=96 ----------------
__global__ __launch_bounds__(64)
void conv1_mfma(const u16* __restrict__ in8, const u16* __restrict__ wp,
                const float* __restrict__ bias, u16* __restrict__ outb)
{
  const int lane = threadIdx.x;
  const int l15 = lane & 15, g8 = lane >> 4;
  // XCD swizzle: 2304 = 8 * 288
  const int bid = blockIdx.x;
  const int sw = (bid & 7) * 288 + (bid >> 3);
  const int y = sw / 6;
  const int x0 = (sw % 6) * 64;

  f32x4 acc[4][4];
  #pragma unroll
  for (int m = 0; m < 4; ++m)
    #pragma unroll
    for (int n = 0; n < 4; ++n)
      acc[m][n] = f32x4{0.f, 0.f, 0.f, 0.f};

  #pragma unroll
  for (int kb = 0; kb < 3; ++kb) {
    const int tap = kb * 4 + g8;
    const int vt = tap < 9 ? tap : 0;                // dup tap0 for pad (weights are 0)
    const int kr = vt / 3, kc = vt % 3;
    const u16* inr = in8 + ((size_t)(y + kr) * AWP + x0 + kc) * 8;
    bf16x8 a[4], b[4];
    #pragma unroll
    for (int m = 0; m < 4; ++m)
      a[m] = *(const bf16x8*)(wp + (kb * 4 + m) * 512 + lane * 8);
    #pragma unroll
    for (int n = 0; n < 4; ++n)
      b[n] = *(const bf16x8*)(inr + (size_t)(n * 16 + l15) * 8);
    #pragma unroll
    for (int m = 0; m < 4; ++m)
      #pragma unroll
      for (int n = 0; n < 4; ++n)
        acc[m][n] = __builtin_amdgcn_mfma_f32_16x16x32_bf16(a[m], b[n], acc[m][n], 0, 0, 0);
  }

  const int oc_lo = g8 * 4;
  #pragma unroll
  for (int m = 0; m < 4; ++m) {
    const int oc0 = m * 16 + oc_lo;
    const f32x4 bv = *(const f32x4*)(bias + oc0);
    #pragma unroll
    for (int n = 0; n < 4; ++n) {
      const int px = x0 + n * 16 + l15;
      const f32x4 v = acc[m][n] + bv;
      u16x4 s;
      #pragma unroll
      for (int j = 0; j < 4; ++j) s[j] = f2bf(v[j]);
      *(u16x4*)(outb + ((size_t)(y + 1) * AWP + (px + 1)) * 64 + oc0) = s;
    }
  }
}

// ---------------- MFMA implicit-GEMM 3x3 conv: LDS-staged B, K-split 2 waves ----------------
// Stages 3 input rows (72px x 128B) once via global_load_lds (kills the 3x kc re-read),
// XOR-swizzled (chunk ^= px&7, 16B units): linear LDS dest + inverse-swizzled global
// source + swizzled ds_read_b128 -> conflict-free (rule: both-sides-or-neither).
// MODE 0: +bias, relu; MODE 1: +bias,+residual; MODE 2: +bias, f32 planar (oc<35)
template<int MODE>
__global__ __launch_bounds__(128, 3)
void conv_mfma(const u16* __restrict__ in, const u16* __restrict__ wp,
               const float* __restrict__ bias, u16* __restrict__ outb,
               float* __restrict__ outf)
{
  __shared__ u16 smem[3 * 72 * 64];                // 27648 B; reused as f32 red buffer
  const int lane = threadIdx.x & 63;
  const int wv = threadIdx.x >> 6;                 // K-half: ich = wv
  const int l15 = lane & 15, g8 = lane >> 4;
  // XCD-aware swizzle: 2304 blocks = 8 XCDs * 288 (48 rows * 6 col-blocks each)
  const int bid = blockIdx.x;
  const int sw = (bid & 7) * 288 + (bid >> 3);
  const int y = sw / 6;
  const int x0 = (sw % 6) * 64;
  const int ich = wv;

  // ---- stage 3 rows x 9KB, 1KB per global_load_lds, alternating waves ----
  {
    const int pxl = lane >> 3;                     // px sub-index within 1KB (0..7)
    const int s = lane & 7;                        // 16B slot (0..7)
    #pragma unroll
    for (int row = 0; row < 3; ++row) {
      const char* gbase = (const char*)(in + (size_t)(y + row) * ASTR + (size_t)x0 * 64);
      #pragma unroll
      for (int j = 0; j < 9; ++j) {
        if (((row * 9 + j) & 1) == wv) {
          const int px = j * 8 + pxl;              // 0..71
          const char* g = gbase + px * 128 + ((s ^ (px & 7)) << 4);
          __builtin_amdgcn_global_load_lds(
              (__attribute__((address_space(1))) const void*)g,
              (__attribute__((address_space(3))) void*)((char*)smem + row * 9216 + j * 1024),
              16, 0, 0);
        }
      }
    }
  }
  __syncthreads();

  f32x4 acc[4][4];
  #pragma unroll
  for (int m = 0; m < 4; ++m)
    #pragma unroll
    for (int n = 0; n < 4; ++n)
      acc[m][n] = f32x4{0.f, 0.f, 0.f, 0.f};

  const int chunk = ich * 4 + g8;                  // 16B chunk within a pixel's 128B
  #pragma unroll
  for (int tap = 0; tap < 9; ++tap) {
    const int kr = tap / 3, kc = tap % 3;
    const u16* wpi = wp + ((tap * 2 + ich) * 4) * 512 + lane * 8;  // coalesced A-frags
    bf16x8 a[4], b[4];
    #pragma unroll
    for (int m = 0; m < 4; ++m)
      a[m] = *(const bf16x8*)(wpi + m * 512);
    #pragma unroll
    for (int n = 0; n < 4; ++n) {
      const int p = kc + n * 16 + l15;             // 0..65 within staged row
      const char* bp = (const char*)smem + kr * 9216 + p * 128 + ((chunk ^ (p & 7)) << 4);
      b[n] = *(const bf16x8*)bp;
    }
    #pragma unroll
    for (int m = 0; m < 4; ++m)
      #pragma unroll
      for (int n = 0; n < 4; ++n)
        acc[m][n] = __builtin_amdgcn_mfma_f32_16x16x32_bf16(a[m], b[n], acc[m][n], 0, 0, 0);
  }

  __syncthreads();                                 // all b-reads done before smem reuse
  float* red = (float*)smem;                       // 16 KB reduction buffer (reuse)
  if (wv == 1) {
    #pragma unroll
    for (int m = 0; m < 4; ++m)
      #pragma unroll
      for (int n = 0; n < 4; ++n)
        *(f32x4*)(red + (m * 4 + n) * 256 + lane * 4) = acc[m][n];
  }
  __syncthreads();
  if (wv == 1) return;

  const int oc_lo = g8 * 4;
  #pragma unroll
  for (int m = 0; m < 4; ++m) {
    const int oc0 = m * 16 + oc_lo;                // D row = (lane>>4)*4 + reg
    const f32x4 bv = *(const f32x4*)(bias + oc0);
    #pragma unroll
    for (int n = 0; n < 4; ++n) {
      const int px = x0 + n * 16 + l15;            // D col = lane&15
      f32x4 v = acc[m][n] + *(const f32x4*)(red + (m * 4 + n) * 256 + lane * 4) + bv;
      if constexpr (MODE == 0) {
        #pragma unroll
        for (int j = 0; j < 4; ++j) v[j] = v[j] > 0.f ? v[j] : 0.f;
      }
      if constexpr (MODE == 1) {
        const u16x4 r = *(const u16x4*)(outb + ((size_t)(y + 1) * AWP + (px + 1)) * 64 + oc0);
        #pragma unroll
        for (int j = 0; j < 4; ++j) v[j] += bf2f(r[j]);
      }
      if constexpr (MODE <= 1) {
        u16x4 s;
        #pragma unroll
        for (int j = 0; j < 4; ++j) s[j] = f2bf(v[j]);
        *(u16x4*)(outb + ((size_t)(y + 1) * AWP + (px + 1)) * 64 + oc0) = s;
      } else {
        #pragma unroll
        for (int j = 0; j < 4; ++j) {
          const int oc = oc0 + j;
          if (oc < 35) outf[(size_t)oc * NPIX + (size_t)y * WW + px] = v[j];
        }
      }
    }
  }
}

// ---------------- KPN apply: template-fold sweep (guaranteed static indexing) ----------------
constexpr int isqrt_(int d2) { int li = 0; while ((li + 1) * (li + 1) <= d2) ++li; return li; }
constexpr double csqrt_(double x) {
  double g = x < 1.0 ? 1.0 : x;
  for (int i = 0; i < 60; ++i) g = 0.5 * (g + x / g);
  return g;
}
constexpr int KOFFS[7] = {0, 2, 5, 9, 14, 20, 27};

template<int SEC0, int NSEC, int CKN, int A, int B, int T>
__device__ __forceinline__ void kpn_sec_one(const float (&g)[3], const float (&ck)[CKN],
                                            float (&s)[NSEC], float (&p)[NSEC][3])
{
  constexpr int WIDE = SEC0 + T + 2;
  if constexpr (A < WIDE && B < WIDE) {
    constexpr int d2 = A * A + B * B;
    constexpr int li = isqrt_(d2);
    constexpr bool exact = (li * li == d2);
    constexpr int hraw = exact ? li : li + 1;
    constexpr float dd = (float)csqrt_((double)d2);
    constexpr float wlo = exact ? 1.0f : ((float)hraw - dd);
    constexpr float whi = exact ? 0.0f : (dd - (float)li);
    constexpr float mult = ((A > 0) ? 2.0f : 1.0f) * ((B > 0) ? 2.0f : 1.0f);
    constexpr int lidx = li < WIDE - 1 ? li : WIDE - 1;
    constexpr int hidx = hraw < WIDE - 1 ? hraw : WIDE - 1;
    constexpr bool msk = d2 <= (WIDE - 1) * (WIDE - 1);
    constexpr int cb = KOFFS[SEC0 + T] - KOFFS[SEC0];
    float e;
    if constexpr (msk) e = __expf(wlo * ck[cb + lidx] + whi * ck[cb + hidx]);
    else e = 1.0f;                                   // masked: logit 0, still in softmax
    s[T] += mult * e;
    p[T][0] += e * g[0];
    p[T][1] += e * g[1];
    p[T][2] += e * g[2];
  }
}

template<int SEC0, int NSEC, int CKN, int A, int B, int... Ts>
__device__ __forceinline__ void kpn_secs(std::integer_sequence<int, Ts...>,
                                         const float (&g)[3], const float (&ck)[CKN],
                                         float (&s)[NSEC], float (&p)[NSEC][3])
{
  (kpn_sec_one<SEC0, NSEC, CKN, A, B, Ts>(g, ck, s, p), ...);
}

template<int SEC0, int NSEC, int CKN, int WMAX, int C>
__device__ __forceinline__ void kpn_cell(const float* __restrict__ base,
                                         const float (&ck)[CKN],
                                         float (&s)[NSEC], float (&p)[NSEC][3])
{
  constexpr int A = C / WMAX, B = C % WMAX;
  float g[3];
  #pragma unroll
  for (int c = 0; c < 3; ++c) {
    const float* bc = base + c * DPLANE;
    float v = bc[A * DP + B];
    if constexpr (B > 0) v += bc[A * DP - B];
    if constexpr (A > 0) v += bc[-A * DP + B];
    if constexpr (A > 0 && B > 0) v += bc[-A * DP - B];
    g[c] = v;
  }
  kpn_secs<SEC0, NSEC, CKN, A, B>(std::make_integer_sequence<int, NSEC>{}, g, ck, s, p);
}

template<int SEC0, int NSEC, int CKN, int WMAX, int... Cs>
__device__ __forceinline__ void kpn_cells(std::integer_sequence<int, Cs...>,
                                          const float* __restrict__ base,
                                          const float (&ck)[CKN],
                                          float (&s)[NSEC], float (&p)[NSEC][3])
{
  (kpn_cell<SEC0, NSEC, CKN, WMAX, Cs>(base, ck, s, p), ...);
}

template<int SEC0, int NSEC>
__device__ __forceinline__ void kpn_grp_body(const float* __restrict__ corep,
                                             const float* __restrict__ dpad,
                                             float* __restrict__ out)
{
  constexpr int WMAX = SEC0 + NSEC + 1;          // widest WIDE in this group
  constexpr int CK0 = KOFFS[SEC0];
  constexpr int CKN = KOFFS[SEC0 + NSEC - 1] + (SEC0 + NSEC + 1) - CK0;

  // XCD-contiguous band swizzle: 576 = 8 XCDs * 72 blocks (48 rows each) ->
  // per-XCD corep slice (~2.6MB) + dpad band fit the private 4MB L2.
  const int bid = blockIdx.x;
  const int sw = (bid & 7) * 72 + (bid >> 3);
  const int px = sw * 256 + threadIdx.x;              // 576*256 = NPIX exactly
  const int y = px / WW, x = px % WW;
  const float* base = dpad + (size_t)(y + 7) * DP + (x + 7);

  float ck[CKN];
  #pragma unroll
  for (int i = 0; i < CKN; ++i) ck[i] = fabsf(corep[(size_t)(CK0 + i) * NPIX + px]);

  float s[NSEC], p[NSEC][3];
  #pragma unroll
  for (int k = 0; k < NSEC; ++k) { s[k] = 0.f; p[k][0] = 0.f; p[k][1] = 0.f; p[k][2] = 0.f; }

  kpn_cells<SEC0, NSEC, CKN, WMAX>(std::make_integer_sequence<int, WMAX * WMAX>{},
                                   base, ck, s, p);

  #pragma unroll
  for (int t = 0; t < NSEC; ++t) {
    const float inv = 1.f / s[t];
    float* o = out + (size_t)(SEC0 + t + 1) * NPIX3 + px;
    o[0] = p[t][0] * inv;
    o[NPIX] = p[t][1] * inv;
    o[2 * NPIX] = p[t][2] * inv;
  }
}

__global__ __launch_bounds__(256, 4)
void kpn_split(const float* __restrict__ corep, const float* __restrict__ dpad,
               float* __restrict__ out)
{
  if (blockIdx.y == 0) kpn_grp_body<0, 5>(corep, dpad, out);   // WIDE 2-6
  else                 kpn_grp_body<5, 2>(corep, dpad, out);   // WIDE 7-8
}

// ---------------- launch ----------------
extern "C" void kernel_launch(void* const* d_in, const int* in_sizes, int n_in,
                              void* d_out, int out_size, void* d_ws, size_t ws_size,
                              hipStream_t stream)
{
  const float* d_est   = (const float*)d_in[0];
  const float* data    = (const float*)d_in[1];
  const float* w_first = (const float*)d_in[2];
  const float* b_first = (const float*)d_in[3];
  const float* w_blk1  = (const float*)d_in[4];
  const float* b_blk1  = (const float*)d_in[5];
  const float* w_blk2  = (const float*)d_in[6];
  const float* b_blk2  = (const float*)d_in[7];
  const float* w_out   = (const float*)d_in[8];
  const float* b_out   = (const float*)d_in[9];

  char* ws = (char*)d_ws;
  const size_t OFF_A1    = ACT_BYTES;
  const size_t OFF_CORE  = 2 * ACT_BYTES;
  const size_t OFF_DPAD  = OFF_CORE + (size_t)35 * NPIX * 4;
  const size_t OFF_WPACK = OFF_DPAD + (size_t)3 * DPLANE * 4;
  const size_t OFF_BPACK = OFF_WPACK + (size_t)7 * WSW * 2;
  const size_t OFF_WP1   = OFF_BPACK + 448 * 4;
  const size_t OFF_IN8   = OFF_WP1 + (size_t)WP1N * 2;

  u16*   A0    = (u16*)(ws);
  u16*   A1    = (u16*)(ws + OFF_A1);
  float* corep = (float*)(ws + OFF_CORE);
  float* dpad  = (float*)(ws + OFF_DPAD);
  u16*   wpack = (u16*)(ws + OFF_WPACK);
  float* bpack = (float*)(ws + OFF_BPACK);
  u16*   wp1   = (u16*)(ws + OFF_WP1);
  u16*   in8   = (u16*)(ws + OFF_IN8);

  // output 0 is an exact copy of `data`
  hipMemcpyAsync(d_out, data, (size_t)NPIX3 * 4, hipMemcpyDeviceToDevice, stream);

  halo_kern<<<333, 256, 0, stream>>>(A0, A1, in8, dpad);
  repack_kern<<<1034, 256, 0, stream>>>(w_blk1, w_blk2, w_out, b_blk1, b_blk2, b_out,
                                        w_first, wpack, bpack, wp1);
  padcopy_kern<<<1728, 256, 0, stream>>>(data, dpad);
  pad6_kern<<<576, 256, 0, stream>>>(d_est, in8);
  conv1_mfma<<<2304, 64, 0, stream>>>(in8, wp1, b_first, A0);

  for (int i = 0; i < 3; ++i) {
    conv_mfma<0><<<2304, 128, 0, stream>>>(A0, wpack + (size_t)(2 * i) * WSW,
                                           bpack + (2 * i) * 64, A1, nullptr);
    conv_mfma<1><<<2304, 128, 0, stream>>>(A1, wpack + (size_t)(2 * i + 1) * WSW,
                                           bpack + (2 * i + 1) * 64, A0, nullptr);
  }
  conv_mfma<2><<<2304, 128, 0, stream>>>(A0, wpack + (size_t)6 * WSW,
                                         bpack + 6 * 64, nullptr, corep);

  kpn_split<<<dim3(576, 2), 256, 0, stream>>>(corep, dpad, (float*)d_out);
}

// Round 17
// 196.064 us; speedup vs baseline: 5.0999x; 1.0512x over previous
//
#include <hip/hip_runtime.h>
#include <hip/hip_bf16.h>
#include <utility>

typedef __attribute__((ext_vector_type(4))) float f32x4;
typedef __attribute__((ext_vector_type(8))) short bf16x8;
typedef __attribute__((ext_vector_type(4))) unsigned short u16x4;
typedef unsigned short u16;

constexpr int HH = 384, WW = 384;
constexpr int AWP = 386;               // padded activation width (+1 halo each side)
constexpr int ASTR = AWP * 64;         // elements per padded activation row
constexpr int NPIX = HH * WW;          // 147456
constexpr int NPIX3 = NPIX * 3;        // 442368 (one output tensor)
constexpr int DP = 398, DPLANE = DP * DP;  // data padded by 7 each side
constexpr size_t ACT_BYTES = (size_t)AWP * AWP * 64 * 2;  // 19,071,488
constexpr int WSW = 72 * 512;          // swizzled weights per conv: 72 iters * 64 lanes * 8
constexpr int WP1N = 12 * 512;         // conv1 swizzled weights (K=96)

__device__ __forceinline__ u16 f2bf(float f) {
  union { __hip_bfloat16 h; u16 u; } v; v.h = __float2bfloat16(f); return v.u;
}
__device__ __forceinline__ float bf2f(u16 u) {
  union { float f; unsigned int i; } v; v.i = ((unsigned int)u) << 16; return v.f;
}

// ---------------- weight/bias repack ----------------
// wpack: 7 convs, A-frag order: iter=(tap*2+ich)*4+m; oc=m*16+(lane&15); ic=ich*32+(lane>>4)*8+j
// wp1: conv1 (6ic, K=96): iter=kb*4+m; oc=m*16+(lane&15); k=kb*32+(lane>>4)*8+j; tap=k/8, ic=k%8
__global__ void repack_kern(const float* __restrict__ w1, const float* __restrict__ w2,
                            const float* __restrict__ wo, const float* __restrict__ b1,
                            const float* __restrict__ b2, const float* __restrict__ bo,
                            const float* __restrict__ wf,
                            u16* __restrict__ wpack, float* __restrict__ bpack,
                            u16* __restrict__ wp1)
{
  const int idx = blockIdx.x * 256 + threadIdx.x;
  constexpr int NW = 7 * WSW;
  if (idx < NW) {
    const int c = idx / WSW;
    const int r = idx % WSW;
    const int iter = r / 512;
    const int lane = (r % 512) / 8;
    const int j = r % 8;
    const int tap = iter >> 3;
    const int ich = (iter >> 2) & 1;
    const int m = iter & 3;
    const int oc = m * 16 + (lane & 15);
    const int ic = ich * 32 + (lane >> 4) * 8 + j;
    float v;
    if (c < 6) {
      const float* s = (c & 1) ? w2 : w1;
      v = s[(((c >> 1) * 64 + oc) * 64 + ic) * 9 + tap];
    } else {
      v = (oc < 35) ? wo[(oc * 64 + ic) * 9 + tap] : 0.f;
    }
    wpack[idx] = f2bf(v);
  } else if (idx < NW + 448) {
    const int t = idx - NW;
    const int c = t / 64, oc = t % 64;
    float v;
    if (c < 6) v = ((c & 1) ? b2 : b1)[(c >> 1) * 64 + oc];
    else v = (oc < 35) ? bo[oc] : 0.f;
    bpack[t] = v;
  } else if (idx < NW + 448 + WP1N) {
    const int t = idx - NW - 448;
    const int iter = t / 512;
    const int lane = (t % 512) / 8;
    const int j = t % 8;
    const int m = iter & 3;
    const int kb = iter >> 2;
    const int oc = m * 16 + (lane & 15);
    const int k = kb * 32 + (lane >> 4) * 8 + j;
    const int tap = k >> 3, ic = k & 7;
    const float v = (tap < 9 && ic < 6) ? wf[oc * 54 + ic * 9 + tap] : 0.f;
    wp1[t] = f2bf(v);
  }
}

// ---------------- halo clear: only the border bytes (replaces 42MB of memsets) ----------------
__global__ void halo_kern(u16* __restrict__ A0, u16* __restrict__ A1,
                          u16* __restrict__ in8, float* __restrict__ dpad)
{
  const int idx = blockIdx.x * 256 + threadIdx.x;
  if (idx < 49280) {                       // A0/A1 border: 1540 px * 16 u16x4 each
    u16* buf = (idx < 24640) ? A0 : A1;
    const int t = (idx < 24640) ? idx : idx - 24640;
    const int pos = t >> 4, q = t & 15;
    int y, x;
    if (pos < 386) { y = 0; x = pos; }
    else if (pos < 772) { y = 385; x = pos - 386; }
    else if (pos < 1156) { y = pos - 772 + 1; x = 0; }
    else { y = pos - 1156 + 1; x = 385; }
    *(u16x4*)(buf + ((size_t)y * AWP + x) * 64 + q * 4) = u16x4{0, 0, 0, 0};
  } else if (idx < 49280 + 3080) {         // in8 border: 1540 px * 2 u16x4
    const int t = idx - 49280;
    const int pos = t >> 1, q = t & 1;
    int y, x;
    if (pos < 386) { y = 0; x = pos; }
    else if (pos < 772) { y = 385; x = pos - 386; }
    else if (pos < 1156) { y = pos - 772 + 1; x = 0; }
    else { y = pos - 1156 + 1; x = 385; }
    *(u16x4*)(in8 + ((size_t)y * AWP + x) * 8 + q * 4) = u16x4{0, 0, 0, 0};
  } else if (idx < 49280 + 3080 + 32844) { // dpad border width 7, 3 ch
    const int t = idx - 52360;
    const int c = t / 10948, r = t % 10948;
    int y, x;
    if (r < 2786) { y = r / 398; x = r % 398; }
    else if (r < 5572) { const int rr = r - 2786; y = 391 + rr / 398; x = rr % 398; }
    else { const int rr = r - 5572; y = 7 + rr / 14; const int k = rr % 14; x = (k < 7) ? k : 384 + k; }
    dpad[(size_t)c * DPLANE + (size_t)y * DP + x] = 0.f;
  }
}

// ---------------- pad-copy data (fp32, halo 7) ----------------
__global__ void padcopy_kern(const float* __restrict__ data, float* __restrict__ dpad)
{
  const int idx = blockIdx.x * 256 + threadIdx.x;  // exactly 442368 threads
  const int c = idx / NPIX, r = idx % NPIX;
  const int y = r / WW, x = r % WW;
  dpad[c * DPLANE + (y + 7) * DP + (x + 7)] = data[idx];
}

// ---------------- pad data_with_est to NHWC8 bf16 (halo 1, ic 6->8 zero) ----------------
__global__ void pad6_kern(const float* __restrict__ din, u16* __restrict__ in8)
{
  const int px = blockIdx.x * 256 + threadIdx.x;   // 576*256 = NPIX exactly
  const int y = px / WW, x = px % WW;
  u16 vals[8];
  #pragma unroll
  for (int ic = 0; ic < 6; ++ic) vals[ic] = f2bf(din[ic * NPIX + px]);
  vals[6] = 0; vals[7] = 0;
  u16* o = in8 + ((size_t)(y + 1) * AWP + (x + 1)) * 8;
  *(u16x4*)(o) = u16x4{vals[0], vals[1], vals[2], vals[3]};
  *(u16x4*)(o + 4) = u16x4{vals[4], vals[5], vals[6], vals[7]};
}

// ---------------- conv1 via MFMA: 8ch NHWC bf16 -> 64, K=96 ----------------
__global__ __launch_bounds__(64)
void conv1_mfma(const u16* __restrict__ in8, const u16* __restrict__ wp,
                const float* __restrict__ bias, u16* __restrict__ outb)
{
  const int lane = threadIdx.x;
  const int l15 = lane & 15, g8 = lane >> 4;
  // XCD swizzle: 2304 = 8 * 288
  const int bid = blockIdx.x;
  const int sw = (bid & 7) * 288 + (bid >> 3);
  const int y = sw / 6;
  const int x0 = (sw % 6) * 64;

  f32x4 acc[4][4];
  #pragma unroll
  for (int m = 0; m < 4; ++m)
    #pragma unroll
    for (int n = 0; n < 4; ++n)
      acc[m][n] = f32x4{0.f, 0.f, 0.f, 0.f};

  #pragma unroll
  for (int kb = 0; kb < 3; ++kb) {
    const int tap = kb * 4 + g8;
    const int vt = tap < 9 ? tap : 0;                // dup tap0 for pad (weights are 0)
    const int kr = vt / 3, kc = vt % 3;
    const u16* inr = in8 + ((size_t)(y + kr) * AWP + x0 + kc) * 8;
    bf16x8 a[4], b[4];
    #pragma unroll
    for (int m = 0; m < 4; ++m)
      a[m] = *(const bf16x8*)(wp + (kb * 4 + m) * 512 + lane * 8);
    #pragma unroll
    for (int n = 0; n < 4; ++n)
      b[n] = *(const bf16x8*)(inr + (size_t)(n * 16 + l15) * 8);
    #pragma unroll
    for (int m = 0; m < 4; ++m)
      #pragma unroll
      for (int n = 0; n < 4; ++n)
        acc[m][n] = __builtin_amdgcn_mfma_f32_16x16x32_bf16(a[m], b[n], acc[m][n], 0, 0, 0);
  }

  const int oc_lo = g8 * 4;
  #pragma unroll
  for (int m = 0; m < 4; ++m) {
    const int oc0 = m * 16 + oc_lo;
    const f32x4 bv = *(const f32x4*)(bias + oc0);
    #pragma unroll
    for (int n = 0; n < 4; ++n) {
      const int px = x0 + n * 16 + l15;
      const f32x4 v = acc[m][n] + bv;
      u16x4 s;
      #pragma unroll
      for (int j = 0; j < 4; ++j) s[j] = f2bf(v[j]);
      *(u16x4*)(outb + ((size_t)(y + 1) * AWP + (px + 1)) * 64 + oc0) = s;
    }
  }
}

// ---------------- MFMA implicit-GEMM 3x3 conv: LDS-staged B, K-split 2 waves ----------------
// Stages 3 input rows (72px x 128B) once via global_load_lds (kills the 3x kc re-read),
// XOR-swizzled (chunk ^= px&7, 16B units): linear LDS dest + inverse-swizzled global
// source + swizzled ds_read_b128 -> conflict-free (rule: both-sides-or-neither).
// MODE 0: +bias, relu; MODE 1: +bias,+residual; MODE 2: +bias, f32 planar (oc<35)
template<int MODE>
__global__ __launch_bounds__(128, 3)
void conv_mfma(const u16* __restrict__ in, const u16* __restrict__ wp,
               const float* __restrict__ bias, u16* __restrict__ outb,
               float* __restrict__ outf)
{
  __shared__ u16 smem[3 * 72 * 64];                // 27648 B; reused as f32 red buffer
  const int lane = threadIdx.x & 63;
  const int wv = threadIdx.x >> 6;                 // K-half: ich = wv
  const int l15 = lane & 15, g8 = lane >> 4;
  // XCD-aware swizzle: 2304 blocks = 8 XCDs * 288 (48 rows * 6 col-blocks each)
  const int bid = blockIdx.x;
  const int sw = (bid & 7) * 288 + (bid >> 3);
  const int y = sw / 6;
  const int x0 = (sw % 6) * 64;
  const int ich = wv;

  // ---- stage 3 rows x 9KB, 1KB per global_load_lds, alternating waves ----
  {
    const int pxl = lane >> 3;                     // px sub-index within 1KB (0..7)
    const int s = lane & 7;                        // 16B slot (0..7)
    #pragma unroll
    for (int row = 0; row < 3; ++row) {
      const char* gbase = (const char*)(in + (size_t)(y + row) * ASTR + (size_t)x0 * 64);
      #pragma unroll
      for (int j = 0; j < 9; ++j) {
        if (((row * 9 + j) & 1) == wv) {
          const int px = j * 8 + pxl;              // 0..71
          const char* g = gbase + px * 128 + ((s ^ (px & 7)) << 4);
          __builtin_amdgcn_global_load_lds(
              (__attribute__((address_space(1))) const void*)g,
              (__attribute__((address_space(3))) void*)((char*)smem + row * 9216 + j * 1024),
              16, 0, 0);
        }
      }
    }
  }
  __syncthreads();

  f32x4 acc[4][4];
  #pragma unroll
  for (int m = 0; m < 4; ++m)
    #pragma unroll
    for (int n = 0; n < 4; ++n)
      acc[m][n] = f32x4{0.f, 0.f, 0.f, 0.f};

  const int chunk = ich * 4 + g8;                  // 16B chunk within a pixel's 128B
  #pragma unroll
  for (int tap = 0; tap < 9; ++tap) {
    const int kr = tap / 3, kc = tap % 3;
    const u16* wpi = wp + ((tap * 2 + ich) * 4) * 512 + lane * 8;  // coalesced A-frags
    bf16x8 a[4], b[4];
    #pragma unroll
    for (int m = 0; m < 4; ++m)
      a[m] = *(const bf16x8*)(wpi + m * 512);
    #pragma unroll
    for (int n = 0; n < 4; ++n) {
      const int p = kc + n * 16 + l15;             // 0..65 within staged row
      const char* bp = (const char*)smem + kr * 9216 + p * 128 + ((chunk ^ (p & 7)) << 4);
      b[n] = *(const bf16x8*)bp;
    }
    #pragma unroll
    for (int m = 0; m < 4; ++m)
      #pragma unroll
      for (int n = 0; n < 4; ++n)
        acc[m][n] = __builtin_amdgcn_mfma_f32_16x16x32_bf16(a[m], b[n], acc[m][n], 0, 0, 0);
  }

  __syncthreads();                                 // all b-reads done before smem reuse
  float* red = (float*)smem;                       // 16 KB reduction buffer (reuse)
  if (wv == 1) {
    #pragma unroll
    for (int m = 0; m < 4; ++m)
      #pragma unroll
      for (int n = 0; n < 4; ++n)
        *(f32x4*)(red + (m * 4 + n) * 256 + lane * 4) = acc[m][n];
  }
  __syncthreads();
  if (wv == 1) return;

  const int oc_lo = g8 * 4;
  #pragma unroll
  for (int m = 0; m < 4; ++m) {
    const int oc0 = m * 16 + oc_lo;                // D row = (lane>>4)*4 + reg
    const f32x4 bv = *(const f32x4*)(bias + oc0);
    #pragma unroll
    for (int n = 0; n < 4; ++n) {
      const int px = x0 + n * 16 + l15;            // D col = lane&15
      f32x4 v = acc[m][n] + *(const f32x4*)(red + (m * 4 + n) * 256 + lane * 4) + bv;
      if constexpr (MODE == 0) {
        #pragma unroll
        for (int j = 0; j < 4; ++j) v[j] = v[j] > 0.f ? v[j] : 0.f;
      }
      if constexpr (MODE == 1) {
        const u16x4 r = *(const u16x4*)(outb + ((size_t)(y + 1) * AWP + (px + 1)) * 64 + oc0);
        #pragma unroll
        for (int j = 0; j < 4; ++j) v[j] += bf2f(r[j]);
      }
      if constexpr (MODE <= 1) {
        u16x4 s;
        #pragma unroll
        for (int j = 0; j < 4; ++j) s[j] = f2bf(v[j]);
        *(u16x4*)(outb + ((size_t)(y + 1) * AWP + (px + 1)) * 64 + oc0) = s;
      } else {
        #pragma unroll
        for (int j = 0; j < 4; ++j) {
          const int oc = oc0 + j;
          if (oc < 35) outf[(size_t)oc * NPIX + (size_t)y * WW + px] = v[j];
        }
      }
    }
  }
}

// ---------------- KPN apply: template-fold sweep (guaranteed static indexing) ----------------
constexpr int isqrt_(int d2) { int li = 0; while ((li + 1) * (li + 1) <= d2) ++li; return li; }
constexpr double csqrt_(double x) {
  double g = x < 1.0 ? 1.0 : x;
  for (int i = 0; i < 60; ++i) g = 0.5 * (g + x / g);
  return g;
}
constexpr int KOFFS[7] = {0, 2, 5, 9, 14, 20, 27};

template<int SEC0, int NSEC, int CKN, int A, int B, int T>
__device__ __forceinline__ void kpn_sec_one(const float (&g)[3], const float (&ck)[CKN],
                                            float (&s)[NSEC], float (&p)[NSEC][3])
{
  constexpr int WIDE = SEC0 + T + 2;
  if constexpr (A < WIDE && B < WIDE) {
    constexpr int d2 = A * A + B * B;
    constexpr int li = isqrt_(d2);
    constexpr bool exact = (li * li == d2);
    constexpr int hraw = exact ? li : li + 1;
    constexpr float dd = (float)csqrt_((double)d2);
    constexpr float wlo = exact ? 1.0f : ((float)hraw - dd);
    constexpr float whi = exact ? 0.0f : (dd - (float)li);
    constexpr float mult = ((A > 0) ? 2.0f : 1.0f) * ((B > 0) ? 2.0f : 1.0f);
    constexpr int lidx = li < WIDE - 1 ? li : WIDE - 1;
    constexpr int hidx = hraw < WIDE - 1 ? hraw : WIDE - 1;
    constexpr bool msk = d2 <= (WIDE - 1) * (WIDE - 1);
    constexpr int cb = KOFFS[SEC0 + T] - KOFFS[SEC0];
    float e;
    if constexpr (msk) e = __expf(wlo * ck[cb + lidx] + whi * ck[cb + hidx]);
    else e = 1.0f;                                   // masked: logit 0, still in softmax
    s[T] += mult * e;
    p[T][0] += e * g[0];
    p[T][1] += e * g[1];
    p[T][2] += e * g[2];
  }
}

template<int SEC0, int NSEC, int CKN, int A, int B, int... Ts>
__device__ __forceinline__ void kpn_secs(std::integer_sequence<int, Ts...>,
                                         const float (&g)[3], const float (&ck)[CKN],
                                         float (&s)[NSEC], float (&p)[NSEC][3])
{
  (kpn_sec_one<SEC0, NSEC, CKN, A, B, Ts>(g, ck, s, p), ...);
}

template<int SEC0, int NSEC, int CKN, int WMAX, int C>
__device__ __forceinline__ void kpn_cell(const float* __restrict__ base,
                                         const float (&ck)[CKN],
                                         float (&s)[NSEC], float (&p)[NSEC][3])
{
  constexpr int A = C / WMAX, B = C % WMAX;
  float g[3];
  #pragma unroll
  for (int c = 0; c < 3; ++c) {
    const float* bc = base + c * DPLANE;
    float v = bc[A * DP + B];
    if constexpr (B > 0) v += bc[A * DP - B];
    if constexpr (A > 0) v += bc[-A * DP + B];
    if constexpr (A > 0 && B > 0) v += bc[-A * DP - B];
    g[c] = v;
  }
  kpn_secs<SEC0, NSEC, CKN, A, B>(std::make_integer_sequence<int, NSEC>{}, g, ck, s, p);
}

template<int SEC0, int NSEC, int CKN, int WMAX, int... Cs>
__device__ __forceinline__ void kpn_cells(std::integer_sequence<int, Cs...>,
                                          const float* __restrict__ base,
                                          const float (&ck)[CKN],
                                          float (&s)[NSEC], float (&p)[NSEC][3])
{
  (kpn_cell<SEC0, NSEC, CKN, WMAX, Cs>(base, ck, s, p), ...);
}

template<int SEC0, int NSEC>
__device__ __forceinline__ void kpn_grp_body(const float* __restrict__ corep,
                                             const float* __restrict__ dpad,
                                             float* __restrict__ out)
{
  constexpr int WMAX = SEC0 + NSEC + 1;          // widest WIDE in this group
  constexpr int CK0 = KOFFS[SEC0];
  constexpr int CKN = KOFFS[SEC0 + NSEC - 1] + (SEC0 + NSEC + 1) - CK0;

  // XCD-contiguous band swizzle: 576 = 8 XCDs * 72 blocks (48 rows each) ->
  // per-XCD corep slice (~2.6MB) + dpad band fit the private 4MB L2.
  const int bid = blockIdx.x;
  const int sw = (bid & 7) * 72 + (bid >> 3);
  const int px = sw * 256 + threadIdx.x;              // 576*256 = NPIX exactly
  const int y = px / WW, x = px % WW;
  const float* base = dpad + (size_t)(y + 7) * DP + (x + 7);

  float ck[CKN];
  #pragma unroll
  for (int i = 0; i < CKN; ++i) ck[i] = fabsf(corep[(size_t)(CK0 + i) * NPIX + px]);

  float s[NSEC], p[NSEC][3];
  #pragma unroll
  for (int k = 0; k < NSEC; ++k) { s[k] = 0.f; p[k][0] = 0.f; p[k][1] = 0.f; p[k][2] = 0.f; }

  kpn_cells<SEC0, NSEC, CKN, WMAX>(std::make_integer_sequence<int, WMAX * WMAX>{},
                                   base, ck, s, p);

  #pragma unroll
  for (int t = 0; t < NSEC; ++t) {
    const float inv = 1.f / s[t];
    float* o = out + (size_t)(SEC0 + t + 1) * NPIX3 + px;
    o[0] = p[t][0] * inv;
    o[NPIX] = p[t][1] * inv;
    o[2 * NPIX] = p[t][2] * inv;
  }
}

// Full 7-section fusion: shares all mirror-gathers across sections (675 loads/px
// vs 1182 for the 2-group split). Safe now: template-fold keeps all indices static
// (R6's spill was the runtime-isqrt path). State: ck[35]+s[7]+p[21] ~= 100 VGPR.
__global__ __launch_bounds__(256, 2)
void kpn_fused7(const float* __restrict__ corep, const float* __restrict__ dpad,
                float* __restrict__ out)
{
  kpn_grp_body<0, 7>(corep, dpad, out);
}

// ---------------- launch ----------------
extern "C" void kernel_launch(void* const* d_in, const int* in_sizes, int n_in,
                              void* d_out, int out_size, void* d_ws, size_t ws_size,
                              hipStream_t stream)
{
  const float* d_est   = (const float*)d_in[0];
  const float* data    = (const float*)d_in[1];
  const float* w_first = (const float*)d_in[2];
  const float* b_first = (const float*)d_in[3];
  const float* w_blk1  = (const float*)d_in[4];
  const float* b_blk1  = (const float*)d_in[5];
  const float* w_blk2  = (const float*)d_in[6];
  const float* b_blk2  = (const float*)d_in[7];
  const float* w_out   = (const float*)d_in[8];
  const float* b_out   = (const float*)d_in[9];

  char* ws = (char*)d_ws;
  const size_t OFF_A1    = ACT_BYTES;
  const size_t OFF_CORE  = 2 * ACT_BYTES;
  const size_t OFF_DPAD  = OFF_CORE + (size_t)35 * NPIX * 4;
  const size_t OFF_WPACK = OFF_DPAD + (size_t)3 * DPLANE * 4;
  const size_t OFF_BPACK = OFF_WPACK + (size_t)7 * WSW * 2;
  const size_t OFF_WP1   = OFF_BPACK + 448 * 4;
  const size_t OFF_IN8   = OFF_WP1 + (size_t)WP1N * 2;

  u16*   A0    = (u16*)(ws);
  u16*   A1    = (u16*)(ws + OFF_A1);
  float* corep = (float*)(ws + OFF_CORE);
  float* dpad  = (float*)(ws + OFF_DPAD);
  u16*   wpack = (u16*)(ws + OFF_WPACK);
  float* bpack = (float*)(ws + OFF_BPACK);
  u16*   wp1   = (u16*)(ws + OFF_WP1);
  u16*   in8   = (u16*)(ws + OFF_IN8);

  // output 0 is an exact copy of `data`
  hipMemcpyAsync(d_out, data, (size_t)NPIX3 * 4, hipMemcpyDeviceToDevice, stream);

  halo_kern<<<333, 256, 0, stream>>>(A0, A1, in8, dpad);
  repack_kern<<<1034, 256, 0, stream>>>(w_blk1, w_blk2, w_out, b_blk1, b_blk2, b_out,
                                        w_first, wpack, bpack, wp1);
  padcopy_kern<<<1728, 256, 0, stream>>>(data, dpad);
  pad6_kern<<<576, 256, 0, stream>>>(d_est, in8);
  conv1_mfma<<<2304, 64, 0, stream>>>(in8, wp1, b_first, A0);

  for (int i = 0; i < 3; ++i) {
    conv_mfma<0><<<2304, 128, 0, stream>>>(A0, wpack + (size_t)(2 * i) * WSW,
                                           bpack + (2 * i) * 64, A1, nullptr);
    conv_mfma<1><<<2304, 128, 0, stream>>>(A1, wpack + (size_t)(2 * i + 1) * WSW,
                                           bpack + (2 * i + 1) * 64, A0, nullptr);
  }
  conv_mfma<2><<<2304, 128, 0, stream>>>(A0, wpack + (size_t)6 * WSW,
                                         bpack + 6 * 64, nullptr, corep);

  kpn_fused7<<<576, 256, 0, stream>>>(corep, dpad, (float*)d_out);
}

// Round 18
// 193.799 us; speedup vs baseline: 5.1595x; 1.0117x over previous
//
#include <hip/hip_runtime.h>
#include <hip/hip_bf16.h>
#include <utility>

typedef __attribute__((ext_vector_type(4))) float f32x4;
typedef __attribute__((ext_vector_type(8))) short bf16x8;
typedef __attribute__((ext_vector_type(4))) unsigned short u16x4;
typedef unsigned short u16;

constexpr int HH = 384, WW = 384;
constexpr int AWP = 386;               // padded activation width (+1 halo each side)
constexpr int ASTR = AWP * 64;         // elements per padded activation row
constexpr int NPIX = HH * WW;          // 147456
constexpr int NPIX3 = NPIX * 3;        // 442368 (one output tensor)
constexpr int DP = 398, DPLANE = DP * DP;  // data padded by 7 each side
constexpr size_t ACT_BYTES = (size_t)AWP * AWP * 64 * 2;  // 19,071,488
constexpr int WSW = 72 * 512;          // swizzled weights per conv: 72 iters * 64 lanes * 8
constexpr int WP1N = 12 * 512;         // conv1 swizzled weights (K=96)

__device__ __forceinline__ u16 f2bf(float f) {
  union { __hip_bfloat16 h; u16 u; } v; v.h = __float2bfloat16(f); return v.u;
}
__device__ __forceinline__ float bf2f(u16 u) {
  union { float f; unsigned int i; } v; v.i = ((unsigned int)u) << 16; return v.f;
}

// ---------------- weight/bias repack ----------------
// wpack: 7 convs, A-frag order: iter=(tap*2+ich)*4+m; oc=m*16+(lane&15); ic=ich*32+(lane>>4)*8+j
// wp1: conv1 (6ic, K=96): iter=kb*4+m; oc=m*16+(lane&15); k=kb*32+(lane>>4)*8+j; tap=k/8, ic=k%8
__global__ void repack_kern(const float* __restrict__ w1, const float* __restrict__ w2,
                            const float* __restrict__ wo, const float* __restrict__ b1,
                            const float* __restrict__ b2, const float* __restrict__ bo,
                            const float* __restrict__ wf,
                            u16* __restrict__ wpack, float* __restrict__ bpack,
                            u16* __restrict__ wp1)
{
  const int idx = blockIdx.x * 256 + threadIdx.x;
  constexpr int NW = 7 * WSW;
  if (idx < NW) {
    const int c = idx / WSW;
    const int r = idx % WSW;
    const int iter = r / 512;
    const int lane = (r % 512) / 8;
    const int j = r % 8;
    const int tap = iter >> 3;
    const int ich = (iter >> 2) & 1;
    const int m = iter & 3;
    const int oc = m * 16 + (lane & 15);
    const int ic = ich * 32 + (lane >> 4) * 8 + j;
    float v;
    if (c < 6) {
      const float* s = (c & 1) ? w2 : w1;
      v = s[(((c >> 1) * 64 + oc) * 64 + ic) * 9 + tap];
    } else {
      v = (oc < 35) ? wo[(oc * 64 + ic) * 9 + tap] : 0.f;
    }
    wpack[idx] = f2bf(v);
  } else if (idx < NW + 448) {
    const int t = idx - NW;
    const int c = t / 64, oc = t % 64;
    float v;
    if (c < 6) v = ((c & 1) ? b2 : b1)[(c >> 1) * 64 + oc];
    else v = (oc < 35) ? bo[oc] : 0.f;
    bpack[t] = v;
  } else if (idx < NW + 448 + WP1N) {
    const int t = idx - NW - 448;
    const int iter = t / 512;
    const int lane = (t % 512) / 8;
    const int j = t % 8;
    const int m = iter & 3;
    const int kb = iter >> 2;
    const int oc = m * 16 + (lane & 15);
    const int k = kb * 32 + (lane >> 4) * 8 + j;
    const int tap = k >> 3, ic = k & 7;
    const float v = (tap < 9 && ic < 6) ? wf[oc * 54 + ic * 9 + tap] : 0.f;
    wp1[t] = f2bf(v);
  }
}

// ---------------- halo clear: only the border bytes (replaces 42MB of memsets) ----------------
__global__ void halo_kern(u16* __restrict__ A0, u16* __restrict__ A1,
                          u16* __restrict__ in8, float* __restrict__ dpad)
{
  const int idx = blockIdx.x * 256 + threadIdx.x;
  if (idx < 49280) {                       // A0/A1 border: 1540 px * 16 u16x4 each
    u16* buf = (idx < 24640) ? A0 : A1;
    const int t = (idx < 24640) ? idx : idx - 24640;
    const int pos = t >> 4, q = t & 15;
    int y, x;
    if (pos < 386) { y = 0; x = pos; }
    else if (pos < 772) { y = 385; x = pos - 386; }
    else if (pos < 1156) { y = pos - 772 + 1; x = 0; }
    else { y = pos - 1156 + 1; x = 385; }
    *(u16x4*)(buf + ((size_t)y * AWP + x) * 64 + q * 4) = u16x4{0, 0, 0, 0};
  } else if (idx < 49280 + 3080) {         // in8 border: 1540 px * 2 u16x4
    const int t = idx - 49280;
    const int pos = t >> 1, q = t & 1;
    int y, x;
    if (pos < 386) { y = 0; x = pos; }
    else if (pos < 772) { y = 385; x = pos - 386; }
    else if (pos < 1156) { y = pos - 772 + 1; x = 0; }
    else { y = pos - 1156 + 1; x = 385; }
    *(u16x4*)(in8 + ((size_t)y * AWP + x) * 8 + q * 4) = u16x4{0, 0, 0, 0};
  } else if (idx < 49280 + 3080 + 32844) { // dpad border width 7, 3 ch
    const int t = idx - 52360;
    const int c = t / 10948, r = t % 10948;
    int y, x;
    if (r < 2786) { y = r / 398; x = r % 398; }
    else if (r < 5572) { const int rr = r - 2786; y = 391 + rr / 398; x = rr % 398; }
    else { const int rr = r - 5572; y = 7 + rr / 14; const int k = rr % 14; x = (k < 7) ? k : 384 + k; }
    dpad[(size_t)c * DPLANE + (size_t)y * DP + x] = 0.f;
  }
}

// ---------------- pad-copy data (fp32, halo 7) ----------------
__global__ void padcopy_kern(const float* __restrict__ data, float* __restrict__ dpad)
{
  const int idx = blockIdx.x * 256 + threadIdx.x;  // exactly 442368 threads
  const int c = idx / NPIX, r = idx % NPIX;
  const int y = r / WW, x = r % WW;
  dpad[c * DPLANE + (y + 7) * DP + (x + 7)] = data[idx];
}

// ---------------- pad data_with_est to NHWC8 bf16 (halo 1, ic 6->8 zero) ----------------
__global__ void pad6_kern(const float* __restrict__ din, u16* __restrict__ in8)
{
  const int px = blockIdx.x * 256 + threadIdx.x;   // 576*256 = NPIX exactly
  const int y = px / WW, x = px % WW;
  u16 vals[8];
  #pragma unroll
  for (int ic = 0; ic < 6; ++ic) vals[ic] = f2bf(din[ic * NPIX + px]);
  vals[6] = 0; vals[7] = 0;
  u16* o = in8 + ((size_t)(y + 1) * AWP + (x + 1)) * 8;
  *(u16x4*)(o) = u16x4{vals[0], vals[1], vals[2], vals[3]};
  *(u16x4*)(o + 4) = u16x4{vals[4], vals[5], vals[6], vals[7]};
}

// ---------------- conv1 via MFMA: 8ch NHWC bf16 -> 64, K=96 ----------------
__global__ __launch_bounds__(64)
void conv1_mfma(const u16* __restrict__ in8, const u16* __restrict__ wp,
                const float* __restrict__ bias, u16* __restrict__ outb)
{
  const int lane = threadIdx.x;
  const int l15 = lane & 15, g8 = lane >> 4;
  // XCD swizzle: 2304 = 8 * 288
  const int bid = blockIdx.x;
  const int sw = (bid & 7) * 288 + (bid >> 3);
  const int y = sw / 6;
  const int x0 = (sw % 6) * 64;

  f32x4 acc[4][4];
  #pragma unroll
  for (int m = 0; m < 4; ++m)
    #pragma unroll
    for (int n = 0; n < 4; ++n)
      acc[m][n] = f32x4{0.f, 0.f, 0.f, 0.f};

  #pragma unroll
  for (int kb = 0; kb < 3; ++kb) {
    const int tap = kb * 4 + g8;
    const int vt = tap < 9 ? tap : 0;                // dup tap0 for pad (weights are 0)
    const int kr = vt / 3, kc = vt % 3;
    const u16* inr = in8 + ((size_t)(y + kr) * AWP + x0 + kc) * 8;
    bf16x8 a[4], b[4];
    #pragma unroll
    for (int m = 0; m < 4; ++m)
      a[m] = *(const bf16x8*)(wp + (kb * 4 + m) * 512 + lane * 8);
    #pragma unroll
    for (int n = 0; n < 4; ++n)
      b[n] = *(const bf16x8*)(inr + (size_t)(n * 16 + l15) * 8);
    #pragma unroll
    for (int m = 0; m < 4; ++m)
      #pragma unroll
      for (int n = 0; n < 4; ++n)
        acc[m][n] = __builtin_amdgcn_mfma_f32_16x16x32_bf16(a[m], b[n], acc[m][n], 0, 0, 0);
  }

  const int oc_lo = g8 * 4;
  #pragma unroll
  for (int m = 0; m < 4; ++m) {
    const int oc0 = m * 16 + oc_lo;
    const f32x4 bv = *(const f32x4*)(bias + oc0);
    #pragma unroll
    for (int n = 0; n < 4; ++n) {
      const int px = x0 + n * 16 + l15;
      const f32x4 v = acc[m][n] + bv;
      u16x4 s;
      #pragma unroll
      for (int j = 0; j < 4; ++j) s[j] = f2bf(v[j]);
      *(u16x4*)(outb + ((size_t)(y + 1) * AWP + (px + 1)) * 64 + oc0) = s;
    }
  }
}

// ---------------- MFMA implicit-GEMM 3x3 conv: 2 rows/block, 4 waves, LDS-staged B ----------------
// Wave (r,ich) = (wv>>1, wv&1). Stages 4 input rows (36.9 KB) once for 2 output rows
// (288 staged B/px vs 432 in the 1-row version); A-loads amortized 2x; 4 blocks/CU.
// Per-wave register set identical to the proven R14 kernel (one acc[4][4]).
// MODE 0: +bias, relu; MODE 1: +bias,+residual; MODE 2: +bias, f32 planar (oc<35)
template<int MODE>
__global__ __launch_bounds__(256, 3)
void conv_mfma(const u16* __restrict__ in, const u16* __restrict__ wp,
               const float* __restrict__ bias, u16* __restrict__ outb,
               float* __restrict__ outf)
{
  __shared__ u16 smem[4 * 72 * 64];                // 36864 B; reused as 2x16KB red buffers
  const int lane = threadIdx.x & 63;
  const int wv = threadIdx.x >> 6;                 // 0..3
  const int r = wv >> 1;                           // output row within pair
  const int ich = wv & 1;                          // K-half
  const int l15 = lane & 15, g8 = lane >> 4;
  // XCD-aware swizzle: 1152 blocks = 8 XCDs * 144 (24 row-pairs * 6 col-blocks)
  const int bid = blockIdx.x;
  const int sw = (bid & 7) * 144 + (bid >> 3);
  const int y0 = (sw / 6) * 2;                     // 0..382 step 2
  const int x0 = (sw % 6) * 64;

  // ---- stage 4 rows x 9KB, 1KB per global_load_lds, 9 per wave ----
  {
    const int pxl = lane >> 3;                     // px sub-index within 1KB (0..7)
    const int s = lane & 7;                        // 16B slot (0..7)
    #pragma unroll
    for (int row = 0; row < 4; ++row) {
      const char* gbase = (const char*)(in + (size_t)(y0 + row) * ASTR + (size_t)x0 * 64);
      #pragma unroll
      for (int j = 0; j < 9; ++j) {
        if (((row * 9 + j) & 3) == wv) {
          const int px = j * 8 + pxl;              // 0..71
          const char* g = gbase + px * 128 + ((s ^ (px & 7)) << 4);
          __builtin_amdgcn_global_load_lds(
              (__attribute__((address_space(1))) const void*)g,
              (__attribute__((address_space(3))) void*)((char*)smem + row * 9216 + j * 1024),
              16, 0, 0);
        }
      }
    }
  }
  __syncthreads();

  f32x4 acc[4][4];
  #pragma unroll
  for (int m = 0; m < 4; ++m)
    #pragma unroll
    for (int n = 0; n < 4; ++n)
      acc[m][n] = f32x4{0.f, 0.f, 0.f, 0.f};

  const int chunk = ich * 4 + g8;                  // 16B chunk within a pixel's 128B
  #pragma unroll
  for (int tap = 0; tap < 9; ++tap) {
    const int kr = tap / 3, kc = tap % 3;
    const u16* wpi = wp + ((tap * 2 + ich) * 4) * 512 + lane * 8;  // coalesced A-frags
    bf16x8 a[4], b[4];
    #pragma unroll
    for (int m = 0; m < 4; ++m)
      a[m] = *(const bf16x8*)(wpi + m * 512);
    #pragma unroll
    for (int n = 0; n < 4; ++n) {
      const int p = kc + n * 16 + l15;             // 0..65 within staged row
      const char* bp = (const char*)smem + (r + kr) * 9216 + p * 128 + ((chunk ^ (p & 7)) << 4);
      b[n] = *(const bf16x8*)bp;
    }
    #pragma unroll
    for (int m = 0; m < 4; ++m)
      #pragma unroll
      for (int n = 0; n < 4; ++n)
        acc[m][n] = __builtin_amdgcn_mfma_f32_16x16x32_bf16(a[m], b[n], acc[m][n], 0, 0, 0);
  }

  __syncthreads();                                 // all b-reads done before smem reuse
  float* red = (float*)smem;                       // 2 x 16 KB reduction buffers (reuse)
  if (ich == 1) {
    #pragma unroll
    for (int m = 0; m < 4; ++m)
      #pragma unroll
      for (int n = 0; n < 4; ++n)
        *(f32x4*)(red + r * 4096 + (m * 4 + n) * 256 + lane * 4) = acc[m][n];
  }
  __syncthreads();
  if (ich == 1) return;

  const int y = y0 + r;
  const int oc_lo = g8 * 4;
  #pragma unroll
  for (int m = 0; m < 4; ++m) {
    const int oc0 = m * 16 + oc_lo;                // D row = (lane>>4)*4 + reg
    const f32x4 bv = *(const f32x4*)(bias + oc0);
    #pragma unroll
    for (int n = 0; n < 4; ++n) {
      const int px = x0 + n * 16 + l15;            // D col = lane&15
      f32x4 v = acc[m][n] + *(const f32x4*)(red + r * 4096 + (m * 4 + n) * 256 + lane * 4) + bv;
      if constexpr (MODE == 0) {
        #pragma unroll
        for (int j = 0; j < 4; ++j) v[j] = v[j] > 0.f ? v[j] : 0.f;
      }
      if constexpr (MODE == 1) {
        const u16x4 rr = *(const u16x4*)(outb + ((size_t)(y + 1) * AWP + (px + 1)) * 64 + oc0);
        #pragma unroll
        for (int j = 0; j < 4; ++j) v[j] += bf2f(rr[j]);
      }
      if constexpr (MODE <= 1) {
        u16x4 s;
        #pragma unroll
        for (int j = 0; j < 4; ++j) s[j] = f2bf(v[j]);
        *(u16x4*)(outb + ((size_t)(y + 1) * AWP + (px + 1)) * 64 + oc0) = s;
      } else {
        #pragma unroll
        for (int j = 0; j < 4; ++j) {
          const int oc = oc0 + j;
          if (oc < 35) outf[(size_t)oc * NPIX + (size_t)y * WW + px] = v[j];
        }
      }
    }
  }
}

// ---------------- KPN apply: template-fold sweep (guaranteed static indexing) ----------------
constexpr int isqrt_(int d2) { int li = 0; while ((li + 1) * (li + 1) <= d2) ++li; return li; }
constexpr double csqrt_(double x) {
  double g = x < 1.0 ? 1.0 : x;
  for (int i = 0; i < 60; ++i) g = 0.5 * (g + x / g);
  return g;
}
constexpr int KOFFS[7] = {0, 2, 5, 9, 14, 20, 27};

template<int SEC0, int NSEC, int CKN, int A, int B, int T>
__device__ __forceinline__ void kpn_sec_one(const float (&g)[3], const float (&ck)[CKN],
                                            float (&s)[NSEC], float (&p)[NSEC][3])
{
  constexpr int WIDE = SEC0 + T + 2;
  if constexpr (A < WIDE && B < WIDE) {
    constexpr int d2 = A * A + B * B;
    constexpr int li = isqrt_(d2);
    constexpr bool exact = (li * li == d2);
    constexpr int hraw = exact ? li : li + 1;
    constexpr float dd = (float)csqrt_((double)d2);
    constexpr float wlo = exact ? 1.0f : ((float)hraw - dd);
    constexpr float whi = exact ? 0.0f : (dd - (float)li);
    constexpr float mult = ((A > 0) ? 2.0f : 1.0f) * ((B > 0) ? 2.0f : 1.0f);
    constexpr int lidx = li < WIDE - 1 ? li : WIDE - 1;
    constexpr int hidx = hraw < WIDE - 1 ? hraw : WIDE - 1;
    constexpr bool msk = d2 <= (WIDE - 1) * (WIDE - 1);
    constexpr int cb = KOFFS[SEC0 + T] - KOFFS[SEC0];
    float e;
    if constexpr (msk) e = __expf(wlo * ck[cb + lidx] + whi * ck[cb + hidx]);
    else e = 1.0f;                                   // masked: logit 0, still in softmax
    s[T] += mult * e;
    p[T][0] += e * g[0];
    p[T][1] += e * g[1];
    p[T][2] += e * g[2];
  }
}

template<int SEC0, int NSEC, int CKN, int A, int B, int... Ts>
__device__ __forceinline__ void kpn_secs(std::integer_sequence<int, Ts...>,
                                         const float (&g)[3], const float (&ck)[CKN],
                                         float (&s)[NSEC], float (&p)[NSEC][3])
{
  (kpn_sec_one<SEC0, NSEC, CKN, A, B, Ts>(g, ck, s, p), ...);
}

template<int SEC0, int NSEC, int CKN, int WMAX, int C>
__device__ __forceinline__ void kpn_cell(const float* __restrict__ base,
                                         const float (&ck)[CKN],
                                         float (&s)[NSEC], float (&p)[NSEC][3])
{
  constexpr int A = C / WMAX, B = C % WMAX;
  float g[3];
  #pragma unroll
  for (int c = 0; c < 3; ++c) {
    const float* bc = base + c * DPLANE;
    float v = bc[A * DP + B];
    if constexpr (B > 0) v += bc[A * DP - B];
    if constexpr (A > 0) v += bc[-A * DP + B];
    if constexpr (A > 0 && B > 0) v += bc[-A * DP - B];
    g[c] = v;
  }
  kpn_secs<SEC0, NSEC, CKN, A, B>(std::make_integer_sequence<int, NSEC>{}, g, ck, s, p);
}

template<int SEC0, int NSEC, int CKN, int WMAX, int... Cs>
__device__ __forceinline__ void kpn_cells(std::integer_sequence<int, Cs...>,
                                          const float* __restrict__ base,
                                          const float (&ck)[CKN],
                                          float (&s)[NSEC], float (&p)[NSEC][3])
{
  (kpn_cell<SEC0, NSEC, CKN, WMAX, Cs>(base, ck, s, p), ...);
}

template<int SEC0, int NSEC>
__device__ __forceinline__ void kpn_grp_body(const float* __restrict__ corep,
                                             const float* __restrict__ dpad,
                                             float* __restrict__ out)
{
  constexpr int WMAX = SEC0 + NSEC + 1;          // widest WIDE in this group
  constexpr int CK0 = KOFFS[SEC0];
  constexpr int CKN = KOFFS[SEC0 + NSEC - 1] + (SEC0 + NSEC + 1) - CK0;

  // XCD-contiguous band swizzle: 576 = 8 XCDs * 72 blocks (48 rows each) ->
  // per-XCD corep slice (~2.6MB) + dpad band fit the private 4MB L2.
  const int bid = blockIdx.x;
  const int sw = (bid & 7) * 72 + (bid >> 3);
  const int px = sw * 256 + threadIdx.x;              // 576*256 = NPIX exactly
  const int y = px / WW, x = px % WW;
  const float* base = dpad + (size_t)(y + 7) * DP + (x + 7);

  float ck[CKN];
  #pragma unroll
  for (int i = 0; i < CKN; ++i) ck[i] = fabsf(corep[(size_t)(CK0 + i) * NPIX + px]);

  float s[NSEC], p[NSEC][3];
  #pragma unroll
  for (int k = 0; k < NSEC; ++k) { s[k] = 0.f; p[k][0] = 0.f; p[k][1] = 0.f; p[k][2] = 0.f; }

  kpn_cells<SEC0, NSEC, CKN, WMAX>(std::make_integer_sequence<int, WMAX * WMAX>{},
                                   base, ck, s, p);

  #pragma unroll
  for (int t = 0; t < NSEC; ++t) {
    const float inv = 1.f / s[t];
    float* o = out + (size_t)(SEC0 + t + 1) * NPIX3 + px;
    o[0] = p[t][0] * inv;
    o[NPIX] = p[t][1] * inv;
    o[2 * NPIX] = p[t][2] * inv;
  }
}

// Full 7-section fusion: shares all mirror-gathers across sections (675 loads/px
// vs 1182 for the 2-group split). Template-fold keeps all indices static.
__global__ __launch_bounds__(256, 2)
void kpn_fused7(const float* __restrict__ corep, const float* __restrict__ dpad,
                float* __restrict__ out)
{
  kpn_grp_body<0, 7>(corep, dpad, out);
}

// ---------------- launch ----------------
extern "C" void kernel_launch(void* const* d_in, const int* in_sizes, int n_in,
                              void* d_out, int out_size, void* d_ws, size_t ws_size,
                              hipStream_t stream)
{
  const float* d_est   = (const float*)d_in[0];
  const float* data    = (const float*)d_in[1];
  const float* w_first = (const float*)d_in[2];
  const float* b_first = (const float*)d_in[3];
  const float* w_blk1  = (const float*)d_in[4];
  const float* b_blk1  = (const float*)d_in[5];
  const float* w_blk2  = (const float*)d_in[6];
  const float* b_blk2  = (const float*)d_in[7];
  const float* w_out   = (const float*)d_in[8];
  const float* b_out   = (const float*)d_in[9];

  char* ws = (char*)d_ws;
  const size_t OFF_A1    = ACT_BYTES;
  const size_t OFF_CORE  = 2 * ACT_BYTES;
  const size_t OFF_DPAD  = OFF_CORE + (size_t)35 * NPIX * 4;
  const size_t OFF_WPACK = OFF_DPAD + (size_t)3 * DPLANE * 4;
  const size_t OFF_BPACK = OFF_WPACK + (size_t)7 * WSW * 2;
  const size_t OFF_WP1   = OFF_BPACK + 448 * 4;
  const size_t OFF_IN8   = OFF_WP1 + (size_t)WP1N * 2;

  u16*   A0    = (u16*)(ws);
  u16*   A1    = (u16*)(ws + OFF_A1);
  float* corep = (float*)(ws + OFF_CORE);
  float* dpad  = (float*)(ws + OFF_DPAD);
  u16*   wpack = (u16*)(ws + OFF_WPACK);
  float* bpack = (float*)(ws + OFF_BPACK);
  u16*   wp1   = (u16*)(ws + OFF_WP1);
  u16*   in8   = (u16*)(ws + OFF_IN8);

  // output 0 is an exact copy of `data`
  hipMemcpyAsync(d_out, data, (size_t)NPIX3 * 4, hipMemcpyDeviceToDevice, stream);

  halo_kern<<<333, 256, 0, stream>>>(A0, A1, in8, dpad);
  repack_kern<<<1034, 256, 0, stream>>>(w_blk1, w_blk2, w_out, b_blk1, b_blk2, b_out,
                                        w_first, wpack, bpack, wp1);
  padcopy_kern<<<1728, 256, 0, stream>>>(data, dpad);
  pad6_kern<<<576, 256, 0, stream>>>(d_est, in8);
  conv1_mfma<<<2304, 64, 0, stream>>>(in8, wp1, b_first, A0);

  for (int i = 0; i < 3; ++i) {
    conv_mfma<0><<<1152, 256, 0, stream>>>(A0, wpack + (size_t)(2 * i) * WSW,
                                           bpack + (2 * i) * 64, A1, nullptr);
    conv_mfma<1><<<1152, 256, 0, stream>>>(A1, wpack + (size_t)(2 * i + 1) * WSW,
                                           bpack + (2 * i + 1) * 64, A0, nullptr);
  }
  conv_mfma<2><<<1152, 256, 0, stream>>>(A0, wpack + (size_t)6 * WSW,
                                         bpack + 6 * 64, nullptr, corep);

  kpn_fused7<<<576, 256, 0, stream>>>(corep, dpad, (float*)d_out);
}

// Round 19
// 183.072 us; speedup vs baseline: 5.4619x; 1.0586x over previous
//
#include <hip/hip_runtime.h>
#include <hip/hip_bf16.h>
#include <utility>

typedef __attribute__((ext_vector_type(4))) float f32x4;
typedef __attribute__((ext_vector_type(8))) short bf16x8;
typedef __attribute__((ext_vector_type(4))) unsigned short u16x4;
typedef unsigned short u16;

constexpr int HH = 384, WW = 384;
constexpr int AWP = 386;               // padded activation width (+1 halo each side)
constexpr int ASTR = AWP * 64;         // elements per padded activation row
constexpr int NPIX = HH * WW;          // 147456
constexpr int NPIX3 = NPIX * 3;        // 442368 (one output tensor)
constexpr int DP = 398, DPLANE = DP * DP;  // data padded by 7 each side
constexpr size_t ACT_BYTES = (size_t)AWP * AWP * 64 * 2;  // 19,071,488
constexpr int WSW = 72 * 512;          // swizzled weights per conv: 72 iters * 64 lanes * 8
constexpr int WP1N = 12 * 512;         // conv1 swizzled weights (K=96)

__device__ __forceinline__ u16 f2bf(float f) {
  union { __hip_bfloat16 h; u16 u; } v; v.h = __float2bfloat16(f); return v.u;
}
__device__ __forceinline__ float bf2f(u16 u) {
  union { float f; unsigned int i; } v; v.i = ((unsigned int)u) << 16; return v.f;
}

// ---------------- fused preprocessing: repack + padcopy + pad6 + halo ----------------
// All four phases are independent (distinct output buffers) -> one kernel, index ranges.
constexpr int PR_REPACK = 7 * WSW + 448 + WP1N;          // 264640
constexpr int PR_PADCOPY = PR_REPACK + NPIX3;            // +442368 = 707008
constexpr int PR_PAD6 = PR_PADCOPY + NPIX;               // +147456 = 854464
constexpr int PR_HALO = PR_PAD6 + 49280 + 3080 + 32844;  // +85204 = 939668

__global__ void prep_kern(const float* __restrict__ w1, const float* __restrict__ w2,
                          const float* __restrict__ wo, const float* __restrict__ b1,
                          const float* __restrict__ b2, const float* __restrict__ bo,
                          const float* __restrict__ wf, const float* __restrict__ data,
                          const float* __restrict__ din6,
                          u16* __restrict__ wpack, float* __restrict__ bpack,
                          u16* __restrict__ wp1, float* __restrict__ dpad,
                          u16* __restrict__ in8, u16* __restrict__ A0,
                          u16* __restrict__ A1)
{
  const int gidx = blockIdx.x * 256 + threadIdx.x;
  if (gidx < PR_REPACK) {
    const int idx = gidx;
    constexpr int NW = 7 * WSW;
    if (idx < NW) {
      const int c = idx / WSW;
      const int r = idx % WSW;
      const int iter = r / 512;
      const int lane = (r % 512) / 8;
      const int j = r % 8;
      const int tap = iter >> 3;
      const int ich = (iter >> 2) & 1;
      const int m = iter & 3;
      const int oc = m * 16 + (lane & 15);
      const int ic = ich * 32 + (lane >> 4) * 8 + j;
      float v;
      if (c < 6) {
        const float* s = (c & 1) ? w2 : w1;
        v = s[(((c >> 1) * 64 + oc) * 64 + ic) * 9 + tap];
      } else {
        v = (oc < 35) ? wo[(oc * 64 + ic) * 9 + tap] : 0.f;
      }
      wpack[idx] = f2bf(v);
    } else if (idx < NW + 448) {
      const int t = idx - NW;
      const int c = t / 64, oc = t % 64;
      float v;
      if (c < 6) v = ((c & 1) ? b2 : b1)[(c >> 1) * 64 + oc];
      else v = (oc < 35) ? bo[oc] : 0.f;
      bpack[t] = v;
    } else {
      const int t = idx - NW - 448;
      const int iter = t / 512;
      const int lane = (t % 512) / 8;
      const int j = t % 8;
      const int m = iter & 3;
      const int kb = iter >> 2;
      const int oc = m * 16 + (lane & 15);
      const int k = kb * 32 + (lane >> 4) * 8 + j;
      const int tap = k >> 3, ic = k & 7;
      const float v = (tap < 9 && ic < 6) ? wf[oc * 54 + ic * 9 + tap] : 0.f;
      wp1[t] = f2bf(v);
    }
  } else if (gidx < PR_PADCOPY) {
    const int idx = gidx - PR_REPACK;
    const int c = idx / NPIX, r = idx % NPIX;
    const int y = r / WW, x = r % WW;
    dpad[c * DPLANE + (y + 7) * DP + (x + 7)] = data[idx];
  } else if (gidx < PR_PAD6) {
    const int px = gidx - PR_PADCOPY;
    const int y = px / WW, x = px % WW;
    u16 vals[8];
    #pragma unroll
    for (int ic = 0; ic < 6; ++ic) vals[ic] = f2bf(din6[ic * NPIX + px]);
    vals[6] = 0; vals[7] = 0;
    u16* o = in8 + ((size_t)(y + 1) * AWP + (x + 1)) * 8;
    *(u16x4*)(o) = u16x4{vals[0], vals[1], vals[2], vals[3]};
    *(u16x4*)(o + 4) = u16x4{vals[4], vals[5], vals[6], vals[7]};
  } else if (gidx < PR_HALO) {
    const int idx = gidx - PR_PAD6;
    if (idx < 49280) {                       // A0/A1 border: 1540 px * 16 u16x4 each
      u16* buf = (idx < 24640) ? A0 : A1;
      const int t = (idx < 24640) ? idx : idx - 24640;
      const int pos = t >> 4, q = t & 15;
      int y, x;
      if (pos < 386) { y = 0; x = pos; }
      else if (pos < 772) { y = 385; x = pos - 386; }
      else if (pos < 1156) { y = pos - 772 + 1; x = 0; }
      else { y = pos - 1156 + 1; x = 385; }
      *(u16x4*)(buf + ((size_t)y * AWP + x) * 64 + q * 4) = u16x4{0, 0, 0, 0};
    } else if (idx < 49280 + 3080) {         // in8 border: 1540 px * 2 u16x4
      const int t = idx - 49280;
      const int pos = t >> 1, q = t & 1;
      int y, x;
      if (pos < 386) { y = 0; x = pos; }
      else if (pos < 772) { y = 385; x = pos - 386; }
      else if (pos < 1156) { y = pos - 772 + 1; x = 0; }
      else { y = pos - 1156 + 1; x = 385; }
      *(u16x4*)(in8 + ((size_t)y * AWP + x) * 8 + q * 4) = u16x4{0, 0, 0, 0};
    } else {                                 // dpad border width 7, 3 ch
      const int t = idx - 52360;
      const int c = t / 10948, r = t % 10948;
      int y, x;
      if (r < 2786) { y = r / 398; x = r % 398; }
      else if (r < 5572) { const int rr = r - 2786; y = 391 + rr / 398; x = rr % 398; }
      else { const int rr = r - 5572; y = 7 + rr / 14; const int k = rr % 14; x = (k < 7) ? k : 384 + k; }
      dpad[(size_t)c * DPLANE + (size_t)y * DP + x] = 0.f;
    }
  }
}

// ---------------- conv1 via MFMA: 8ch NHWC bf16 -> 64, K=96 ----------------
__global__ __launch_bounds__(64)
void conv1_mfma(const u16* __restrict__ in8, const u16* __restrict__ wp,
                const float* __restrict__ bias, u16* __restrict__ outb)
{
  const int lane = threadIdx.x;
  const int l15 = lane & 15, g8 = lane >> 4;
  // XCD swizzle: 2304 = 8 * 288
  const int bid = blockIdx.x;
  const int sw = (bid & 7) * 288 + (bid >> 3);
  const int y = sw / 6;
  const int x0 = (sw % 6) * 64;

  f32x4 acc[4][4];
  #pragma unroll
  for (int m = 0; m < 4; ++m)
    #pragma unroll
    for (int n = 0; n < 4; ++n)
      acc[m][n] = f32x4{0.f, 0.f, 0.f, 0.f};

  #pragma unroll
  for (int kb = 0; kb < 3; ++kb) {
    const int tap = kb * 4 + g8;
    const int vt = tap < 9 ? tap : 0;                // dup tap0 for pad (weights are 0)
    const int kr = vt / 3, kc = vt % 3;
    const u16* inr = in8 + ((size_t)(y + kr) * AWP + x0 + kc) * 8;
    bf16x8 a[4], b[4];
    #pragma unroll
    for (int m = 0; m < 4; ++m)
      a[m] = *(const bf16x8*)(wp + (kb * 4 + m) * 512 + lane * 8);
    #pragma unroll
    for (int n = 0; n < 4; ++n)
      b[n] = *(const bf16x8*)(inr + (size_t)(n * 16 + l15) * 8);
    #pragma unroll
    for (int m = 0; m < 4; ++m)
      #pragma unroll
      for (int n = 0; n < 4; ++n)
        acc[m][n] = __builtin_amdgcn_mfma_f32_16x16x32_bf16(a[m], b[n], acc[m][n], 0, 0, 0);
  }

  const int oc_lo = g8 * 4;
  #pragma unroll
  for (int m = 0; m < 4; ++m) {
    const int oc0 = m * 16 + oc_lo;
    const f32x4 bv = *(const f32x4*)(bias + oc0);
    #pragma unroll
    for (int n = 0; n < 4; ++n) {
      const int px = x0 + n * 16 + l15;
      const f32x4 v = acc[m][n] + bv;
      u16x4 s;
      #pragma unroll
      for (int j = 0; j < 4; ++j) s[j] = f2bf(v[j]);
      *(u16x4*)(outb + ((size_t)(y + 1) * AWP + (px + 1)) * 64 + oc0) = s;
    }
  }
}

// ---------------- MFMA implicit-GEMM 3x3 conv: 128-px tile, 4 waves, LDS-staged B ----------------
// Wave (pxh, ich): px-half 64 px, K-half ich. Halves per-px A-traffic vs 64-px tile
// (72 KB weights/block serve 128 px). Per-wave regs identical to proven R14 kernel.
// Stage 3 rows x 136 px (52.2 KB), XOR swizzle chunk^=px&7 (both-sides rule).
// MODE 0: +bias, relu; MODE 1: +bias,+residual; MODE 2: +bias, f32 planar (oc<35)
template<int MODE>
__global__ __launch_bounds__(256, 3)
void conv_mfma(const u16* __restrict__ in, const u16* __restrict__ wp,
               const float* __restrict__ bias, u16* __restrict__ outb,
               float* __restrict__ outf)
{
  __shared__ u16 smem[3 * 136 * 64];               // 52224 B; reused as 2x16KB red buffers
  const int lane = threadIdx.x & 63;
  const int wv = threadIdx.x >> 6;                 // 0..3
  const int pxh = wv >> 1;                         // px half (0: px 0-63, 1: px 64-127)
  const int ich = wv & 1;                          // K-half
  const int l15 = lane & 15, g8 = lane >> 4;
  // XCD band swizzle: 1152 = 8 XCDs * 144 (48 rows * 3 col-blocks of 128 px)
  const int bid = blockIdx.x;
  const int sw = (bid & 7) * 144 + (bid >> 3);
  const int y = sw / 3;
  const int x0 = (sw % 3) * 128;

  // ---- stage 3 rows x 17 KB (136 px), 1KB per global_load_lds, 51 loads / 4 waves ----
  {
    const int pxl = lane >> 3;                     // px sub-index within 1KB (0..7)
    const int s = lane & 7;                        // 16B slot (0..7)
    #pragma unroll
    for (int row = 0; row < 3; ++row) {
      const char* gbase = (const char*)(in + (size_t)(y + row) * ASTR + (size_t)x0 * 64);
      #pragma unroll
      for (int j = 0; j < 17; ++j) {
        if (((row * 17 + j) & 3) == wv) {
          const int px = j * 8 + pxl;              // 0..135 (reads beyond col 129 unused)
          const char* g = gbase + px * 128 + ((s ^ (px & 7)) << 4);
          __builtin_amdgcn_global_load_lds(
              (__attribute__((address_space(1))) const void*)g,
              (__attribute__((address_space(3))) void*)((char*)smem + row * 17408 + j * 1024),
              16, 0, 0);
        }
      }
    }
  }
  __syncthreads();

  f32x4 acc[4][4];
  #pragma unroll
  for (int m = 0; m < 4; ++m)
    #pragma unroll
    for (int n = 0; n < 4; ++n)
      acc[m][n] = f32x4{0.f, 0.f, 0.f, 0.f};

  const int chunk = ich * 4 + g8;                  // 16B chunk within a pixel's 128B
  #pragma unroll
  for (int tap = 0; tap < 9; ++tap) {
    const int kr = tap / 3, kc = tap % 3;
    const u16* wpi = wp + ((tap * 2 + ich) * 4) * 512 + lane * 8;  // coalesced A-frags
    bf16x8 a[4], b[4];
    #pragma unroll
    for (int m = 0; m < 4; ++m)
      a[m] = *(const bf16x8*)(wpi + m * 512);
    #pragma unroll
    for (int n = 0; n < 4; ++n) {
      const int p = pxh * 64 + kc + n * 16 + l15;  // 0..129 within staged row
      const char* bp = (const char*)smem + kr * 17408 + p * 128 + ((chunk ^ (p & 7)) << 4);
      b[n] = *(const bf16x8*)bp;
    }
    #pragma unroll
    for (int m = 0; m < 4; ++m)
      #pragma unroll
      for (int n = 0; n < 4; ++n)
        acc[m][n] = __builtin_amdgcn_mfma_f32_16x16x32_bf16(a[m], b[n], acc[m][n], 0, 0, 0);
  }

  __syncthreads();                                 // all b-reads done before smem reuse
  float* red = (float*)smem;                       // 2 x 16 KB reduction buffers (reuse)
  if (ich == 1) {
    #pragma unroll
    for (int m = 0; m < 4; ++m)
      #pragma unroll
      for (int n = 0; n < 4; ++n)
        *(f32x4*)(red + pxh * 4096 + (m * 4 + n) * 256 + lane * 4) = acc[m][n];
  }
  __syncthreads();
  if (ich == 1) return;

  const int oc_lo = g8 * 4;
  #pragma unroll
  for (int m = 0; m < 4; ++m) {
    const int oc0 = m * 16 + oc_lo;                // D row = (lane>>4)*4 + reg
    const f32x4 bv = *(const f32x4*)(bias + oc0);
    #pragma unroll
    for (int n = 0; n < 4; ++n) {
      const int px = x0 + pxh * 64 + n * 16 + l15; // D col = lane&15
      f32x4 v = acc[m][n] + *(const f32x4*)(red + pxh * 4096 + (m * 4 + n) * 256 + lane * 4) + bv;
      if constexpr (MODE == 0) {
        #pragma unroll
        for (int j = 0; j < 4; ++j) v[j] = v[j] > 0.f ? v[j] : 0.f;
      }
      if constexpr (MODE == 1) {
        const u16x4 rr = *(const u16x4*)(outb + ((size_t)(y + 1) * AWP + (px + 1)) * 64 + oc0);
        #pragma unroll
        for (int j = 0; j < 4; ++j) v[j] += bf2f(rr[j]);
      }
      if constexpr (MODE <= 1) {
        u16x4 s;
        #pragma unroll
        for (int j = 0; j < 4; ++j) s[j] = f2bf(v[j]);
        *(u16x4*)(outb + ((size_t)(y + 1) * AWP + (px + 1)) * 64 + oc0) = s;
      } else {
        #pragma unroll
        for (int j = 0; j < 4; ++j) {
          const int oc = oc0 + j;
          if (oc < 35) outf[(size_t)oc * NPIX + (size_t)y * WW + px] = v[j];
        }
      }
    }
  }
}

// ---------------- KPN apply: template-fold sweep (guaranteed static indexing) ----------------
constexpr int isqrt_(int d2) { int li = 0; while ((li + 1) * (li + 1) <= d2) ++li; return li; }
constexpr double csqrt_(double x) {
  double g = x < 1.0 ? 1.0 : x;
  for (int i = 0; i < 60; ++i) g = 0.5 * (g + x / g);
  return g;
}
constexpr int KOFFS[7] = {0, 2, 5, 9, 14, 20, 27};

template<int SEC0, int NSEC, int CKN, int A, int B, int T>
__device__ __forceinline__ void kpn_sec_one(const float (&g)[3], const float (&ck)[CKN],
                                            float (&s)[NSEC], float (&p)[NSEC][3])
{
  constexpr int WIDE = SEC0 + T + 2;
  if constexpr (A < WIDE && B < WIDE) {
    constexpr int d2 = A * A + B * B;
    constexpr int li = isqrt_(d2);
    constexpr bool exact = (li * li == d2);
    constexpr int hraw = exact ? li : li + 1;
    constexpr float dd = (float)csqrt_((double)d2);
    constexpr float wlo = exact ? 1.0f : ((float)hraw - dd);
    constexpr float whi = exact ? 0.0f : (dd - (float)li);
    constexpr float mult = ((A > 0) ? 2.0f : 1.0f) * ((B > 0) ? 2.0f : 1.0f);
    constexpr int lidx = li < WIDE - 1 ? li : WIDE - 1;
    constexpr int hidx = hraw < WIDE - 1 ? hraw : WIDE - 1;
    constexpr bool msk = d2 <= (WIDE - 1) * (WIDE - 1);
    constexpr int cb = KOFFS[SEC0 + T] - KOFFS[SEC0];
    float e;
    if constexpr (msk) e = __expf(wlo * ck[cb + lidx] + whi * ck[cb + hidx]);
    else e = 1.0f;                                   // masked: logit 0, still in softmax
    s[T] += mult * e;
    p[T][0] += e * g[0];
    p[T][1] += e * g[1];
    p[T][2] += e * g[2];
  }
}

template<int SEC0, int NSEC, int CKN, int A, int B, int... Ts>
__device__ __forceinline__ void kpn_secs(std::integer_sequence<int, Ts...>,
                                         const float (&g)[3], const float (&ck)[CKN],
                                         float (&s)[NSEC], float (&p)[NSEC][3])
{
  (kpn_sec_one<SEC0, NSEC, CKN, A, B, Ts>(g, ck, s, p), ...);
}

template<int SEC0, int NSEC, int CKN, int WMAX, int C>
__device__ __forceinline__ void kpn_cell(const float* __restrict__ base,
                                         const float (&ck)[CKN],
                                         float (&s)[NSEC], float (&p)[NSEC][3])
{
  constexpr int A = C / WMAX, B = C % WMAX;
  float g[3];
  #pragma unroll
  for (int c = 0; c < 3; ++c) {
    const float* bc = base + c * DPLANE;
    float v = bc[A * DP + B];
    if constexpr (B > 0) v += bc[A * DP - B];
    if constexpr (A > 0) v += bc[-A * DP + B];
    if constexpr (A > 0 && B > 0) v += bc[-A * DP - B];
    g[c] = v;
  }
  kpn_secs<SEC0, NSEC, CKN, A, B>(std::make_integer_sequence<int, NSEC>{}, g, ck, s, p);
}

template<int SEC0, int NSEC, int CKN, int WMAX, int... Cs>
__device__ __forceinline__ void kpn_cells(std::integer_sequence<int, Cs...>,
                                          const float* __restrict__ base,
                                          const float (&ck)[CKN],
                                          float (&s)[NSEC], float (&p)[NSEC][3])
{
  (kpn_cell<SEC0, NSEC, CKN, WMAX, Cs>(base, ck, s, p), ...);
}

template<int SEC0, int NSEC>
__device__ __forceinline__ void kpn_grp_body(const float* __restrict__ corep,
                                             const float* __restrict__ dpad,
                                             float* __restrict__ out)
{
  constexpr int WMAX = SEC0 + NSEC + 1;          // widest WIDE in this group
  constexpr int CK0 = KOFFS[SEC0];
  constexpr int CKN = KOFFS[SEC0 + NSEC - 1] + (SEC0 + NSEC + 1) - CK0;

  // XCD-contiguous band swizzle: 576 = 8 XCDs * 72 blocks (48 rows each)
  const int bid = blockIdx.x;
  const int sw = (bid & 7) * 72 + (bid >> 3);
  const int px = sw * 256 + threadIdx.x;              // 576*256 = NPIX exactly
  const int y = px / WW, x = px % WW;
  const float* base = dpad + (size_t)(y + 7) * DP + (x + 7);

  float ck[CKN];
  #pragma unroll
  for (int i = 0; i < CKN; ++i) ck[i] = fabsf(corep[(size_t)(CK0 + i) * NPIX + px]);

  float s[NSEC], p[NSEC][3];
  #pragma unroll
  for (int k = 0; k < NSEC; ++k) { s[k] = 0.f; p[k][0] = 0.f; p[k][1] = 0.f; p[k][2] = 0.f; }

  kpn_cells<SEC0, NSEC, CKN, WMAX>(std::make_integer_sequence<int, WMAX * WMAX>{},
                                   base, ck, s, p);

  #pragma unroll
  for (int t = 0; t < NSEC; ++t) {
    const float inv = 1.f / s[t];
    float* o = out + (size_t)(SEC0 + t + 1) * NPIX3 + px;
    o[0] = p[t][0] * inv;
    o[NPIX] = p[t][1] * inv;
    o[2 * NPIX] = p[t][2] * inv;
  }
}

// Full 7-section fusion: shares all mirror-gathers across sections (675 loads/px).
__global__ __launch_bounds__(256, 2)
void kpn_fused7(const float* __restrict__ corep, const float* __restrict__ dpad,
                float* __restrict__ out)
{
  kpn_grp_body<0, 7>(corep, dpad, out);
}

// ---------------- launch ----------------
extern "C" void kernel_launch(void* const* d_in, const int* in_sizes, int n_in,
                              void* d_out, int out_size, void* d_ws, size_t ws_size,
                              hipStream_t stream)
{
  const float* d_est   = (const float*)d_in[0];
  const float* data    = (const float*)d_in[1];
  const float* w_first = (const float*)d_in[2];
  const float* b_first = (const float*)d_in[3];
  const float* w_blk1  = (const float*)d_in[4];
  const float* b_blk1  = (const float*)d_in[5];
  const float* w_blk2  = (const float*)d_in[6];
  const float* b_blk2  = (const float*)d_in[7];
  const float* w_out   = (const float*)d_in[8];
  const float* b_out   = (const float*)d_in[9];

  char* ws = (char*)d_ws;
  const size_t OFF_A1    = ACT_BYTES;
  const size_t OFF_CORE  = 2 * ACT_BYTES;
  const size_t OFF_DPAD  = OFF_CORE + (size_t)35 * NPIX * 4;
  const size_t OFF_WPACK = OFF_DPAD + (size_t)3 * DPLANE * 4;
  const size_t OFF_BPACK = OFF_WPACK + (size_t)7 * WSW * 2;
  const size_t OFF_WP1   = OFF_BPACK + 448 * 4;
  const size_t OFF_IN8   = OFF_WP1 + (size_t)WP1N * 2;

  u16*   A0    = (u16*)(ws);
  u16*   A1    = (u16*)(ws + OFF_A1);
  float* corep = (float*)(ws + OFF_CORE);
  float* dpad  = (float*)(ws + OFF_DPAD);
  u16*   wpack = (u16*)(ws + OFF_WPACK);
  float* bpack = (float*)(ws + OFF_BPACK);
  u16*   wp1   = (u16*)(ws + OFF_WP1);
  u16*   in8   = (u16*)(ws + OFF_IN8);

  // output 0 is an exact copy of `data`
  hipMemcpyAsync(d_out, data, (size_t)NPIX3 * 4, hipMemcpyDeviceToDevice, stream);

  prep_kern<<<3671, 256, 0, stream>>>(w_blk1, w_blk2, w_out, b_blk1, b_blk2, b_out,
                                      w_first, data, d_est,
                                      wpack, bpack, wp1, dpad, in8, A0, A1);
  conv1_mfma<<<2304, 64, 0, stream>>>(in8, wp1, b_first, A0);

  for (int i = 0; i < 3; ++i) {
    conv_mfma<0><<<1152, 256, 0, stream>>>(A0, wpack + (size_t)(2 * i) * WSW,
                                           bpack + (2 * i) * 64, A1, nullptr);
    conv_mfma<1><<<1152, 256, 0, stream>>>(A1, wpack + (size_t)(2 * i + 1) * WSW,
                                           bpack + (2 * i + 1) * 64, A0, nullptr);
  }
  conv_mfma<2><<<1152, 256, 0, stream>>>(A0, wpack + (size_t)6 * WSW,
                                         bpack + 6 * 64, nullptr, corep);

  kpn_fused7<<<576, 256, 0, stream>>>(corep, dpad, (float*)d_out);
}

// Round 20
// 181.625 us; speedup vs baseline: 5.5054x; 1.0080x over previous
//
#include <hip/hip_runtime.h>
#include <hip/hip_bf16.h>
#include <utility>

typedef __attribute__((ext_vector_type(4))) float f32x4;
typedef float f32x4u __attribute__((ext_vector_type(4), aligned(4)));  // dword-aligned vec load
typedef __attribute__((ext_vector_type(8))) short bf16x8;
typedef __attribute__((ext_vector_type(4))) unsigned short u16x4;
typedef unsigned short u16;

constexpr int HH = 384, WW = 384;
constexpr int AWP = 386;               // padded activation width (+1 halo each side)
constexpr int ASTR = AWP * 64;         // elements per padded activation row
constexpr int NPIX = HH * WW;          // 147456
constexpr int NPIX3 = NPIX * 3;        // 442368 (one output tensor)
constexpr int DP = 398, DPLANE = DP * DP;  // data padded by 7 each side
constexpr size_t ACT_BYTES = (size_t)AWP * AWP * 64 * 2;  // 19,071,488
constexpr int WSW = 72 * 512;          // swizzled weights per conv: 72 iters * 64 lanes * 8
constexpr int WP1N = 12 * 512;         // conv1 swizzled weights (K=96)

__device__ __forceinline__ u16 f2bf(float f) {
  union { __hip_bfloat16 h; u16 u; } v; v.h = __float2bfloat16(f); return v.u;
}
__device__ __forceinline__ float bf2f(u16 u) {
  union { float f; unsigned int i; } v; v.i = ((unsigned int)u) << 16; return v.f;
}

// ---------------- fused preprocessing: repack + padcopy + pad6 + halo ----------------
constexpr int PR_REPACK = 7 * WSW + 448 + WP1N;          // 264640
constexpr int PR_PADCOPY = PR_REPACK + NPIX3;            // +442368 = 707008
constexpr int PR_PAD6 = PR_PADCOPY + NPIX;               // +147456 = 854464
constexpr int PR_HALO = PR_PAD6 + 49280 + 3080 + 32844;  // +85204 = 939668

__global__ void prep_kern(const float* __restrict__ w1, const float* __restrict__ w2,
                          const float* __restrict__ wo, const float* __restrict__ b1,
                          const float* __restrict__ b2, const float* __restrict__ bo,
                          const float* __restrict__ wf, const float* __restrict__ data,
                          const float* __restrict__ din6,
                          u16* __restrict__ wpack, float* __restrict__ bpack,
                          u16* __restrict__ wp1, float* __restrict__ dpad,
                          u16* __restrict__ in8, u16* __restrict__ A0,
                          u16* __restrict__ A1)
{
  const int gidx = blockIdx.x * 256 + threadIdx.x;
  if (gidx < PR_REPACK) {
    const int idx = gidx;
    constexpr int NW = 7 * WSW;
    if (idx < NW) {
      const int c = idx / WSW;
      const int r = idx % WSW;
      const int iter = r / 512;
      const int lane = (r % 512) / 8;
      const int j = r % 8;
      const int tap = iter >> 3;
      const int ich = (iter >> 2) & 1;
      const int m = iter & 3;
      const int oc = m * 16 + (lane & 15);
      const int ic = ich * 32 + (lane >> 4) * 8 + j;
      float v;
      if (c < 6) {
        const float* s = (c & 1) ? w2 : w1;
        v = s[(((c >> 1) * 64 + oc) * 64 + ic) * 9 + tap];
      } else {
        v = (oc < 35) ? wo[(oc * 64 + ic) * 9 + tap] : 0.f;
      }
      wpack[idx] = f2bf(v);
    } else if (idx < NW + 448) {
      const int t = idx - NW;
      const int c = t / 64, oc = t % 64;
      float v;
      if (c < 6) v = ((c & 1) ? b2 : b1)[(c >> 1) * 64 + oc];
      else v = (oc < 35) ? bo[oc] : 0.f;
      bpack[t] = v;
    } else {
      const int t = idx - NW - 448;
      const int iter = t / 512;
      const int lane = (t % 512) / 8;
      const int j = t % 8;
      const int m = iter & 3;
      const int kb = iter >> 2;
      const int oc = m * 16 + (lane & 15);
      const int k = kb * 32 + (lane >> 4) * 8 + j;
      const int tap = k >> 3, ic = k & 7;
      const float v = (tap < 9 && ic < 6) ? wf[oc * 54 + ic * 9 + tap] : 0.f;
      wp1[t] = f2bf(v);
    }
  } else if (gidx < PR_PADCOPY) {
    const int idx = gidx - PR_REPACK;
    const int c = idx / NPIX, r = idx % NPIX;
    const int y = r / WW, x = r % WW;
    dpad[c * DPLANE + (y + 7) * DP + (x + 7)] = data[idx];
  } else if (gidx < PR_PAD6) {
    const int px = gidx - PR_PADCOPY;
    const int y = px / WW, x = px % WW;
    u16 vals[8];
    #pragma unroll
    for (int ic = 0; ic < 6; ++ic) vals[ic] = f2bf(din6[ic * NPIX + px]);
    vals[6] = 0; vals[7] = 0;
    u16* o = in8 + ((size_t)(y + 1) * AWP + (x + 1)) * 8;
    *(u16x4*)(o) = u16x4{vals[0], vals[1], vals[2], vals[3]};
    *(u16x4*)(o + 4) = u16x4{vals[4], vals[5], vals[6], vals[7]};
  } else if (gidx < PR_HALO) {
    const int idx = gidx - PR_PAD6;
    if (idx < 49280) {                       // A0/A1 border: 1540 px * 16 u16x4 each
      u16* buf = (idx < 24640) ? A0 : A1;
      const int t = (idx < 24640) ? idx : idx - 24640;
      const int pos = t >> 4, q = t & 15;
      int y, x;
      if (pos < 386) { y = 0; x = pos; }
      else if (pos < 772) { y = 385; x = pos - 386; }
      else if (pos < 1156) { y = pos - 772 + 1; x = 0; }
      else { y = pos - 1156 + 1; x = 385; }
      *(u16x4*)(buf + ((size_t)y * AWP + x) * 64 + q * 4) = u16x4{0, 0, 0, 0};
    } else if (idx < 49280 + 3080) {         // in8 border: 1540 px * 2 u16x4
      const int t = idx - 49280;
      const int pos = t >> 1, q = t & 1;
      int y, x;
      if (pos < 386) { y = 0; x = pos; }
      else if (pos < 772) { y = 385; x = pos - 386; }
      else if (pos < 1156) { y = pos - 772 + 1; x = 0; }
      else { y = pos - 1156 + 1; x = 385; }
      *(u16x4*)(in8 + ((size_t)y * AWP + x) * 8 + q * 4) = u16x4{0, 0, 0, 0};
    } else {                                 // dpad border width 7, 3 ch
      const int t = idx - 52360;
      const int c = t / 10948, r = t % 10948;
      int y, x;
      if (r < 2786) { y = r / 398; x = r % 398; }
      else if (r < 5572) { const int rr = r - 2786; y = 391 + rr / 398; x = rr % 398; }
      else { const int rr = r - 5572; y = 7 + rr / 14; const int k = rr % 14; x = (k < 7) ? k : 384 + k; }
      dpad[(size_t)c * DPLANE + (size_t)y * DP + x] = 0.f;
    }
  }
}

// ---------------- conv1 via MFMA: 8ch NHWC bf16 -> 64, K=96 ----------------
__global__ __launch_bounds__(64)
void conv1_mfma(const u16* __restrict__ in8, const u16* __restrict__ wp,
                const float* __restrict__ bias, u16* __restrict__ outb)
{
  const int lane = threadIdx.x;
  const int l15 = lane & 15, g8 = lane >> 4;
  // XCD swizzle: 2304 = 8 * 288
  const int bid = blockIdx.x;
  const int sw = (bid & 7) * 288 + (bid >> 3);
  const int y = sw / 6;
  const int x0 = (sw % 6) * 64;

  f32x4 acc[4][4];
  #pragma unroll
  for (int m = 0; m < 4; ++m)
    #pragma unroll
    for (int n = 0; n < 4; ++n)
      acc[m][n] = f32x4{0.f, 0.f, 0.f, 0.f};

  #pragma unroll
  for (int kb = 0; kb < 3; ++kb) {
    const int tap = kb * 4 + g8;
    const int vt = tap < 9 ? tap : 0;                // dup tap0 for pad (weights are 0)
    const int kr = vt / 3, kc = vt % 3;
    const u16* inr = in8 + ((size_t)(y + kr) * AWP + x0 + kc) * 8;
    bf16x8 a[4], b[4];
    #pragma unroll
    for (int m = 0; m < 4; ++m)
      a[m] = *(const bf16x8*)(wp + (kb * 4 + m) * 512 + lane * 8);
    #pragma unroll
    for (int n = 0; n < 4; ++n)
      b[n] = *(const bf16x8*)(inr + (size_t)(n * 16 + l15) * 8);
    #pragma unroll
    for (int m = 0; m < 4; ++m)
      #pragma unroll
      for (int n = 0; n < 4; ++n)
        acc[m][n] = __builtin_amdgcn_mfma_f32_16x16x32_bf16(a[m], b[n], acc[m][n], 0, 0, 0);
  }

  const int oc_lo = g8 * 4;
  #pragma unroll
  for (int m = 0; m < 4; ++m) {
    const int oc0 = m * 16 + oc_lo;
    const f32x4 bv = *(const f32x4*)(bias + oc0);
    #pragma unroll
    for (int n = 0; n < 4; ++n) {
      const int px = x0 + n * 16 + l15;
      const f32x4 v = acc[m][n] + bv;
      u16x4 s;
      #pragma unroll
      for (int j = 0; j < 4; ++j) s[j] = f2bf(v[j]);
      *(u16x4*)(outb + ((size_t)(y + 1) * AWP + (px + 1)) * 64 + oc0) = s;
    }
  }
}

// ---------------- MFMA implicit-GEMM 3x3 conv: 128-px tile, 4 waves, LDS-staged B ----------------
// Wave (pxh, ich): px-half 64 px, K-half ich. MODE 2 computes only m<3 (oc>=48 unused).
// MODE 0: +bias, relu; MODE 1: +bias,+residual; MODE 2: +bias, f32 planar (oc<35)
template<int MODE>
__global__ __launch_bounds__(256, 3)
void conv_mfma(const u16* __restrict__ in, const u16* __restrict__ wp,
               const float* __restrict__ bias, u16* __restrict__ outb,
               float* __restrict__ outf)
{
  constexpr int MM = (MODE == 2) ? 3 : 4;          // m-frags (oc tiles) actually needed
  __shared__ u16 smem[3 * 136 * 64];               // 52224 B; reused as 2x16KB red buffers
  const int lane = threadIdx.x & 63;
  const int wv = threadIdx.x >> 6;                 // 0..3
  const int pxh = wv >> 1;                         // px half (0: px 0-63, 1: px 64-127)
  const int ich = wv & 1;                          // K-half
  const int l15 = lane & 15, g8 = lane >> 4;
  // XCD band swizzle: 1152 = 8 XCDs * 144 (48 rows * 3 col-blocks of 128 px)
  const int bid = blockIdx.x;
  const int sw = (bid & 7) * 144 + (bid >> 3);
  const int y = sw / 3;
  const int x0 = (sw % 3) * 128;

  // ---- stage 3 rows x 17 KB (136 px), 1KB per global_load_lds, 51 loads / 4 waves ----
  {
    const int pxl = lane >> 3;                     // px sub-index within 1KB (0..7)
    const int s = lane & 7;                        // 16B slot (0..7)
    #pragma unroll
    for (int row = 0; row < 3; ++row) {
      const char* gbase = (const char*)(in + (size_t)(y + row) * ASTR + (size_t)x0 * 64);
      #pragma unroll
      for (int j = 0; j < 17; ++j) {
        if (((row * 17 + j) & 3) == wv) {
          const int px = j * 8 + pxl;              // 0..135 (reads beyond col 129 unused)
          const char* g = gbase + px * 128 + ((s ^ (px & 7)) << 4);
          __builtin_amdgcn_global_load_lds(
              (__attribute__((address_space(1))) const void*)g,
              (__attribute__((address_space(3))) void*)((char*)smem + row * 17408 + j * 1024),
              16, 0, 0);
        }
      }
    }
  }
  __syncthreads();

  f32x4 acc[MM][4];
  #pragma unroll
  for (int m = 0; m < MM; ++m)
    #pragma unroll
    for (int n = 0; n < 4; ++n)
      acc[m][n] = f32x4{0.f, 0.f, 0.f, 0.f};

  const int chunk = ich * 4 + g8;                  // 16B chunk within a pixel's 128B
  #pragma unroll
  for (int tap = 0; tap < 9; ++tap) {
    const int kr = tap / 3, kc = tap % 3;
    const u16* wpi = wp + ((tap * 2 + ich) * 4) * 512 + lane * 8;  // coalesced A-frags
    bf16x8 a[MM], b[4];
    #pragma unroll
    for (int m = 0; m < MM; ++m)
      a[m] = *(const bf16x8*)(wpi + m * 512);
    #pragma unroll
    for (int n = 0; n < 4; ++n) {
      const int p = pxh * 64 + kc + n * 16 + l15;  // 0..129 within staged row
      const char* bp = (const char*)smem + kr * 17408 + p * 128 + ((chunk ^ (p & 7)) << 4);
      b[n] = *(const bf16x8*)bp;
    }
    #pragma unroll
    for (int m = 0; m < MM; ++m)
      #pragma unroll
      for (int n = 0; n < 4; ++n)
        acc[m][n] = __builtin_amdgcn_mfma_f32_16x16x32_bf16(a[m], b[n], acc[m][n], 0, 0, 0);
  }

  __syncthreads();                                 // all b-reads done before smem reuse
  float* red = (float*)smem;                       // 2 x 16 KB reduction buffers (reuse)
  if (ich == 1) {
    #pragma unroll
    for (int m = 0; m < MM; ++m)
      #pragma unroll
      for (int n = 0; n < 4; ++n)
        *(f32x4*)(red + pxh * 4096 + (m * 4 + n) * 256 + lane * 4) = acc[m][n];
  }
  __syncthreads();
  if (ich == 1) return;

  const int oc_lo = g8 * 4;
  #pragma unroll
  for (int m = 0; m < MM; ++m) {
    const int oc0 = m * 16 + oc_lo;                // D row = (lane>>4)*4 + reg
    const f32x4 bv = *(const f32x4*)(bias + oc0);
    #pragma unroll
    for (int n = 0; n < 4; ++n) {
      const int px = x0 + pxh * 64 + n * 16 + l15; // D col = lane&15
      f32x4 v = acc[m][n] + *(const f32x4*)(red + pxh * 4096 + (m * 4 + n) * 256 + lane * 4) + bv;
      if constexpr (MODE == 0) {
        #pragma unroll
        for (int j = 0; j < 4; ++j) v[j] = v[j] > 0.f ? v[j] : 0.f;
      }
      if constexpr (MODE == 1) {
        const u16x4 rr = *(const u16x4*)(outb + ((size_t)(y + 1) * AWP + (px + 1)) * 64 + oc0);
        #pragma unroll
        for (int j = 0; j < 4; ++j) v[j] += bf2f(rr[j]);
      }
      if constexpr (MODE <= 1) {
        u16x4 s;
        #pragma unroll
        for (int j = 0; j < 4; ++j) s[j] = f2bf(v[j]);
        *(u16x4*)(outb + ((size_t)(y + 1) * AWP + (px + 1)) * 64 + oc0) = s;
      } else {
        #pragma unroll
        for (int j = 0; j < 4; ++j) {
          const int oc = oc0 + j;
          if (oc < 35) outf[(size_t)oc * NPIX + (size_t)y * WW + px] = v[j];
        }
      }
    }
  }
}

// ---------------- KPN apply: float4-row gathers + template-fold sections ----------------
constexpr int isqrt_(int d2) { int li = 0; while ((li + 1) * (li + 1) <= d2) ++li; return li; }
constexpr double csqrt_(double x) {
  double g = x < 1.0 ? 1.0 : x;
  for (int i = 0; i < 60; ++i) g = 0.5 * (g + x / g);
  return g;
}
constexpr int KOFFS[7] = {0, 2, 5, 9, 14, 20, 27};

template<int SEC0, int NSEC, int CKN, int A, int B, int T>
__device__ __forceinline__ void kpn_sec_one(const float (&g)[3], const float (&ck)[CKN],
                                            float (&s)[NSEC], float (&p)[NSEC][3])
{
  constexpr int WIDE = SEC0 + T + 2;
  if constexpr (A < WIDE && B < WIDE) {
    constexpr int d2 = A * A + B * B;
    constexpr int li = isqrt_(d2);
    constexpr bool exact = (li * li == d2);
    constexpr int hraw = exact ? li : li + 1;
    constexpr float dd = (float)csqrt_((double)d2);
    constexpr float wlo = exact ? 1.0f : ((float)hraw - dd);
    constexpr float whi = exact ? 0.0f : (dd - (float)li);
    constexpr float mult = ((A > 0) ? 2.0f : 1.0f) * ((B > 0) ? 2.0f : 1.0f);
    constexpr int lidx = li < WIDE - 1 ? li : WIDE - 1;
    constexpr int hidx = hraw < WIDE - 1 ? hraw : WIDE - 1;
    constexpr bool msk = d2 <= (WIDE - 1) * (WIDE - 1);
    constexpr int cb = KOFFS[SEC0 + T] - KOFFS[SEC0];
    float e;
    if constexpr (msk) e = __expf(wlo * ck[cb + lidx] + whi * ck[cb + hidx]);
    else e = 1.0f;                                   // masked: logit 0, still in softmax
    s[T] += mult * e;
    p[T][0] += e * g[0];
    p[T][1] += e * g[1];
    p[T][2] += e * g[2];
  }
}

template<int SEC0, int NSEC, int CKN, int A, int B, int... Ts>
__device__ __forceinline__ void kpn_secs(std::integer_sequence<int, Ts...>,
                                         const float (&g)[3], const float (&ck)[CKN],
                                         float (&s)[NSEC], float (&p)[NSEC][3])
{
  (kpn_sec_one<SEC0, NSEC, CKN, A, B, Ts>(g, ck, s, p), ...);
}

template<int SEC0, int NSEC, int CKN, int A, int B>
__device__ __forceinline__ void kpn_bcol(const float (&rf)[3][8], const float (&ck)[CKN],
                                         float (&s)[NSEC], float (&p)[NSEC][3])
{
  const float g[3] = {rf[0][B], rf[1][B], rf[2][B]};
  kpn_secs<SEC0, NSEC, CKN, A, B>(std::make_integer_sequence<int, NSEC>{}, g, ck, s, p);
}

template<int SEC0, int NSEC, int CKN, int A, int... Bs>
__device__ __forceinline__ void kpn_bcols(std::integer_sequence<int, Bs...>,
                                          const float (&rf)[3][8], const float (&ck)[CKN],
                                          float (&s)[NSEC], float (&p)[NSEC][3])
{
  (kpn_bcol<SEC0, NSEC, CKN, A, Bs>(rf, ck, s, p), ...);
}

// One mirror row-pair (+A, -A): 4 float4 loads per channel per row, fold the +-A
// row-sum and +-b column-mirror into rf[3][8], then run all section updates.
template<int SEC0, int NSEC, int CKN, int WMAX, int A>
__device__ __forceinline__ void kpn_arow(const float* __restrict__ base,
                                         const float (&ck)[CKN],
                                         float (&s)[NSEC], float (&p)[NSEC][3])
{
  float rf[3][8];
  #pragma unroll
  for (int c = 0; c < 3; ++c) {
    const float* bc = base + c * DPLANE;
    f32x4u v[4];
    #pragma unroll
    for (int q = 0; q < 4; ++q)
      v[q] = *(const f32x4u*)(bc + A * DP - 7 + q * 4);   // cols -7..8
    if constexpr (A > 0) {
      #pragma unroll
      for (int q = 0; q < 4; ++q) {
        const f32x4u w = *(const f32x4u*)(bc - A * DP - 7 + q * 4);
        v[q] += w;
      }
    }
    // raw[k] = v[k>>2][k&3], col offset k-7; rf[b] = raw[7+b] + raw[7-b] (b>0)
    rf[c][0] = v[1][3];
    rf[c][1] = v[2][0] + v[1][2];
    rf[c][2] = v[2][1] + v[1][1];
    rf[c][3] = v[2][2] + v[1][0];
    rf[c][4] = v[2][3] + v[0][3];
    rf[c][5] = v[3][0] + v[0][2];
    rf[c][6] = v[3][1] + v[0][1];
    rf[c][7] = v[3][2] + v[0][0];
  }
  kpn_bcols<SEC0, NSEC, CKN, A>(std::make_integer_sequence<int, WMAX>{}, rf, ck, s, p);
}

template<int SEC0, int NSEC, int CKN, int WMAX, int... As>
__device__ __forceinline__ void kpn_arows(std::integer_sequence<int, As...>,
                                          const float* __restrict__ base,
                                          const float (&ck)[CKN],
                                          float (&s)[NSEC], float (&p)[NSEC][3])
{
  (kpn_arow<SEC0, NSEC, CKN, WMAX, As>(base, ck, s, p), ...);
}

template<int SEC0, int NSEC>
__device__ __forceinline__ void kpn_grp_body(const float* __restrict__ corep,
                                             const float* __restrict__ dpad,
                                             float* __restrict__ out)
{
  constexpr int WMAX = SEC0 + NSEC + 1;          // widest WIDE in this group
  constexpr int CK0 = KOFFS[SEC0];
  constexpr int CKN = KOFFS[SEC0 + NSEC - 1] + (SEC0 + NSEC + 1) - CK0;

  // XCD-contiguous band swizzle: 576 = 8 XCDs * 72 blocks (48 rows each)
  const int bid = blockIdx.x;
  const int sw = (bid & 7) * 72 + (bid >> 3);
  const int px = sw * 256 + threadIdx.x;              // 576*256 = NPIX exactly
  const int y = px / WW, x = px % WW;
  const float* base = dpad + (size_t)(y + 7) * DP + (x + 7);

  float ck[CKN];
  #pragma unroll
  for (int i = 0; i < CKN; ++i) ck[i] = fabsf(corep[(size_t)(CK0 + i) * NPIX + px]);

  float s[NSEC], p[NSEC][3];
  #pragma unroll
  for (int k = 0; k < NSEC; ++k) { s[k] = 0.f; p[k][0] = 0.f; p[k][1] = 0.f; p[k][2] = 0.f; }

  kpn_arows<SEC0, NSEC, CKN, WMAX>(std::make_integer_sequence<int, WMAX>{},
                                   base, ck, s, p);

  #pragma unroll
  for (int t = 0; t < NSEC; ++t) {
    const float inv = 1.f / s[t];
    float* o = out + (size_t)(SEC0 + t + 1) * NPIX3 + px;
    o[0] = p[t][0] * inv;
    o[NPIX] = p[t][1] * inv;
    o[2 * NPIX] = p[t][2] * inv;
  }
}

// Full 7-section fusion with float4 row gathers (180 load-instrs/px vs 675 scalar).
// No min-waves bound: VGPR ~135 keeps 8 waves/CU (same as (256,2)) without spill.
__global__ __launch_bounds__(256)
void kpn_fused7(const float* __restrict__ corep, const float* __restrict__ dpad,
                float* __restrict__ out)
{
  kpn_grp_body<0, 7>(corep, dpad, out);
}

// ---------------- launch ----------------
extern "C" void kernel_launch(void* const* d_in, const int* in_sizes, int n_in,
                              void* d_out, int out_size, void* d_ws, size_t ws_size,
                              hipStream_t stream)
{
  const float* d_est   = (const float*)d_in[0];
  const float* data    = (const float*)d_in[1];
  const float* w_first = (const float*)d_in[2];
  const float* b_first = (const float*)d_in[3];
  const float* w_blk1  = (const float*)d_in[4];
  const float* b_blk1  = (const float*)d_in[5];
  const float* w_blk2  = (const float*)d_in[6];
  const float* b_blk2  = (const float*)d_in[7];
  const float* w_out   = (const float*)d_in[8];
  const float* b_out   = (const float*)d_in[9];

  char* ws = (char*)d_ws;
  const size_t OFF_A1    = ACT_BYTES;
  const size_t OFF_CORE  = 2 * ACT_BYTES;
  const size_t OFF_DPAD  = OFF_CORE + (size_t)35 * NPIX * 4;
  const size_t OFF_WPACK = OFF_DPAD + (size_t)3 * DPLANE * 4;
  const size_t OFF_BPACK = OFF_WPACK + (size_t)7 * WSW * 2;
  const size_t OFF_WP1   = OFF_BPACK + 448 * 4;
  const size_t OFF_IN8   = OFF_WP1 + (size_t)WP1N * 2;

  u16*   A0    = (u16*)(ws);
  u16*   A1    = (u16*)(ws + OFF_A1);
  float* corep = (float*)(ws + OFF_CORE);
  float* dpad  = (float*)(ws + OFF_DPAD);
  u16*   wpack = (u16*)(ws + OFF_WPACK);
  float* bpack = (float*)(ws + OFF_BPACK);
  u16*   wp1   = (u16*)(ws + OFF_WP1);
  u16*   in8   = (u16*)(ws + OFF_IN8);

  // output 0 is an exact copy of `data`
  hipMemcpyAsync(d_out, data, (size_t)NPIX3 * 4, hipMemcpyDeviceToDevice, stream);

  prep_kern<<<3671, 256, 0, stream>>>(w_blk1, w_blk2, w_out, b_blk1, b_blk2, b_out,
                                      w_first, data, d_est,
                                      wpack, bpack, wp1, dpad, in8, A0, A1);
  conv1_mfma<<<2304, 64, 0, stream>>>(in8, wp1, b_first, A0);

  for (int i = 0; i < 3; ++i) {
    conv_mfma<0><<<1152, 256, 0, stream>>>(A0, wpack + (size_t)(2 * i) * WSW,
                                           bpack + (2 * i) * 64, A1, nullptr);
    conv_mfma<1><<<1152, 256, 0, stream>>>(A1, wpack + (size_t)(2 * i + 1) * WSW,
                                           bpack + (2 * i + 1) * 64, A0, nullptr);
  }
  conv_mfma<2><<<1152, 256, 0, stream>>>(A0, wpack + (size_t)6 * WSW,
                                         bpack + 6 * 64, nullptr, corep);

  kpn_fused7<<<576, 256, 0, stream>>>(corep, dpad, (float*)d_out);
}